// Round 1
// baseline (614.767 us; speedup 1.0000x reference)
//
#include <hip/hip_runtime.h>
#include <hip/hip_bf16.h>
#include <cstdint>

// MLA: B=2, T=2048, H=16, d_nope=128, d_rope=64, d_qk=192, d_v=128,
// kv_lora=512, q_lora=1536, hidden=2048. Output f32 [4096][2048].

typedef __bf16 bf16;
typedef __bf16 bf16x8 __attribute__((ext_vector_type(8)));
typedef __bf16 bf16x4v __attribute__((ext_vector_type(4)));
typedef float f32x4 __attribute__((ext_vector_type(4)));

#define TSEQ 2048
#define MR 4096  // B*T

typedef const uint32_t __attribute__((address_space(1))) * gas1_t;
typedef uint32_t __attribute__((address_space(3))) * las3_t;

static __device__ __forceinline__ void gload_lds16(const void* g, void* l) {
  __builtin_amdgcn_global_load_lds(
      reinterpret_cast<gas1_t>(reinterpret_cast<uintptr_t>(g)),
      reinterpret_cast<las3_t>(reinterpret_cast<uintptr_t>(l)), 16, 0, 0);
}

// Assumed A/B fragment layout for v_mfma_f32_16x16x32_bf16:
//   A: lane l holds A[row = l&15][k = 8*(l>>4) + j], j=0..7 (contiguous 8)
//   B: lane l holds B[k = 8*(l>>4) + j][col = l&15]
// C/D (verified, learn_hip m89): col = lane&15, row = (lane>>4)*4 + reg.
static __device__ __forceinline__ f32x4 mfma16(bf16x8 a, bf16x8 b, f32x4 c) {
  return __builtin_amdgcn_mfma_f32_16x16x32_bf16(a, b, c, 0, 0, 0);
}

// ---------------- prep kernels ----------------

__global__ __launch_bounds__(256) void k_cvt_bf16(const float* __restrict__ in,
                                                  bf16* __restrict__ out) {
  int i = blockIdx.x * 256 + threadIdx.x;
  float4 f = reinterpret_cast<const float4*>(in)[i];
  bf16x4v o = {(bf16)f.x, (bf16)f.y, (bf16)f.z, (bf16)f.w};
  reinterpret_cast<bf16x4v*>(out)[i] = o;
}

// W [K][N] f32 -> Wt [N][K] bf16 (K, N multiples of 32)
__global__ __launch_bounds__(256) void k_transpose(const float* __restrict__ W,
                                                   bf16* __restrict__ Wt,
                                                   int K, int N) {
  __shared__ float t[32][33];
  int bi = blockIdx.x, bj = blockIdx.y;
  int c = threadIdx.x & 31, r0 = threadIdx.x >> 5;
#pragma unroll
  for (int rr = 0; rr < 32; rr += 8)
    t[rr + r0][c] = W[(size_t)(bj * 32 + rr + r0) * N + bi * 32 + c];
  __syncthreads();
#pragma unroll
  for (int rr = 0; rr < 32; rr += 8)
    Wt[(size_t)(bi * 32 + rr + r0) * K + bj * 32 + c] = (bf16)t[c][rr + r0];
}

// rt[t][j] = {cos, sin}(t * theta^(-j/32)), t<2048, j<32
__global__ __launch_bounds__(64) void k_rope_table(float* __restrict__ rt) {
  int t = blockIdx.x * 2 + (threadIdx.x >> 5);
  int j = threadIdx.x & 31;
  float freq = exp2f(-(float)j * (1.0f / 32.0f) * log2f(500000.0f));
  float ang = (float)t * freq;
  rt[t * 64 + 2 * j] = cosf(ang);
  rt[t * 64 + 2 * j + 1] = sinf(ang);
}

template <int NCH>  // D = NCH*512, one wave per row
__global__ __launch_bounds__(64) void k_rmsnorm(const bf16* __restrict__ in,
                                                const float* __restrict__ w,
                                                bf16* __restrict__ out, int D) {
  int row = blockIdx.x, lane = threadIdx.x;
  const bf16* ip = in + (size_t)row * D;
  bf16x8 v[NCH];
  float ss = 0.f;
#pragma unroll
  for (int c = 0; c < NCH; ++c) {
    v[c] = *reinterpret_cast<const bf16x8*>(ip + c * 512 + lane * 8);
#pragma unroll
    for (int e = 0; e < 8; ++e) { float f = (float)v[c][e]; ss += f * f; }
  }
#pragma unroll
  for (int m = 1; m <= 32; m <<= 1) ss += __shfl_xor(ss, m);
  float rs = rsqrtf(ss / (float)D + 1e-6f);
  bf16* op = out + (size_t)row * D;
#pragma unroll
  for (int c = 0; c < NCH; ++c) {
    bf16x8 o;
#pragma unroll
    for (int e = 0; e < 8; ++e)
      o[e] = (bf16)((float)v[c][e] * rs * w[c * 512 + lane * 8 + e]);
    *reinterpret_cast<bf16x8*>(op + c * 512 + lane * 8) = o;
  }
}

// ckv [MR][576]: rmsnorm cols 0..511 -> kvn [MR][512]; rope cols 512..575 -> kr [MR][64]
__global__ __launch_bounds__(64) void k_kv_norm_rope(
    const bf16* __restrict__ ckv, const float* __restrict__ w,
    const float* __restrict__ rt, bf16* __restrict__ kvn,
    bf16* __restrict__ kr) {
  int row = blockIdx.x, lane = threadIdx.x;
  const bf16* ip = ckv + (size_t)row * 576;
  bf16x8 v = *reinterpret_cast<const bf16x8*>(ip + lane * 8);
  float ss = 0.f;
#pragma unroll
  for (int e = 0; e < 8; ++e) { float f = (float)v[e]; ss += f * f; }
#pragma unroll
  for (int m = 1; m <= 32; m <<= 1) ss += __shfl_xor(ss, m);
  float rs = rsqrtf(ss / 512.0f + 1e-6f);
  bf16x8 o;
#pragma unroll
  for (int e = 0; e < 8; ++e) o[e] = (bf16)((float)v[e] * rs * w[lane * 8 + e]);
  *reinterpret_cast<bf16x8*>(kvn + (size_t)row * 512 + lane * 8) = o;
  if (lane < 32) {
    int t = row & (TSEQ - 1);
    float x0 = (float)ip[512 + 2 * lane], x1 = (float)ip[512 + 2 * lane + 1];
    float c = rt[t * 64 + 2 * lane], s = rt[t * 64 + 2 * lane + 1];
    kr[(size_t)row * 64 + lane] = (bf16)(x0 * c - x1 * s);
    kr[(size_t)row * 64 + 32 + lane] = (bf16)(x1 * c + x0 * s);
  }
}

// q [MR][3072] (16 heads x 192); rope cols h*192+128..+191 -> qr [MR][16][64]
__global__ __launch_bounds__(256) void k_rope_q(const bf16* __restrict__ q,
                                                const float* __restrict__ rt,
                                                bf16* __restrict__ qr) {
  int idx = blockIdx.x * 256 + threadIdx.x;  // MR*16*32 total
  int j = idx & 31, h = (idx >> 5) & 15, row = idx >> 9;
  int t = row & (TSEQ - 1);
  const bf16* src = q + (size_t)row * 3072 + h * 192 + 128;
  float x0 = (float)src[2 * j], x1 = (float)src[2 * j + 1];
  float c = rt[t * 64 + 2 * j], s = rt[t * 64 + 2 * j + 1];
  bf16* dst = qr + ((size_t)row * 16 + h) * 64;
  dst[j] = (bf16)(x0 * c - x1 * s);
  dst[32 + j] = (bf16)(x1 * c + x0 * s);
}

// ---------------- GEMM: C[M][N] = A[M][K] @ Bt[N][K]^T ----------------
// 128x128 tile, BK=32, 4 waves (2x2 of 64x64), global_load_lds staging.
template <bool OUT_F32>
__global__ __launch_bounds__(256) void k_gemm_bt(const bf16* __restrict__ A,
                                                 const bf16* __restrict__ Bt,
                                                 void* __restrict__ C, int M,
                                                 int N, int K) {
  __shared__ bf16 As[128 * 32];
  __shared__ bf16 Bs[128 * 32];
  const int tid = threadIdx.x, lane = tid & 63, w = tid >> 6;
  const int wm = w >> 1, wn = w & 1;
  const int lg = lane >> 4, lr = lane & 15;
  const int m0 = blockIdx.y * 128, n0 = blockIdx.x * 128;
  f32x4 acc[4][4] = {};
  for (int k0 = 0; k0 < K; k0 += 32) {
    __syncthreads();
#pragma unroll
    for (int i = 0; i < 2; ++i) {
      int chunk = i * 256 + w * 64 + lane;
      int row = chunk >> 2, cc = chunk & 3;
      gload_lds16(A + (size_t)(m0 + row) * K + k0 + cc * 8,
                  (char*)As + (size_t)(i * 256 + w * 64) * 16);
      int nr = n0 + row;
      nr = nr < N ? nr : N - 1;  // clamp (garbage cols never stored)
      gload_lds16(Bt + (size_t)nr * K + k0 + cc * 8,
                  (char*)Bs + (size_t)(i * 256 + w * 64) * 16);
    }
    __syncthreads();
    bf16x8 af[4], bfr[4];
#pragma unroll
    for (int mi = 0; mi < 4; ++mi)
      af[mi] = *reinterpret_cast<const bf16x8*>(
          &As[(wm * 64 + mi * 16 + lr) * 32 + lg * 8]);
#pragma unroll
    for (int ni = 0; ni < 4; ++ni)
      bfr[ni] = *reinterpret_cast<const bf16x8*>(
          &Bs[(wn * 64 + ni * 16 + lr) * 32 + lg * 8]);
#pragma unroll
    for (int mi = 0; mi < 4; ++mi)
#pragma unroll
      for (int ni = 0; ni < 4; ++ni)
        acc[mi][ni] = mfma16(af[mi], bfr[ni], acc[mi][ni]);
  }
#pragma unroll
  for (int mi = 0; mi < 4; ++mi)
#pragma unroll
    for (int ni = 0; ni < 4; ++ni) {
      int col = n0 + wn * 64 + ni * 16 + lr;
      if (col < N) {
#pragma unroll
        for (int r = 0; r < 4; ++r) {
          int rowg = m0 + wm * 64 + mi * 16 + lg * 4 + r;
          if (OUT_F32)
            reinterpret_cast<float*>(C)[(size_t)rowg * N + col] = acc[mi][ni][r];
          else
            reinterpret_cast<bf16*>(C)[(size_t)rowg * N + col] =
                (bf16)acc[mi][ni][r];
        }
      }
    }
}

// ---------------- causal flash attention ----------------
// grid (qt=32, bh=32), 4 waves; wave w owns q-rows q0+w*16..+15.
// S^T = mfma(A=K, B=Q^T) so softmax over k is lane-local + 2 shfl_xor.
// P goes through wave-private LDS [q][k] so PV B-frags are single b128 reads.
// V staged in fragment-packed LDS (XOR-g swizzled) so PV A-frags (V^T) are b128.
__global__ __launch_bounds__(256) void k_attn(const bf16* __restrict__ q,
                                              const bf16* __restrict__ qr,
                                              const bf16* __restrict__ kv,
                                              const bf16* __restrict__ kr,
                                              bf16* __restrict__ o) {
  __shared__ bf16 Ks[64 * 200];        // [k][192] stride 200
  __shared__ bf16 Vs[8192];            // frag-packed V^T
  __shared__ bf16 Ps[4 * 16 * 72];     // per-wave P [16 q][64 k] stride 72
  const int tid = threadIdx.x, lane = tid & 63, w = tid >> 6;
  const int lg = lane >> 4, lr = lane & 15;
  const int qt = blockIdx.x, bh = blockIdx.y;
  const int b = bh >> 4, h = bh & 15;
  const int q0 = qt * 64;
  const size_t rowbase = (size_t)b * TSEQ;
  const int qg = q0 + w * 16 + lr;  // this lane's q row / S^T column

  bf16x8 qf[6];
  {
    const bf16* qp = q + (rowbase + qg) * 3072 + h * 192;
#pragma unroll
    for (int dc = 0; dc < 4; ++dc)
      qf[dc] = *reinterpret_cast<const bf16x8*>(qp + dc * 32 + lg * 8);
    const bf16* qrp = qr + ((rowbase + qg) * 16 + h) * 64;
#pragma unroll
    for (int dc = 0; dc < 2; ++dc)
      qf[4 + dc] = *reinterpret_cast<const bf16x8*>(qrp + dc * 32 + lg * 8);
  }

  f32x4 oacc[8] = {};
  float m_run = -1e30f, l_run = 0.f;
  const int qmax = q0 + w * 16 + 15;
  const float scale = 0.07216878364870323f;  // 192^-0.5
  const int nkt = qt + 1;

  for (int kt = 0; kt < nkt; ++kt) {
    const int kbase = kt * 64;
    __syncthreads();
    // stage K: 64 rows x (128 nope from kv | 64 rope from kr)
#pragma unroll
    for (int i = 0; i < 6; ++i) {
      int ch = i * 256 + tid;
      int row = ch / 24, cc = ch % 24;
      const bf16* src =
          (cc < 16) ? kv + (rowbase + kbase + row) * 4096 + h * 256 + cc * 8
                    : kr + (rowbase + kbase + row) * 64 + (cc - 16) * 8;
      *reinterpret_cast<uint4*>(&Ks[row * 200 + cc * 8]) =
          *reinterpret_cast<const uint4*>(src);
    }
    // stage V fragment-packed: elem(k,vd) -> [((k>>5)*8+(vd>>4))*4+((k>>3)&3)]*128
    //                                        + ((vd&15)^((k>>3)&3))*8 + (k&7)
    {
      int kq = tid >> 4, vc = tid & 15;
      int kb0 = kq * 4;
      uint32_t rd[4][4];
#pragma unroll
      for (int kk = 0; kk < 4; ++kk) {
        uint4 t4 = *reinterpret_cast<const uint4*>(
            kv + (rowbase + kbase + kb0 + kk) * 4096 + h * 256 + 128 + vc * 8);
        rd[kk][0] = t4.x; rd[kk][1] = t4.y; rd[kk][2] = t4.z; rd[kk][3] = t4.w;
      }
      const int cC = kb0 >> 5, g = (kb0 >> 3) & 3, j0 = kb0 & 7;
#pragma unroll
      for (int e = 0; e < 8; ++e) {
        uint32_t h0 = (rd[0][e >> 1] >> ((e & 1) * 16)) & 0xffffu;
        uint32_t h1 = (rd[1][e >> 1] >> ((e & 1) * 16)) & 0xffffu;
        uint32_t h2 = (rd[2][e >> 1] >> ((e & 1) * 16)) & 0xffffu;
        uint32_t h3 = (rd[3][e >> 1] >> ((e & 1) * 16)) & 0xffffu;
        int vd = vc * 8 + e;
        int slot = (vd & 15) ^ g;
        uint2 wv = make_uint2(h0 | (h1 << 16), h2 | (h3 << 16));
        *reinterpret_cast<uint2*>(
            &Vs[((cC * 8 + (vd >> 4)) * 4 + g) * 128 + slot * 8 + j0]) = wv;
      }
    }
    __syncthreads();
    if (kbase > qmax) continue;  // wave-uniform

    // S^T
    f32x4 sacc[4];
#pragma unroll
    for (int kb = 0; kb < 4; ++kb) {
      f32x4 s = {0.f, 0.f, 0.f, 0.f};
#pragma unroll
      for (int dc = 0; dc < 6; ++dc) {
        bf16x8 kf = *reinterpret_cast<const bf16x8*>(
            &Ks[(kb * 16 + lr) * 200 + dc * 32 + lg * 8]);
        s = mfma16(kf, qf[dc], s);
      }
      sacc[kb] = s;
    }
    // online softmax; lane's k = kbase + kb*16 + lg*4 + r, q = qg
    float sv[4][4];
    float pmax = -1e30f;
#pragma unroll
    for (int kb = 0; kb < 4; ++kb)
#pragma unroll
      for (int r = 0; r < 4; ++r) {
        int kgl = kbase + kb * 16 + lg * 4 + r;
        float val = sacc[kb][r] * scale;
        val = (kgl <= qg) ? val : -1e30f;
        sv[kb][r] = val;
        pmax = fmaxf(pmax, val);
      }
    pmax = fmaxf(pmax, __shfl_xor(pmax, 16));
    pmax = fmaxf(pmax, __shfl_xor(pmax, 32));
    float mnew = fmaxf(m_run, pmax);
    float alpha = __expf(m_run - mnew);
    float ls = 0.f;
#pragma unroll
    for (int kb = 0; kb < 4; ++kb) {
      bf16x4v pw;
#pragma unroll
      for (int r = 0; r < 4; ++r) {
        float p = __expf(sv[kb][r] - mnew);
        ls += p;
        pw[r] = (bf16)p;
      }
      *reinterpret_cast<bf16x4v*>(&Ps[(w * 16 + lr) * 72 + kb * 16 + lg * 4]) = pw;
    }
    ls += __shfl_xor(ls, 16);
    ls += __shfl_xor(ls, 32);
    l_run = l_run * alpha + ls;
    m_run = mnew;
#pragma unroll
    for (int vb = 0; vb < 8; ++vb) {
      oacc[vb][0] *= alpha; oacc[vb][1] *= alpha;
      oacc[vb][2] *= alpha; oacc[vb][3] *= alpha;
    }
    // PV: O^T += V^T @ P^T
#pragma unroll
    for (int c = 0; c < 2; ++c) {
      bf16x8 pb = *reinterpret_cast<const bf16x8*>(
          &Ps[(w * 16 + lr) * 72 + c * 32 + lg * 8]);
#pragma unroll
      for (int vb = 0; vb < 8; ++vb) {
        bf16x8 av = *reinterpret_cast<const bf16x8*>(
            &Vs[((c * 8 + vb) * 4 + lg) * 128 + (lr ^ lg) * 8]);
        oacc[vb] = mfma16(av, pb, oacc[vb]);
      }
    }
  }
  // epilogue: lane holds O^T[vd = vb*16+lg*4+r][q = qg]
  float inv = 1.0f / l_run;
  bf16* op = o + (rowbase + qg) * 2048 + h * 128;
#pragma unroll
  for (int vb = 0; vb < 8; ++vb) {
    bf16x4v ov;
#pragma unroll
    for (int r = 0; r < 4; ++r) ov[r] = (bf16)(oacc[vb][r] * inv);
    *reinterpret_cast<bf16x4v*>(op + vb * 16 + lg * 4) = ov;
  }
}

// ---------------- launch ----------------
extern "C" void kernel_launch(void* const* d_in, const int* in_sizes, int n_in,
                              void* d_out, int out_size, void* d_ws,
                              size_t ws_size, hipStream_t stream) {
  (void)in_sizes; (void)n_in; (void)out_size; (void)ws_size;
  const float* x       = (const float*)d_in[0];
  const float* q_a_w   = (const float*)d_in[1];
  const float* q_a_ln  = (const float*)d_in[2];
  const float* q_b_w   = (const float*)d_in[3];
  const float* kv_a_w  = (const float*)d_in[4];
  const float* kv_a_ln = (const float*)d_in[5];
  const float* kv_b_w  = (const float*)d_in[6];
  const float* o_w     = (const float*)d_in[7];

  char* ws = (char*)d_ws;
  size_t off = 0;
  auto alloc = [&](size_t bytes) {
    void* p = ws + off;
    off += (bytes + 255) & ~(size_t)255;
    return p;
  };
  bf16* x_bf   = (bf16*)alloc((size_t)MR * 2048 * 2);
  bf16* qa_wt  = (bf16*)alloc((size_t)1536 * 2048 * 2);
  bf16* qb_wt  = (bf16*)alloc((size_t)3072 * 1536 * 2);
  bf16* kva_wt = (bf16*)alloc((size_t)576 * 2048 * 2);
  bf16* kvb_wt = (bf16*)alloc((size_t)4096 * 512 * 2);
  bf16* o_wt   = (bf16*)alloc((size_t)2048 * 2048 * 2);
  float* rt    = (float*)alloc((size_t)2048 * 64 * 4);
  bf16* q_a    = (bf16*)alloc((size_t)MR * 1536 * 2);
  bf16* q_a_n  = (bf16*)alloc((size_t)MR * 1536 * 2);
  bf16* ckv    = (bf16*)alloc((size_t)MR * 576 * 2);
  bf16* kv_c_n = (bf16*)alloc((size_t)MR * 512 * 2);
  bf16* kr     = (bf16*)alloc((size_t)MR * 64 * 2);
  bf16* qbuf   = (bf16*)alloc((size_t)MR * 3072 * 2);
  bf16* qr     = (bf16*)alloc((size_t)MR * 16 * 64 * 2);
  bf16* kvbuf  = (bf16*)alloc((size_t)MR * 4096 * 2);
  bf16* attn_o = (bf16*)alloc((size_t)MR * 2048 * 2);

  k_cvt_bf16<<<8192, 256, 0, stream>>>(x, x_bf);
  k_transpose<<<dim3(1536 / 32, 2048 / 32), 256, 0, stream>>>(q_a_w, qa_wt, 2048, 1536);
  k_transpose<<<dim3(3072 / 32, 1536 / 32), 256, 0, stream>>>(q_b_w, qb_wt, 1536, 3072);
  k_transpose<<<dim3(576 / 32, 2048 / 32), 256, 0, stream>>>(kv_a_w, kva_wt, 2048, 576);
  k_transpose<<<dim3(4096 / 32, 512 / 32), 256, 0, stream>>>(kv_b_w, kvb_wt, 512, 4096);
  k_transpose<<<dim3(2048 / 32, 2048 / 32), 256, 0, stream>>>(o_w, o_wt, 2048, 2048);
  k_rope_table<<<1024, 64, 0, stream>>>(rt);

  k_gemm_bt<false><<<dim3(12, 32), 256, 0, stream>>>(x_bf, qa_wt, q_a, MR, 1536, 2048);
  k_gemm_bt<false><<<dim3(5, 32), 256, 0, stream>>>(x_bf, kva_wt, ckv, MR, 576, 2048);
  k_rmsnorm<3><<<MR, 64, 0, stream>>>(q_a, q_a_ln, q_a_n, 1536);
  k_kv_norm_rope<<<MR, 64, 0, stream>>>(ckv, kv_a_ln, rt, kv_c_n, kr);
  k_gemm_bt<false><<<dim3(24, 32), 256, 0, stream>>>(q_a_n, qb_wt, qbuf, MR, 3072, 1536);
  k_rope_q<<<8192, 256, 0, stream>>>(qbuf, rt, qr);
  k_gemm_bt<false><<<dim3(32, 32), 256, 0, stream>>>(kv_c_n, kvb_wt, kvbuf, MR, 4096, 512);
  k_attn<<<dim3(32, 32), 256, 0, stream>>>(qbuf, qr, kvbuf, kr, attn_o);
  k_gemm_bt<true><<<dim3(16, 32), 256, 0, stream>>>(attn_o, o_wt, d_out, MR, 2048, 2048);
}

// Round 2
// 504.324 us; speedup vs baseline: 1.2190x; 1.2190x over previous
//
#include <hip/hip_runtime.h>
#include <hip/hip_bf16.h>
#include <cstdint>

// MLA: B=2, T=2048, H=16, d_nope=128, d_rope=64, d_qk=192, d_v=128,
// kv_lora=512, q_lora=1536, hidden=2048. Output f32 [4096][2048].

typedef __bf16 bf16;
typedef __bf16 bf16x8 __attribute__((ext_vector_type(8)));
typedef __bf16 bf16x4v __attribute__((ext_vector_type(4)));
typedef float f32x4 __attribute__((ext_vector_type(4)));

#define TSEQ 2048
#define MR 4096  // B*T

typedef const uint32_t __attribute__((address_space(1))) * gas1_t;
typedef uint32_t __attribute__((address_space(3))) * las3_t;

static __device__ __forceinline__ void gload_lds16(const void* g, void* l) {
  __builtin_amdgcn_global_load_lds(
      reinterpret_cast<gas1_t>(reinterpret_cast<uintptr_t>(g)),
      reinterpret_cast<las3_t>(reinterpret_cast<uintptr_t>(l)), 16, 0, 0);
}

static __device__ __forceinline__ f32x4 mfma16(bf16x8 a, bf16x8 b, f32x4 c) {
  return __builtin_amdgcn_mfma_f32_16x16x32_bf16(a, b, c, 0, 0, 0);
}

// ---------------- prep kernels ----------------

__global__ __launch_bounds__(256) void k_cvt_bf16(const float* __restrict__ in,
                                                  bf16* __restrict__ out) {
  int i = blockIdx.x * 256 + threadIdx.x;
  float4 f = reinterpret_cast<const float4*>(in)[i];
  bf16x4v o = {(bf16)f.x, (bf16)f.y, (bf16)f.z, (bf16)f.w};
  reinterpret_cast<bf16x4v*>(out)[i] = o;
}

// W [K][N] f32 -> Wt [N][K] bf16 (K, N multiples of 32)
__global__ __launch_bounds__(256) void k_transpose(const float* __restrict__ W,
                                                   bf16* __restrict__ Wt,
                                                   int K, int N) {
  __shared__ float t[32][33];
  int bi = blockIdx.x, bj = blockIdx.y;
  int c = threadIdx.x & 31, r0 = threadIdx.x >> 5;
#pragma unroll
  for (int rr = 0; rr < 32; rr += 8)
    t[rr + r0][c] = W[(size_t)(bj * 32 + rr + r0) * N + bi * 32 + c];
  __syncthreads();
#pragma unroll
  for (int rr = 0; rr < 32; rr += 8)
    Wt[(size_t)(bi * 32 + rr + r0) * K + bj * 32 + c] = (bf16)t[c][rr + r0];
}

// rt[t][j] = {cos, sin}(t * theta^(-j/32)), t<2048, j<32
__global__ __launch_bounds__(64) void k_rope_table(float* __restrict__ rt) {
  int t = blockIdx.x * 2 + (threadIdx.x >> 5);
  int j = threadIdx.x & 31;
  float freq = exp2f(-(float)j * (1.0f / 32.0f) * log2f(500000.0f));
  float ang = (float)t * freq;
  rt[t * 64 + 2 * j] = cosf(ang);
  rt[t * 64 + 2 * j + 1] = sinf(ang);
}

template <int NCH>  // D = NCH*512, one wave per row
__global__ __launch_bounds__(64) void k_rmsnorm(const bf16* __restrict__ in,
                                                const float* __restrict__ w,
                                                bf16* __restrict__ out, int D) {
  int row = blockIdx.x, lane = threadIdx.x;
  const bf16* ip = in + (size_t)row * D;
  bf16x8 v[NCH];
  float ss = 0.f;
#pragma unroll
  for (int c = 0; c < NCH; ++c) {
    v[c] = *reinterpret_cast<const bf16x8*>(ip + c * 512 + lane * 8);
#pragma unroll
    for (int e = 0; e < 8; ++e) { float f = (float)v[c][e]; ss += f * f; }
  }
#pragma unroll
  for (int m = 1; m <= 32; m <<= 1) ss += __shfl_xor(ss, m);
  float rs = rsqrtf(ss / (float)D + 1e-6f);
  bf16* op = out + (size_t)row * D;
#pragma unroll
  for (int c = 0; c < NCH; ++c) {
    bf16x8 o;
#pragma unroll
    for (int e = 0; e < 8; ++e)
      o[e] = (bf16)((float)v[c][e] * rs * w[c * 512 + lane * 8 + e]);
    *reinterpret_cast<bf16x8*>(op + c * 512 + lane * 8) = o;
  }
}

// ckv [MR][576]: rmsnorm cols 0..511 -> kvn [MR][512]; rope cols 512..575 -> kr [MR][64]
__global__ __launch_bounds__(64) void k_kv_norm_rope(
    const bf16* __restrict__ ckv, const float* __restrict__ w,
    const float* __restrict__ rt, bf16* __restrict__ kvn,
    bf16* __restrict__ kr) {
  int row = blockIdx.x, lane = threadIdx.x;
  const bf16* ip = ckv + (size_t)row * 576;
  bf16x8 v = *reinterpret_cast<const bf16x8*>(ip + lane * 8);
  float ss = 0.f;
#pragma unroll
  for (int e = 0; e < 8; ++e) { float f = (float)v[e]; ss += f * f; }
#pragma unroll
  for (int m = 1; m <= 32; m <<= 1) ss += __shfl_xor(ss, m);
  float rs = rsqrtf(ss / 512.0f + 1e-6f);
  bf16x8 o;
#pragma unroll
  for (int e = 0; e < 8; ++e) o[e] = (bf16)((float)v[e] * rs * w[lane * 8 + e]);
  *reinterpret_cast<bf16x8*>(kvn + (size_t)row * 512 + lane * 8) = o;
  if (lane < 32) {
    int t = row & (TSEQ - 1);
    float x0 = (float)ip[512 + 2 * lane], x1 = (float)ip[512 + 2 * lane + 1];
    float c = rt[t * 64 + 2 * lane], s = rt[t * 64 + 2 * lane + 1];
    kr[(size_t)row * 64 + lane] = (bf16)(x0 * c - x1 * s);
    kr[(size_t)row * 64 + 32 + lane] = (bf16)(x1 * c + x0 * s);
  }
}

// q [MR][3072] (16 heads x 192); rope cols h*192+128..+191 -> qr [MR][16][64]
__global__ __launch_bounds__(256) void k_rope_q(const bf16* __restrict__ q,
                                                const float* __restrict__ rt,
                                                bf16* __restrict__ qr) {
  int idx = blockIdx.x * 256 + threadIdx.x;  // MR*16*32 total
  int j = idx & 31, h = (idx >> 5) & 15, row = idx >> 9;
  int t = row & (TSEQ - 1);
  const bf16* src = q + (size_t)row * 3072 + h * 192 + 128;
  float x0 = (float)src[2 * j], x1 = (float)src[2 * j + 1];
  float c = rt[t * 64 + 2 * j], s = rt[t * 64 + 2 * j + 1];
  bf16* dst = qr + ((size_t)row * 16 + h) * 64;
  dst[j] = (bf16)(x0 * c - x1 * s);
  dst[32 + j] = (bf16)(x1 * c + x0 * s);
}

// ---------------- GEMM: C[M][N] = A[M][K] @ Bt[N][K]^T ----------------
template <bool OUT_F32>
__global__ __launch_bounds__(256) void k_gemm_bt(const bf16* __restrict__ A,
                                                 const bf16* __restrict__ Bt,
                                                 void* __restrict__ C, int M,
                                                 int N, int K) {
  __shared__ bf16 As[128 * 32];
  __shared__ bf16 Bs[128 * 32];
  const int tid = threadIdx.x, lane = tid & 63, w = tid >> 6;
  const int wm = w >> 1, wn = w & 1;
  const int lg = lane >> 4, lr = lane & 15;
  const int m0 = blockIdx.y * 128, n0 = blockIdx.x * 128;
  f32x4 acc[4][4] = {};
  for (int k0 = 0; k0 < K; k0 += 32) {
    __syncthreads();
#pragma unroll
    for (int i = 0; i < 2; ++i) {
      int chunk = i * 256 + w * 64 + lane;
      int row = chunk >> 2, cc = chunk & 3;
      gload_lds16(A + (size_t)(m0 + row) * K + k0 + cc * 8,
                  (char*)As + (size_t)(i * 256 + w * 64) * 16);
      int nr = n0 + row;
      nr = nr < N ? nr : N - 1;  // clamp (garbage cols never stored)
      gload_lds16(Bt + (size_t)nr * K + k0 + cc * 8,
                  (char*)Bs + (size_t)(i * 256 + w * 64) * 16);
    }
    __syncthreads();
    bf16x8 af[4], bfr[4];
#pragma unroll
    for (int mi = 0; mi < 4; ++mi)
      af[mi] = *reinterpret_cast<const bf16x8*>(
          &As[(wm * 64 + mi * 16 + lr) * 32 + lg * 8]);
#pragma unroll
    for (int ni = 0; ni < 4; ++ni)
      bfr[ni] = *reinterpret_cast<const bf16x8*>(
          &Bs[(wn * 64 + ni * 16 + lr) * 32 + lg * 8]);
#pragma unroll
    for (int mi = 0; mi < 4; ++mi)
#pragma unroll
      for (int ni = 0; ni < 4; ++ni)
        acc[mi][ni] = mfma16(af[mi], bfr[ni], acc[mi][ni]);
  }
#pragma unroll
  for (int mi = 0; mi < 4; ++mi)
#pragma unroll
    for (int ni = 0; ni < 4; ++ni) {
      int col = n0 + wn * 64 + ni * 16 + lr;
      if (col < N) {
#pragma unroll
        for (int r = 0; r < 4; ++r) {
          int rowg = m0 + wm * 64 + mi * 16 + lg * 4 + r;
          if (OUT_F32)
            reinterpret_cast<float*>(C)[(size_t)rowg * N + col] = acc[mi][ni][r];
          else
            reinterpret_cast<bf16*>(C)[(size_t)rowg * N + col] =
                (bf16)acc[mi][ni][r];
        }
      }
    }
}

// ---------------- causal flash attention ----------------
// QBLK=128 (wave w owns rows q0+w*32..+31 = 2 subtiles), KBLK=64, 4 waves.
// grid (bh=32, qt'=16), qt = 15-qt' (LPT: big blocks dispatched first).
// T14 async staging: issue tile kt+1 global loads -> regs before computing
// tile kt from LDS; ds_write after the bottom barrier.
// S^T = mfma(A=K, B=Q^T); softmax lane-local + 2 shfl_xor (exp2 domain,
// scale*log2e folded into Q). P via swizzled wave-private LDS; V via
// fragment-packed swizzled LDS.
__global__ __launch_bounds__(256, 2) void k_attn(const bf16* __restrict__ q,
                                                 const bf16* __restrict__ qr,
                                                 const bf16* __restrict__ kv,
                                                 const bf16* __restrict__ kr,
                                                 bf16* __restrict__ o) {
  __shared__ bf16 Kn[64 * 128];   // XOR-swizzled: slot ^= (row&15)
  __shared__ bf16 Kr[64 * 64];    // XOR-swizzled: slot ^= (row&7)
  __shared__ bf16 Vs[8192];       // fragment-packed V^T
  __shared__ bf16 Ps[4 * 16 * 64];// per-wave P, swizzled: slot ^= (lr&7)
  const int tid = threadIdx.x, lane = tid & 63, w = tid >> 6;
  const int lg = lane >> 4, lr = lane & 15;
  const int bh = blockIdx.x, qt = 15 - blockIdx.y;
  const int b = bh >> 4, h = bh & 15;
  const int q0 = qt * 128;
  const size_t rowbase = (size_t)b * TSEQ;
  const int nkt = 2 * qt + 2;
  const float qsc = 0.07216878364870323f * 1.44269504088896f;  // 192^-.5 * log2e

  // Q fragments, scale folded in (exp2 softmax domain)
  bf16x8 qf[2][6];
#pragma unroll
  for (int s = 0; s < 2; ++s) {
    const int qg = q0 + w * 32 + s * 16 + lr;
    const bf16* qp = q + (rowbase + qg) * 3072 + h * 192;
#pragma unroll
    for (int dc = 0; dc < 4; ++dc) {
      bf16x8 v = *reinterpret_cast<const bf16x8*>(qp + dc * 32 + lg * 8);
#pragma unroll
      for (int e = 0; e < 8; ++e) v[e] = (bf16)((float)v[e] * qsc);
      qf[s][dc] = v;
    }
    const bf16* qrp = qr + ((rowbase + qg) * 16 + h) * 64;
#pragma unroll
    for (int dc = 0; dc < 2; ++dc) {
      bf16x8 v = *reinterpret_cast<const bf16x8*>(qrp + dc * 32 + lg * 8);
#pragma unroll
      for (int e = 0; e < 8; ++e) v[e] = (bf16)((float)v[e] * qsc);
      qf[s][4 + dc] = v;
    }
  }

  // staging registers (static indexing only)
  uint4 knreg[4], krreg[2], vreg[4];
  const int vkq = tid >> 4, vvc = tid & 15;  // V staging role

  auto load_tile = [&](int kbase) {
#pragma unroll
    for (int i = 0; i < 4; ++i) {
      int c = tid + i * 256;  // 0..1023
      int row = c >> 4, j = c & 15;
      knreg[i] = *reinterpret_cast<const uint4*>(
          kv + (rowbase + kbase + row) * 4096 + h * 256 + j * 8);
    }
#pragma unroll
    for (int i = 0; i < 2; ++i) {
      int c = tid + i * 256;  // 0..511
      int row = c >> 3, j = c & 7;
      krreg[i] = *reinterpret_cast<const uint4*>(
          kr + (rowbase + kbase + row) * 64 + j * 8);
    }
#pragma unroll
    for (int kk = 0; kk < 4; ++kk)
      vreg[kk] = *reinterpret_cast<const uint4*>(
          kv + (rowbase + kbase + vkq * 4 + kk) * 4096 + h * 256 + 128 + vvc * 8);
  };

  auto write_tile = [&]() {
#pragma unroll
    for (int i = 0; i < 4; ++i) {
      int c = tid + i * 256;
      int row = c >> 4, j = c & 15;
      *reinterpret_cast<uint4*>(&Kn[row * 128 + ((j ^ (row & 15)) * 8)]) =
          knreg[i];
    }
#pragma unroll
    for (int i = 0; i < 2; ++i) {
      int c = tid + i * 256;
      int row = c >> 3, j = c & 7;
      *reinterpret_cast<uint4*>(&Kr[row * 64 + ((j ^ (row & 7)) * 8)]) =
          krreg[i];
    }
    {
      const int kb0 = vkq * 4;
      const int cC = kb0 >> 5, g = (kb0 >> 3) & 3, j0 = kb0 & 7;
      uint32_t rd[4][4];
#pragma unroll
      for (int kk = 0; kk < 4; ++kk) {
        rd[kk][0] = vreg[kk].x; rd[kk][1] = vreg[kk].y;
        rd[kk][2] = vreg[kk].z; rd[kk][3] = vreg[kk].w;
      }
#pragma unroll
      for (int e = 0; e < 8; ++e) {
        uint32_t h0 = (rd[0][e >> 1] >> ((e & 1) * 16)) & 0xffffu;
        uint32_t h1 = (rd[1][e >> 1] >> ((e & 1) * 16)) & 0xffffu;
        uint32_t h2 = (rd[2][e >> 1] >> ((e & 1) * 16)) & 0xffffu;
        uint32_t h3 = (rd[3][e >> 1] >> ((e & 1) * 16)) & 0xffffu;
        int vd = vvc * 8 + e;
        int slot = (vd & 15) ^ g;
        uint2 wv = make_uint2(h0 | (h1 << 16), h2 | (h3 << 16));
        *reinterpret_cast<uint2*>(
            &Vs[((cC * 8 + (vd >> 4)) * 4 + g) * 128 + slot * 8 + j0]) = wv;
      }
    }
  };

  f32x4 oacc[2][8] = {};
  float m_run[2] = {-1e30f, -1e30f}, l_run[2] = {0.f, 0.f};

  // prologue: stage tile 0
  load_tile(0);
  write_tile();

  for (int kt = 0; kt < nkt; ++kt) {
    const int kbase = kt * 64;
    __syncthreads();  // LDS tile kt ready
    if (kt + 1 < nkt) load_tile((kt + 1) * 64);  // issue early (T14)

#pragma unroll
    for (int s = 0; s < 2; ++s) {
      if (kbase <= q0 + w * 32 + s * 16 + 15) {  // wave-uniform
        // S^T
        f32x4 sacc[4];
#pragma unroll
        for (int kb = 0; kb < 4; ++kb) {
          const int row = kb * 16 + lr;
          f32x4 sa = {0.f, 0.f, 0.f, 0.f};
#pragma unroll
          for (int dc = 0; dc < 4; ++dc) {
            bf16x8 kf = *reinterpret_cast<const bf16x8*>(
                &Kn[row * 128 + (((dc * 4 + lg) ^ (row & 15)) * 8)]);
            sa = mfma16(kf, qf[s][dc], sa);
          }
#pragma unroll
          for (int dc = 0; dc < 2; ++dc) {
            bf16x8 kf = *reinterpret_cast<const bf16x8*>(
                &Kr[row * 64 + (((dc * 4 + lg) ^ (row & 7)) * 8)]);
            sa = mfma16(kf, qf[s][4 + dc], sa);
          }
          sacc[kb] = sa;
        }
        // online softmax (exp2 domain)
        const int qg = q0 + w * 32 + s * 16 + lr;
        float sv[4][4];
        float pmax = -1e30f;
#pragma unroll
        for (int kb = 0; kb < 4; ++kb)
#pragma unroll
          for (int r = 0; r < 4; ++r) {
            int kgl = kbase + kb * 16 + lg * 4 + r;
            float val = (kgl <= qg) ? sacc[kb][r] : -1e30f;
            sv[kb][r] = val;
            pmax = fmaxf(pmax, val);
          }
        pmax = fmaxf(pmax, __shfl_xor(pmax, 16));
        pmax = fmaxf(pmax, __shfl_xor(pmax, 32));
        float mnew = fmaxf(m_run[s], pmax);
        float alpha = exp2f(m_run[s] - mnew);
        float ls = 0.f;
#pragma unroll
        for (int kb = 0; kb < 4; ++kb) {
          bf16x4v pw;
#pragma unroll
          for (int r = 0; r < 4; ++r) {
            float p = exp2f(sv[kb][r] - mnew);
            ls += p;
            pw[r] = (bf16)p;
          }
          *reinterpret_cast<bf16x4v*>(
              &Ps[w * 1024 + lr * 64 +
                  (((kb * 2 + (lg >> 1)) ^ (lr & 7)) * 8) + (lg & 1) * 4]) = pw;
        }
        ls += __shfl_xor(ls, 16);
        ls += __shfl_xor(ls, 32);
        l_run[s] = l_run[s] * alpha + ls;
        m_run[s] = mnew;
#pragma unroll
        for (int vb = 0; vb < 8; ++vb) {
          oacc[s][vb][0] *= alpha; oacc[s][vb][1] *= alpha;
          oacc[s][vb][2] *= alpha; oacc[s][vb][3] *= alpha;
        }
        // PV: O^T += V^T @ P^T
#pragma unroll
        for (int c = 0; c < 2; ++c) {
          bf16x8 pb = *reinterpret_cast<const bf16x8*>(
              &Ps[w * 1024 + lr * 64 + (((c * 4 + lg) ^ (lr & 7)) * 8)]);
#pragma unroll
          for (int vb = 0; vb < 8; ++vb) {
            bf16x8 av = *reinterpret_cast<const bf16x8*>(
                &Vs[((c * 8 + vb) * 4 + lg) * 128 + (lr ^ lg) * 8]);
            oacc[s][vb] = mfma16(av, pb, oacc[s][vb]);
          }
        }
      }
    }
    __syncthreads();  // all reads of tile kt done
    if (kt + 1 < nkt) write_tile();
  }

  // epilogue: lane holds O^T[vd = vb*16+lg*4+r][q = qg]
#pragma unroll
  for (int s = 0; s < 2; ++s) {
    const int qg = q0 + w * 32 + s * 16 + lr;
    float inv = 1.0f / l_run[s];
    bf16* op = o + (rowbase + qg) * 2048 + h * 128;
#pragma unroll
    for (int vb = 0; vb < 8; ++vb) {
      bf16x4v ov;
#pragma unroll
      for (int r = 0; r < 4; ++r) ov[r] = (bf16)(oacc[s][vb][r] * inv);
      *reinterpret_cast<bf16x4v*>(op + vb * 16 + lg * 4) = ov;
    }
  }
}

// ---------------- launch ----------------
extern "C" void kernel_launch(void* const* d_in, const int* in_sizes, int n_in,
                              void* d_out, int out_size, void* d_ws,
                              size_t ws_size, hipStream_t stream) {
  (void)in_sizes; (void)n_in; (void)out_size; (void)ws_size;
  const float* x       = (const float*)d_in[0];
  const float* q_a_w   = (const float*)d_in[1];
  const float* q_a_ln  = (const float*)d_in[2];
  const float* q_b_w   = (const float*)d_in[3];
  const float* kv_a_w  = (const float*)d_in[4];
  const float* kv_a_ln = (const float*)d_in[5];
  const float* kv_b_w  = (const float*)d_in[6];
  const float* o_w     = (const float*)d_in[7];

  char* ws = (char*)d_ws;
  size_t off = 0;
  auto alloc = [&](size_t bytes) {
    void* p = ws + off;
    off += (bytes + 255) & ~(size_t)255;
    return p;
  };
  bf16* x_bf   = (bf16*)alloc((size_t)MR * 2048 * 2);
  bf16* qa_wt  = (bf16*)alloc((size_t)1536 * 2048 * 2);
  bf16* qb_wt  = (bf16*)alloc((size_t)3072 * 1536 * 2);
  bf16* kva_wt = (bf16*)alloc((size_t)576 * 2048 * 2);
  bf16* kvb_wt = (bf16*)alloc((size_t)4096 * 512 * 2);
  bf16* o_wt   = (bf16*)alloc((size_t)2048 * 2048 * 2);
  float* rt    = (float*)alloc((size_t)2048 * 64 * 4);
  bf16* q_a    = (bf16*)alloc((size_t)MR * 1536 * 2);
  bf16* q_a_n  = (bf16*)alloc((size_t)MR * 1536 * 2);
  bf16* ckv    = (bf16*)alloc((size_t)MR * 576 * 2);
  bf16* kv_c_n = (bf16*)alloc((size_t)MR * 512 * 2);
  bf16* kr     = (bf16*)alloc((size_t)MR * 64 * 2);
  bf16* qbuf   = (bf16*)alloc((size_t)MR * 3072 * 2);
  bf16* qr     = (bf16*)alloc((size_t)MR * 16 * 64 * 2);
  bf16* kvbuf  = (bf16*)alloc((size_t)MR * 4096 * 2);
  bf16* attn_o = (bf16*)alloc((size_t)MR * 2048 * 2);

  k_cvt_bf16<<<8192, 256, 0, stream>>>(x, x_bf);
  k_transpose<<<dim3(1536 / 32, 2048 / 32), 256, 0, stream>>>(q_a_w, qa_wt, 2048, 1536);
  k_transpose<<<dim3(3072 / 32, 1536 / 32), 256, 0, stream>>>(q_b_w, qb_wt, 1536, 3072);
  k_transpose<<<dim3(576 / 32, 2048 / 32), 256, 0, stream>>>(kv_a_w, kva_wt, 2048, 576);
  k_transpose<<<dim3(4096 / 32, 512 / 32), 256, 0, stream>>>(kv_b_w, kvb_wt, 512, 4096);
  k_transpose<<<dim3(2048 / 32, 2048 / 32), 256, 0, stream>>>(o_w, o_wt, 2048, 2048);
  k_rope_table<<<1024, 64, 0, stream>>>(rt);

  k_gemm_bt<false><<<dim3(12, 32), 256, 0, stream>>>(x_bf, qa_wt, q_a, MR, 1536, 2048);
  k_gemm_bt<false><<<dim3(5, 32), 256, 0, stream>>>(x_bf, kva_wt, ckv, MR, 576, 2048);
  k_rmsnorm<3><<<MR, 64, 0, stream>>>(q_a, q_a_ln, q_a_n, 1536);
  k_kv_norm_rope<<<MR, 64, 0, stream>>>(ckv, kv_a_ln, rt, kv_c_n, kr);
  k_gemm_bt<false><<<dim3(24, 32), 256, 0, stream>>>(q_a_n, qb_wt, qbuf, MR, 3072, 1536);
  k_rope_q<<<8192, 256, 0, stream>>>(qbuf, rt, qr);
  k_gemm_bt<false><<<dim3(32, 32), 256, 0, stream>>>(kv_c_n, kvb_wt, kvbuf, MR, 4096, 512);
  k_attn<<<dim3(32, 16), 256, 0, stream>>>(qbuf, qr, kvbuf, kr, attn_o);
  k_gemm_bt<true><<<dim3(16, 32), 256, 0, stream>>>(attn_o, o_wt, d_out, MR, 2048, 2048);
}

// Round 3
// 446.831 us; speedup vs baseline: 1.3758x; 1.1287x over previous
//
#include <hip/hip_runtime.h>
#include <hip/hip_bf16.h>
#include <cstdint>

// MLA: B=2, T=2048, H=16, d_nope=128, d_rope=64, d_qk=192, d_v=128,
// kv_lora=512, q_lora=1536, hidden=2048. Output f32 [4096][2048].

typedef __bf16 bf16;
typedef __bf16 bf16x8 __attribute__((ext_vector_type(8)));
typedef __bf16 bf16x4v __attribute__((ext_vector_type(4)));
typedef float f32x4 __attribute__((ext_vector_type(4)));

#define TSEQ 2048
#define MR 4096  // B*T

typedef const uint32_t __attribute__((address_space(1))) * gas1_t;
typedef uint32_t __attribute__((address_space(3))) * las3_t;

static __device__ __forceinline__ void gload_lds16(const void* g, void* l) {
  __builtin_amdgcn_global_load_lds(
      reinterpret_cast<gas1_t>(reinterpret_cast<uintptr_t>(g)),
      reinterpret_cast<las3_t>(reinterpret_cast<uintptr_t>(l)), 16, 0, 0);
}

static __device__ __forceinline__ f32x4 mfma16(bf16x8 a, bf16x8 b, f32x4 c) {
  return __builtin_amdgcn_mfma_f32_16x16x32_bf16(a, b, c, 0, 0, 0);
}

// ---------------- prep kernels ----------------

__global__ __launch_bounds__(256) void k_cvt_bf16(const float* __restrict__ in,
                                                  bf16* __restrict__ out) {
  int i = blockIdx.x * 256 + threadIdx.x;
  float4 f = reinterpret_cast<const float4*>(in)[i];
  bf16x4v o = {(bf16)f.x, (bf16)f.y, (bf16)f.z, (bf16)f.w};
  reinterpret_cast<bf16x4v*>(out)[i] = o;
}

// W [K][N] f32 -> Wt [N][K] bf16 (K, N multiples of 32)
__global__ __launch_bounds__(256) void k_transpose(const float* __restrict__ W,
                                                   bf16* __restrict__ Wt,
                                                   int K, int N) {
  __shared__ float t[32][33];
  int bi = blockIdx.x, bj = blockIdx.y;
  int c = threadIdx.x & 31, r0 = threadIdx.x >> 5;
#pragma unroll
  for (int rr = 0; rr < 32; rr += 8)
    t[rr + r0][c] = W[(size_t)(bj * 32 + rr + r0) * N + bi * 32 + c];
  __syncthreads();
#pragma unroll
  for (int rr = 0; rr < 32; rr += 8)
    Wt[(size_t)(bi * 32 + rr + r0) * K + bj * 32 + c] = (bf16)t[c][rr + r0];
}

// rt[t][j] = {cos, sin}(t * theta^(-j/32)), t<2048, j<32
__global__ __launch_bounds__(64) void k_rope_table(float* __restrict__ rt) {
  int t = blockIdx.x * 2 + (threadIdx.x >> 5);
  int j = threadIdx.x & 31;
  float freq = exp2f(-(float)j * (1.0f / 32.0f) * log2f(500000.0f));
  float ang = (float)t * freq;
  rt[t * 64 + 2 * j] = cosf(ang);
  rt[t * 64 + 2 * j + 1] = sinf(ang);
}

template <int NCH>  // D = NCH*512, one wave per row
__global__ __launch_bounds__(64) void k_rmsnorm(const bf16* __restrict__ in,
                                                const float* __restrict__ w,
                                                bf16* __restrict__ out, int D) {
  int row = blockIdx.x, lane = threadIdx.x;
  const bf16* ip = in + (size_t)row * D;
  bf16x8 v[NCH];
  float ss = 0.f;
#pragma unroll
  for (int c = 0; c < NCH; ++c) {
    v[c] = *reinterpret_cast<const bf16x8*>(ip + c * 512 + lane * 8);
#pragma unroll
    for (int e = 0; e < 8; ++e) { float f = (float)v[c][e]; ss += f * f; }
  }
#pragma unroll
  for (int m = 1; m <= 32; m <<= 1) ss += __shfl_xor(ss, m);
  float rs = rsqrtf(ss / (float)D + 1e-6f);
  bf16* op = out + (size_t)row * D;
#pragma unroll
  for (int c = 0; c < NCH; ++c) {
    bf16x8 o;
#pragma unroll
    for (int e = 0; e < 8; ++e)
      o[e] = (bf16)((float)v[c][e] * rs * w[c * 512 + lane * 8 + e]);
    *reinterpret_cast<bf16x8*>(op + c * 512 + lane * 8) = o;
  }
}

// ckv [MR][576]: rmsnorm cols 0..511 -> kvn [MR][512]; rope cols 512..575 -> kr [MR][64]
__global__ __launch_bounds__(64) void k_kv_norm_rope(
    const bf16* __restrict__ ckv, const float* __restrict__ w,
    const float* __restrict__ rt, bf16* __restrict__ kvn,
    bf16* __restrict__ kr) {
  int row = blockIdx.x, lane = threadIdx.x;
  const bf16* ip = ckv + (size_t)row * 576;
  bf16x8 v = *reinterpret_cast<const bf16x8*>(ip + lane * 8);
  float ss = 0.f;
#pragma unroll
  for (int e = 0; e < 8; ++e) { float f = (float)v[e]; ss += f * f; }
#pragma unroll
  for (int m = 1; m <= 32; m <<= 1) ss += __shfl_xor(ss, m);
  float rs = rsqrtf(ss / 512.0f + 1e-6f);
  bf16x8 o;
#pragma unroll
  for (int e = 0; e < 8; ++e) o[e] = (bf16)((float)v[e] * rs * w[lane * 8 + e]);
  *reinterpret_cast<bf16x8*>(kvn + (size_t)row * 512 + lane * 8) = o;
  if (lane < 32) {
    int t = row & (TSEQ - 1);
    float x0 = (float)ip[512 + 2 * lane], x1 = (float)ip[512 + 2 * lane + 1];
    float c = rt[t * 64 + 2 * lane], s = rt[t * 64 + 2 * lane + 1];
    kr[(size_t)row * 64 + lane] = (bf16)(x0 * c - x1 * s);
    kr[(size_t)row * 64 + 32 + lane] = (bf16)(x1 * c + x0 * s);
  }
}

// q [MR][3072] (16 heads x 192); rope cols h*192+128..+191 -> qr [MR][16][64]
__global__ __launch_bounds__(256) void k_rope_q(const bf16* __restrict__ q,
                                                const float* __restrict__ rt,
                                                bf16* __restrict__ qr) {
  int idx = blockIdx.x * 256 + threadIdx.x;  // MR*16*32 total
  int j = idx & 31, h = (idx >> 5) & 15, row = idx >> 9;
  int t = row & (TSEQ - 1);
  const bf16* src = q + (size_t)row * 3072 + h * 192 + 128;
  float x0 = (float)src[2 * j], x1 = (float)src[2 * j + 1];
  float c = rt[t * 64 + 2 * j], s = rt[t * 64 + 2 * j + 1];
  bf16* dst = qr + ((size_t)row * 16 + h) * 64;
  dst[j] = (bf16)(x0 * c - x1 * s);
  dst[32 + j] = (bf16)(x1 * c + x0 * s);
}

// ---------------- GEMM: C[M][N] = A[M][K] @ Bt[N][K]^T ----------------
template <bool OUT_F32>
__global__ __launch_bounds__(256) void k_gemm_bt(const bf16* __restrict__ A,
                                                 const bf16* __restrict__ Bt,
                                                 void* __restrict__ C, int M,
                                                 int N, int K) {
  __shared__ bf16 As[128 * 32];
  __shared__ bf16 Bs[128 * 32];
  const int tid = threadIdx.x, lane = tid & 63, w = tid >> 6;
  const int wm = w >> 1, wn = w & 1;
  const int lg = lane >> 4, lr = lane & 15;
  const int m0 = blockIdx.y * 128, n0 = blockIdx.x * 128;
  f32x4 acc[4][4] = {};
  for (int k0 = 0; k0 < K; k0 += 32) {
    __syncthreads();
#pragma unroll
    for (int i = 0; i < 2; ++i) {
      int chunk = i * 256 + w * 64 + lane;
      int row = chunk >> 2, cc = chunk & 3;
      gload_lds16(A + (size_t)(m0 + row) * K + k0 + cc * 8,
                  (char*)As + (size_t)(i * 256 + w * 64) * 16);
      int nr = n0 + row;
      nr = nr < N ? nr : N - 1;  // clamp (garbage cols never stored)
      gload_lds16(Bt + (size_t)nr * K + k0 + cc * 8,
                  (char*)Bs + (size_t)(i * 256 + w * 64) * 16);
    }
    __syncthreads();
    bf16x8 af[4], bfr[4];
#pragma unroll
    for (int mi = 0; mi < 4; ++mi)
      af[mi] = *reinterpret_cast<const bf16x8*>(
          &As[(wm * 64 + mi * 16 + lr) * 32 + lg * 8]);
#pragma unroll
    for (int ni = 0; ni < 4; ++ni)
      bfr[ni] = *reinterpret_cast<const bf16x8*>(
          &Bs[(wn * 64 + ni * 16 + lr) * 32 + lg * 8]);
#pragma unroll
    for (int mi = 0; mi < 4; ++mi)
#pragma unroll
      for (int ni = 0; ni < 4; ++ni)
        acc[mi][ni] = mfma16(af[mi], bfr[ni], acc[mi][ni]);
  }
#pragma unroll
  for (int mi = 0; mi < 4; ++mi)
#pragma unroll
    for (int ni = 0; ni < 4; ++ni) {
      int col = n0 + wn * 64 + ni * 16 + lr;
      if (col < N) {
#pragma unroll
        for (int r = 0; r < 4; ++r) {
          int rowg = m0 + wm * 64 + mi * 16 + lg * 4 + r;
          if (OUT_F32)
            reinterpret_cast<float*>(C)[(size_t)rowg * N + col] = acc[mi][ni][r];
          else
            reinterpret_cast<bf16*>(C)[(size_t)rowg * N + col] =
                (bf16)acc[mi][ni][r];
        }
      }
    }
}

// ---------------- causal flash attention v3 ----------------
// QBLK=128 (wave w owns rows q0+w*32..+31), KBLK=64, 4 waves.
// K staged via global_load_lds with PRE-SWIZZLED global source (linear LDS
// dest, XOR-swizzled read), double-buffered -> loads fly during compute.
// V reg-staged (genuine 2B transpose), written after barrier 1 (T14).
// K fragments read once per kb, shared across both s-subtiles.
// Epilogue through LDS for fully-coalesced b128 stores.
__global__ __launch_bounds__(256, 2) void k_attn(const bf16* __restrict__ q,
                                                 const bf16* __restrict__ qr,
                                                 const bf16* __restrict__ kv,
                                                 const bf16* __restrict__ kr,
                                                 bf16* __restrict__ o) {
  __shared__ bf16 Kn[2][64 * 128];  // linear chunks; data col = j^(row&15)
  __shared__ bf16 Kr[2][64 * 64];   // data col = j^(row&7)
  __shared__ bf16 Vs[8192];         // fragment-packed V^T
  __shared__ bf16 Ps[4 * 1024];     // per-wave P (one s at a time)
  const int tid = threadIdx.x, lane = tid & 63, w = tid >> 6;
  const int lg = lane >> 4, lr = lane & 15;
  const int bh = blockIdx.x, qt = 15 - blockIdx.y;
  const int b = bh >> 4, h = bh & 15;
  const int q0 = qt * 128;
  const size_t rowbase = (size_t)b * TSEQ;
  const int nkt = 2 * qt + 2;
  const float qsc = 0.07216878364870323f * 1.44269504088896f;  // 192^-.5*log2e

  // Q fragments, scale folded in (exp2 softmax domain)
  bf16x8 qf[2][6];
#pragma unroll
  for (int s = 0; s < 2; ++s) {
    const int qg = q0 + w * 32 + s * 16 + lr;
    const bf16* qp = q + (rowbase + qg) * 3072 + h * 192;
#pragma unroll
    for (int dc = 0; dc < 4; ++dc) {
      bf16x8 v = *reinterpret_cast<const bf16x8*>(qp + dc * 32 + lg * 8);
#pragma unroll
      for (int e = 0; e < 8; ++e) v[e] = (bf16)((float)v[e] * qsc);
      qf[s][dc] = v;
    }
    const bf16* qrp = qr + ((rowbase + qg) * 16 + h) * 64;
#pragma unroll
    for (int dc = 0; dc < 2; ++dc) {
      bf16x8 v = *reinterpret_cast<const bf16x8*>(qrp + dc * 32 + lg * 8);
#pragma unroll
      for (int e = 0; e < 8; ++e) v[e] = (bf16)((float)v[e] * qsc);
      qf[s][4 + dc] = v;
    }
  }

  uint4 vreg[4];
  const int vkq = tid >> 4, vvc = tid & 15;  // V staging role

  auto issue_loads = [&](int kbase, int buf) {
    // V -> regs (issued first; waited together with K by vmcnt(0))
#pragma unroll
    for (int kk = 0; kk < 4; ++kk)
      vreg[kk] = *reinterpret_cast<const uint4*>(
          kv + (rowbase + kbase + vkq * 4 + kk) * 4096 + h * 256 + 128 + vvc * 8);
    // Kn: 4 x global_load_lds, source col pre-swizzled
#pragma unroll
    for (int i = 0; i < 4; ++i) {
      int c = i * 256 + tid;
      int row = c >> 4, j = c & 15;
      gload_lds16(
          kv + (rowbase + kbase + row) * 4096 + h * 256 + ((j ^ (row & 15)) * 8),
          (char*)&Kn[buf][0] + (size_t)(i * 256 + w * 64) * 16);
    }
    // Kr: 2 x global_load_lds
#pragma unroll
    for (int i = 0; i < 2; ++i) {
      int c = i * 256 + tid;
      int row = c >> 3, j = c & 7;
      gload_lds16(kr + (rowbase + kbase + row) * 64 + ((j ^ (row & 7)) * 8),
                  (char*)&Kr[buf][0] + (size_t)(i * 256 + w * 64) * 16);
    }
  };

  auto write_vs = [&]() {
    const int kb0 = vkq * 4;
    const int cC = kb0 >> 5, g = (kb0 >> 3) & 3, j0 = kb0 & 7;
    uint32_t rd[4][4];
#pragma unroll
    for (int kk = 0; kk < 4; ++kk) {
      rd[kk][0] = vreg[kk].x; rd[kk][1] = vreg[kk].y;
      rd[kk][2] = vreg[kk].z; rd[kk][3] = vreg[kk].w;
    }
#pragma unroll
    for (int e = 0; e < 8; ++e) {
      uint32_t h0 = (rd[0][e >> 1] >> ((e & 1) * 16)) & 0xffffu;
      uint32_t h1 = (rd[1][e >> 1] >> ((e & 1) * 16)) & 0xffffu;
      uint32_t h2 = (rd[2][e >> 1] >> ((e & 1) * 16)) & 0xffffu;
      uint32_t h3 = (rd[3][e >> 1] >> ((e & 1) * 16)) & 0xffffu;
      int vd = vvc * 8 + e;
      int slot = (vd & 15) ^ g;
      uint2 wv = make_uint2(h0 | (h1 << 16), h2 | (h3 << 16));
      *reinterpret_cast<uint2*>(
          &Vs[((cC * 8 + (vd >> 4)) * 4 + g) * 128 + slot * 8 + j0]) = wv;
    }
  };

  f32x4 oacc[2][8] = {};
  float m_run[2] = {-1e30f, -1e30f}, l_run[2] = {0.f, 0.f};

  // prologue: stage tile 0
  issue_loads(0, 0);
  asm volatile("s_waitcnt vmcnt(0)");
  write_vs();
  __syncthreads();

  for (int kt = 0; kt < nkt; ++kt) {
    const int kbase = kt * 64;
    const int buf = kt & 1;
    const bool more = (kt + 1 < nkt);
    if (more) issue_loads((kt + 1) * 64, buf ^ 1);

    if (kbase <= q0 + w * 32 + 31) {  // wave-uniform
      // ---- S^T: K frags once per kb, shared across both s ----
      f32x4 sacc[2][4];
#pragma unroll
      for (int kb = 0; kb < 4; ++kb) {
        const int row = kb * 16 + lr;
        bf16x8 kf[6];
#pragma unroll
        for (int dc = 0; dc < 4; ++dc)
          kf[dc] = *reinterpret_cast<const bf16x8*>(
              &Kn[buf][row * 128 + (((dc * 4 + lg) ^ (row & 15)) * 8)]);
#pragma unroll
        for (int dc = 0; dc < 2; ++dc)
          kf[4 + dc] = *reinterpret_cast<const bf16x8*>(
              &Kr[buf][row * 64 + (((dc * 4 + lg) ^ (row & 7)) * 8)]);
        __builtin_amdgcn_s_setprio(1);
#pragma unroll
        for (int s = 0; s < 2; ++s) {
          f32x4 sa = {0.f, 0.f, 0.f, 0.f};
#pragma unroll
          for (int dc = 0; dc < 6; ++dc) sa = mfma16(kf[dc], qf[s][dc], sa);
          sacc[s][kb] = sa;
        }
        __builtin_amdgcn_s_setprio(0);
      }
      // ---- per-s: softmax + PV ----
#pragma unroll
      for (int s = 0; s < 2; ++s) {
        const int qg = q0 + w * 32 + s * 16 + lr;
        float sv[4][4];
        float pmax = -1e30f;
#pragma unroll
        for (int kb = 0; kb < 4; ++kb)
#pragma unroll
          for (int r = 0; r < 4; ++r) {
            int kgl = kbase + kb * 16 + lg * 4 + r;
            float val = (kgl <= qg) ? sacc[s][kb][r] : -1e30f;
            sv[kb][r] = val;
            pmax = fmaxf(pmax, val);
          }
        pmax = fmaxf(pmax, __shfl_xor(pmax, 16));
        pmax = fmaxf(pmax, __shfl_xor(pmax, 32));
        float mnew = fmaxf(m_run[s], pmax);
        float alpha = exp2f(m_run[s] - mnew);
        float ls = 0.f;
#pragma unroll
        for (int kb = 0; kb < 4; ++kb) {
          bf16x4v pw;
#pragma unroll
          for (int r = 0; r < 4; ++r) {
            float p = exp2f(sv[kb][r] - mnew);
            ls += p;
            pw[r] = (bf16)p;
          }
          *reinterpret_cast<bf16x4v*>(
              &Ps[w * 1024 + lr * 64 +
                  (((kb * 2 + (lg >> 1)) ^ (lr & 7)) * 8) + (lg & 1) * 4]) = pw;
        }
        ls += __shfl_xor(ls, 16);
        ls += __shfl_xor(ls, 32);
        l_run[s] = l_run[s] * alpha + ls;
        m_run[s] = mnew;
#pragma unroll
        for (int vb = 0; vb < 8; ++vb) {
          oacc[s][vb][0] *= alpha; oacc[s][vb][1] *= alpha;
          oacc[s][vb][2] *= alpha; oacc[s][vb][3] *= alpha;
        }
#pragma unroll
        for (int c = 0; c < 2; ++c) {
          bf16x8 pb = *reinterpret_cast<const bf16x8*>(
              &Ps[w * 1024 + lr * 64 + (((c * 4 + lg) ^ (lr & 7)) * 8)]);
          __builtin_amdgcn_s_setprio(1);
#pragma unroll
          for (int vb = 0; vb < 8; ++vb) {
            bf16x8 av = *reinterpret_cast<const bf16x8*>(
                &Vs[((c * 8 + vb) * 4 + lg) * 128 + (lr ^ lg) * 8]);
            oacc[s][vb] = mfma16(av, pb, oacc[s][vb]);
          }
          __builtin_amdgcn_s_setprio(0);
        }
      }
    }
    __syncthreads();  // Vs/Ps reads of tile kt done
    if (more) {
      asm volatile("s_waitcnt vmcnt(0)");  // K glds + V regs landed
      write_vs();
    }
    __syncthreads();  // Vs(kt+1) + Kn/Kr(kt+1) visible
  }

  // ---- epilogue via LDS (Kn is free) -> coalesced b128 stores ----
  bf16* Os = &Kn[0][0] + w * 4096;  // 32 rows x 128 cols per wave
#pragma unroll
  for (int s = 0; s < 2; ++s) {
    float inv = 1.0f / l_run[s];
    const int row = s * 16 + lr;
#pragma unroll
    for (int vb = 0; vb < 8; ++vb) {
      bf16x4v ov;
#pragma unroll
      for (int r = 0; r < 4; ++r) ov[r] = (bf16)(oacc[s][vb][r] * inv);
      int slot16 = vb * 2 + (lg >> 1);
      *reinterpret_cast<bf16x4v*>(
          &Os[row * 128 + ((slot16 ^ (lr & 7)) * 8) + (lg & 1) * 4]) = ov;
    }
  }
  asm volatile("s_waitcnt lgkmcnt(0)");
  __builtin_amdgcn_sched_barrier(0);
#pragma unroll
  for (int i = 0; i < 8; ++i) {
    const int r = i * 4 + lg;  // 0..31
    bf16x8 ov = *reinterpret_cast<const bf16x8*>(
        &Os[r * 128 + ((lr ^ (r & 7)) * 8)]);
    *reinterpret_cast<bf16x8*>(
        o + (rowbase + q0 + w * 32 + r) * 2048 + h * 128 + lr * 8) = ov;
  }
}

// ---------------- launch ----------------
extern "C" void kernel_launch(void* const* d_in, const int* in_sizes, int n_in,
                              void* d_out, int out_size, void* d_ws,
                              size_t ws_size, hipStream_t stream) {
  (void)in_sizes; (void)n_in; (void)out_size; (void)ws_size;
  const float* x       = (const float*)d_in[0];
  const float* q_a_w   = (const float*)d_in[1];
  const float* q_a_ln  = (const float*)d_in[2];
  const float* q_b_w   = (const float*)d_in[3];
  const float* kv_a_w  = (const float*)d_in[4];
  const float* kv_a_ln = (const float*)d_in[5];
  const float* kv_b_w  = (const float*)d_in[6];
  const float* o_w     = (const float*)d_in[7];

  char* ws = (char*)d_ws;
  size_t off = 0;
  auto alloc = [&](size_t bytes) {
    void* p = ws + off;
    off += (bytes + 255) & ~(size_t)255;
    return p;
  };
  bf16* x_bf   = (bf16*)alloc((size_t)MR * 2048 * 2);
  bf16* qa_wt  = (bf16*)alloc((size_t)1536 * 2048 * 2);
  bf16* qb_wt  = (bf16*)alloc((size_t)3072 * 1536 * 2);
  bf16* kva_wt = (bf16*)alloc((size_t)576 * 2048 * 2);
  bf16* kvb_wt = (bf16*)alloc((size_t)4096 * 512 * 2);
  bf16* o_wt   = (bf16*)alloc((size_t)2048 * 2048 * 2);
  float* rt    = (float*)alloc((size_t)2048 * 64 * 4);
  bf16* q_a    = (bf16*)alloc((size_t)MR * 1536 * 2);
  bf16* q_a_n  = (bf16*)alloc((size_t)MR * 1536 * 2);
  bf16* ckv    = (bf16*)alloc((size_t)MR * 576 * 2);
  bf16* kv_c_n = (bf16*)alloc((size_t)MR * 512 * 2);
  bf16* kr     = (bf16*)alloc((size_t)MR * 64 * 2);
  bf16* qbuf   = (bf16*)alloc((size_t)MR * 3072 * 2);
  bf16* qr     = (bf16*)alloc((size_t)MR * 16 * 64 * 2);
  bf16* kvbuf  = (bf16*)alloc((size_t)MR * 4096 * 2);
  bf16* attn_o = (bf16*)alloc((size_t)MR * 2048 * 2);

  k_cvt_bf16<<<8192, 256, 0, stream>>>(x, x_bf);
  k_transpose<<<dim3(1536 / 32, 2048 / 32), 256, 0, stream>>>(q_a_w, qa_wt, 2048, 1536);
  k_transpose<<<dim3(3072 / 32, 1536 / 32), 256, 0, stream>>>(q_b_w, qb_wt, 1536, 3072);
  k_transpose<<<dim3(576 / 32, 2048 / 32), 256, 0, stream>>>(kv_a_w, kva_wt, 2048, 576);
  k_transpose<<<dim3(4096 / 32, 512 / 32), 256, 0, stream>>>(kv_b_w, kvb_wt, 512, 4096);
  k_transpose<<<dim3(2048 / 32, 2048 / 32), 256, 0, stream>>>(o_w, o_wt, 2048, 2048);
  k_rope_table<<<1024, 64, 0, stream>>>(rt);

  k_gemm_bt<false><<<dim3(12, 32), 256, 0, stream>>>(x_bf, qa_wt, q_a, MR, 1536, 2048);
  k_gemm_bt<false><<<dim3(5, 32), 256, 0, stream>>>(x_bf, kva_wt, ckv, MR, 576, 2048);
  k_rmsnorm<3><<<MR, 64, 0, stream>>>(q_a, q_a_ln, q_a_n, 1536);
  k_kv_norm_rope<<<MR, 64, 0, stream>>>(ckv, kv_a_ln, rt, kv_c_n, kr);
  k_gemm_bt<false><<<dim3(24, 32), 256, 0, stream>>>(q_a_n, qb_wt, qbuf, MR, 3072, 1536);
  k_rope_q<<<8192, 256, 0, stream>>>(qbuf, rt, qr);
  k_gemm_bt<false><<<dim3(32, 32), 256, 0, stream>>>(kv_c_n, kvb_wt, kvbuf, MR, 4096, 512);
  k_attn<<<dim3(32, 16), 256, 0, stream>>>(qbuf, qr, kvbuf, kr, attn_o);
  k_gemm_bt<true><<<dim3(16, 32), 256, 0, stream>>>(attn_o, o_wt, d_out, MR, 2048, 2048);
}

// Round 4
// 403.851 us; speedup vs baseline: 1.5223x; 1.1064x over previous
//
#include <hip/hip_runtime.h>
#include <hip/hip_bf16.h>
#include <cstdint>

// MLA: B=2, T=2048, H=16, d_nope=128, d_rope=64, d_qk=192, d_v=128,
// kv_lora=512, q_lora=1536, hidden=2048. Output f32 [4096][2048].

typedef __bf16 bf16;
typedef __bf16 bf16x8 __attribute__((ext_vector_type(8)));
typedef __bf16 bf16x4v __attribute__((ext_vector_type(4)));
typedef float f32x4 __attribute__((ext_vector_type(4)));

#define TSEQ 2048
#define MR 4096  // B*T

typedef const uint32_t __attribute__((address_space(1))) * gas1_t;
typedef uint32_t __attribute__((address_space(3))) * las3_t;

static __device__ __forceinline__ void gload_lds16(const void* g, void* l) {
  __builtin_amdgcn_global_load_lds(
      reinterpret_cast<gas1_t>(reinterpret_cast<uintptr_t>(g)),
      reinterpret_cast<las3_t>(reinterpret_cast<uintptr_t>(l)), 16, 0, 0);
}

static __device__ __forceinline__ f32x4 mfma16(bf16x8 a, bf16x8 b, f32x4 c) {
  return __builtin_amdgcn_mfma_f32_16x16x32_bf16(a, b, c, 0, 0, 0);
}

// ---------------- prep kernels ----------------

__global__ __launch_bounds__(256) void k_cvt_bf16(const float* __restrict__ in,
                                                  bf16* __restrict__ out) {
  int i = blockIdx.x * 256 + threadIdx.x;
  float4 f = reinterpret_cast<const float4*>(in)[i];
  bf16x4v o = {(bf16)f.x, (bf16)f.y, (bf16)f.z, (bf16)f.w};
  reinterpret_cast<bf16x4v*>(out)[i] = o;
}

// W [K][N] f32 -> Wt [N][K] bf16 (K, N multiples of 32)
__global__ __launch_bounds__(256) void k_transpose(const float* __restrict__ W,
                                                   bf16* __restrict__ Wt,
                                                   int K, int N) {
  __shared__ float t[32][33];
  int bi = blockIdx.x, bj = blockIdx.y;
  int c = threadIdx.x & 31, r0 = threadIdx.x >> 5;
#pragma unroll
  for (int rr = 0; rr < 32; rr += 8)
    t[rr + r0][c] = W[(size_t)(bj * 32 + rr + r0) * N + bi * 32 + c];
  __syncthreads();
#pragma unroll
  for (int rr = 0; rr < 32; rr += 8)
    Wt[(size_t)(bi * 32 + rr + r0) * K + bj * 32 + c] = (bf16)t[c][rr + r0];
}

// rt[t][j] = {cos, sin}(t * theta^(-j/32)), t<2048, j<32
__global__ __launch_bounds__(64) void k_rope_table(float* __restrict__ rt) {
  int t = blockIdx.x * 2 + (threadIdx.x >> 5);
  int j = threadIdx.x & 31;
  float freq = exp2f(-(float)j * (1.0f / 32.0f) * log2f(500000.0f));
  float ang = (float)t * freq;
  rt[t * 64 + 2 * j] = cosf(ang);
  rt[t * 64 + 2 * j + 1] = sinf(ang);
}

template <int NCH>  // D = NCH*512, one wave per row; input row stride variable
__global__ __launch_bounds__(64) void k_rmsnorm(const bf16* __restrict__ in,
                                                const float* __restrict__ w,
                                                bf16* __restrict__ out,
                                                int in_stride) {
  int row = blockIdx.x, lane = threadIdx.x;
  const int D = NCH * 512;
  const bf16* ip = in + (size_t)row * in_stride;
  bf16x8 v[NCH];
  float ss = 0.f;
#pragma unroll
  for (int c = 0; c < NCH; ++c) {
    v[c] = *reinterpret_cast<const bf16x8*>(ip + c * 512 + lane * 8);
#pragma unroll
    for (int e = 0; e < 8; ++e) { float f = (float)v[c][e]; ss += f * f; }
  }
#pragma unroll
  for (int m = 1; m <= 32; m <<= 1) ss += __shfl_xor(ss, m);
  float rs = rsqrtf(ss / (float)D + 1e-6f);
  bf16* op = out + (size_t)row * D;
#pragma unroll
  for (int c = 0; c < NCH; ++c) {
    bf16x8 o;
#pragma unroll
    for (int e = 0; e < 8; ++e)
      o[e] = (bf16)((float)v[c][e] * rs * w[c * 512 + lane * 8 + e]);
    *reinterpret_cast<bf16x8*>(op + c * 512 + lane * 8) = o;
  }
}

// in [MR][stride], cols 0..511 rmsnorm -> kvn [MR][512]; cols 512..575 rope -> kr
__global__ __launch_bounds__(64) void k_kv_norm_rope(
    const bf16* __restrict__ in, const float* __restrict__ w,
    const float* __restrict__ rt, bf16* __restrict__ kvn,
    bf16* __restrict__ kr, int in_stride) {
  int row = blockIdx.x, lane = threadIdx.x;
  const bf16* ip = in + (size_t)row * in_stride;
  bf16x8 v = *reinterpret_cast<const bf16x8*>(ip + lane * 8);
  float ss = 0.f;
#pragma unroll
  for (int e = 0; e < 8; ++e) { float f = (float)v[e]; ss += f * f; }
#pragma unroll
  for (int m = 1; m <= 32; m <<= 1) ss += __shfl_xor(ss, m);
  float rs = rsqrtf(ss / 512.0f + 1e-6f);
  bf16x8 o;
#pragma unroll
  for (int e = 0; e < 8; ++e) o[e] = (bf16)((float)v[e] * rs * w[lane * 8 + e]);
  *reinterpret_cast<bf16x8*>(kvn + (size_t)row * 512 + lane * 8) = o;
  if (lane < 32) {
    int t = row & (TSEQ - 1);
    float x0 = (float)ip[512 + 2 * lane], x1 = (float)ip[512 + 2 * lane + 1];
    float c = rt[t * 64 + 2 * lane], s = rt[t * 64 + 2 * lane + 1];
    kr[(size_t)row * 64 + lane] = (bf16)(x0 * c - x1 * s);
    kr[(size_t)row * 64 + 32 + lane] = (bf16)(x1 * c + x0 * s);
  }
}

// q [MR][3072] (16 heads x 192); rope cols h*192+128..+191 -> qr [MR][16][64]
__global__ __launch_bounds__(256) void k_rope_q(const bf16* __restrict__ q,
                                                const float* __restrict__ rt,
                                                bf16* __restrict__ qr) {
  int idx = blockIdx.x * 256 + threadIdx.x;  // MR*16*32 total
  int j = idx & 31, h = (idx >> 5) & 15, row = idx >> 9;
  int t = row & (TSEQ - 1);
  const bf16* src = q + (size_t)row * 3072 + h * 192 + 128;
  float x0 = (float)src[2 * j], x1 = (float)src[2 * j + 1];
  float c = rt[t * 64 + 2 * j], s = rt[t * 64 + 2 * j + 1];
  bf16* dst = qr + ((size_t)row * 16 + h) * 64;
  dst[j] = (bf16)(x0 * c - x1 * s);
  dst[32 + j] = (bf16)(x1 * c + x0 * s);
}

// ---------------- GEMM: C[M][N] = A[M][K] @ Bt[N][K]^T ----------------
template <bool OUT_F32>
__global__ __launch_bounds__(256) void k_gemm_bt(const bf16* __restrict__ A,
                                                 const bf16* __restrict__ Bt,
                                                 void* __restrict__ C, int M,
                                                 int N, int K) {
  __shared__ bf16 As[128 * 32];
  __shared__ bf16 Bs[128 * 32];
  const int tid = threadIdx.x, lane = tid & 63, w = tid >> 6;
  const int wm = w >> 1, wn = w & 1;
  const int lg = lane >> 4, lr = lane & 15;
  const int m0 = blockIdx.y * 128, n0 = blockIdx.x * 128;
  f32x4 acc[4][4] = {};
  for (int k0 = 0; k0 < K; k0 += 32) {
    __syncthreads();
#pragma unroll
    for (int i = 0; i < 2; ++i) {
      int chunk = i * 256 + w * 64 + lane;
      int row = chunk >> 2, cc = chunk & 3;
      gload_lds16(A + (size_t)(m0 + row) * K + k0 + cc * 8,
                  (char*)As + (size_t)(i * 256 + w * 64) * 16);
      int nr = n0 + row;
      nr = nr < N ? nr : N - 1;  // clamp (garbage cols never stored)
      gload_lds16(Bt + (size_t)nr * K + k0 + cc * 8,
                  (char*)Bs + (size_t)(i * 256 + w * 64) * 16);
    }
    __syncthreads();
    bf16x8 af[4], bfr[4];
#pragma unroll
    for (int mi = 0; mi < 4; ++mi)
      af[mi] = *reinterpret_cast<const bf16x8*>(
          &As[(wm * 64 + mi * 16 + lr) * 32 + lg * 8]);
#pragma unroll
    for (int ni = 0; ni < 4; ++ni)
      bfr[ni] = *reinterpret_cast<const bf16x8*>(
          &Bs[(wn * 64 + ni * 16 + lr) * 32 + lg * 8]);
#pragma unroll
    for (int mi = 0; mi < 4; ++mi)
#pragma unroll
      for (int ni = 0; ni < 4; ++ni)
        acc[mi][ni] = mfma16(af[mi], bfr[ni], acc[mi][ni]);
  }
#pragma unroll
  for (int mi = 0; mi < 4; ++mi)
#pragma unroll
    for (int ni = 0; ni < 4; ++ni) {
      int col = n0 + wn * 64 + ni * 16 + lr;
      if (col < N) {
#pragma unroll
        for (int r = 0; r < 4; ++r) {
          int rowg = m0 + wm * 64 + mi * 16 + lg * 4 + r;
          if (OUT_F32)
            reinterpret_cast<float*>(C)[(size_t)rowg * N + col] = acc[mi][ni][r];
          else
            reinterpret_cast<bf16*>(C)[(size_t)rowg * N + col] =
                (bf16)acc[mi][ni][r];
        }
      }
    }
}

// ---------------- causal flash attention v4 ----------------
// 256 blocks, each runs TWO tasks (id = blk, then 511-blk): qtA + qtB = 15,
// so every block does exactly 34 k-tile units -> zero tail.
// QBLK=128 (wave owns 32 rows = 2 subtiles), KBLK=64, 4 waves.
// Single barrier per k-tile: K via source-preswizzled global_load_lds (dbuf),
// V reg-staged -> fragment-packed Vs (dbuf), write after compute.
// V-fragment reads shared across both s-subtiles (Ps holds both s).
__global__ __launch_bounds__(256, 1) void k_attn(const bf16* __restrict__ q,
                                                 const bf16* __restrict__ qr,
                                                 const bf16* __restrict__ kv,
                                                 const bf16* __restrict__ kr,
                                                 bf16* __restrict__ o) {
  __shared__ bf16 Kn[2][64 * 128];  // linear chunks; data col = j^(row&15)
  __shared__ bf16 Kr[2][64 * 64];   // data col = j^(row&7)
  __shared__ bf16 Vs[2][64 * 128];  // fragment-packed V^T
  __shared__ bf16 Ps[2][4 * 1024];  // [s][wave-private P]
  const int tid = threadIdx.x, lane = tid & 63, w = tid >> 6;
  const int lg = lane >> 4, lr = lane & 15;
  const float qsc = 0.07216878364870323f * 1.44269504088896f;  // 192^-.5*log2e
  uint4 vreg[4];
  const int vkq = tid >> 4, vvc = tid & 15;  // V staging role

  for (int t = 0; t < 2; ++t) {
    const int id = t ? 511 - (int)blockIdx.x : (int)blockIdx.x;
    const int qt = 15 - (id >> 5);
    const int bh = id & 31;
    const int b = bh >> 4, h = bh & 15;
    const int q0 = qt * 128;
    const size_t rowbase = (size_t)b * TSEQ;
    const int nkt = 2 * qt + 2;

    auto issue_loads = [&](int kbase, int buf) {
      // V -> regs first (so write_vs's implicit wait is vmcnt(6)-like)
#pragma unroll
      for (int kk = 0; kk < 4; ++kk)
        vreg[kk] = *reinterpret_cast<const uint4*>(
            kv + (rowbase + kbase + vkq * 4 + kk) * 4096 + h * 256 + 128 +
            vvc * 8);
#pragma unroll
      for (int i = 0; i < 4; ++i) {
        int c = i * 256 + tid;
        int row = c >> 4, j = c & 15;
        gload_lds16(
            kv + (rowbase + kbase + row) * 4096 + h * 256 +
                ((j ^ (row & 15)) * 8),
            (char*)&Kn[buf][0] + (size_t)(i * 256 + w * 64) * 16);
      }
#pragma unroll
      for (int i = 0; i < 2; ++i) {
        int c = i * 256 + tid;
        int row = c >> 3, j = c & 7;
        gload_lds16(kr + (rowbase + kbase + row) * 64 + ((j ^ (row & 7)) * 8),
                    (char*)&Kr[buf][0] + (size_t)(i * 256 + w * 64) * 16);
      }
    };

    auto write_vs = [&](int buf) {
      const int kb0 = vkq * 4;
      const int cC = kb0 >> 5, g = (kb0 >> 3) & 3, j0 = kb0 & 7;
      uint32_t rd[4][4];
#pragma unroll
      for (int kk = 0; kk < 4; ++kk) {
        rd[kk][0] = vreg[kk].x; rd[kk][1] = vreg[kk].y;
        rd[kk][2] = vreg[kk].z; rd[kk][3] = vreg[kk].w;
      }
#pragma unroll
      for (int e = 0; e < 8; ++e) {
        uint32_t h0 = (rd[0][e >> 1] >> ((e & 1) * 16)) & 0xffffu;
        uint32_t h1 = (rd[1][e >> 1] >> ((e & 1) * 16)) & 0xffffu;
        uint32_t h2 = (rd[2][e >> 1] >> ((e & 1) * 16)) & 0xffffu;
        uint32_t h3 = (rd[3][e >> 1] >> ((e & 1) * 16)) & 0xffffu;
        int vd = vvc * 8 + e;
        int slot = (vd & 15) ^ g;
        uint2 wv = make_uint2(h0 | (h1 << 16), h2 | (h3 << 16));
        *reinterpret_cast<uint2*>(
            &Vs[buf][((cC * 8 + (vd >> 4)) * 4 + g) * 128 + slot * 8 + j0]) =
            wv;
      }
    };

    // Q fragments, scale folded in (exp2 softmax domain)
    bf16x8 qf[2][6];
#pragma unroll
    for (int s = 0; s < 2; ++s) {
      const int qg = q0 + w * 32 + s * 16 + lr;
      const bf16* qp = q + (rowbase + qg) * 3072 + h * 192;
#pragma unroll
      for (int dc = 0; dc < 4; ++dc) {
        bf16x8 v = *reinterpret_cast<const bf16x8*>(qp + dc * 32 + lg * 8);
#pragma unroll
        for (int e = 0; e < 8; ++e) v[e] = (bf16)((float)v[e] * qsc);
        qf[s][dc] = v;
      }
      const bf16* qrp = qr + ((rowbase + qg) * 16 + h) * 64;
#pragma unroll
      for (int dc = 0; dc < 2; ++dc) {
        bf16x8 v = *reinterpret_cast<const bf16x8*>(qrp + dc * 32 + lg * 8);
#pragma unroll
        for (int e = 0; e < 8; ++e) v[e] = (bf16)((float)v[e] * qsc);
        qf[s][4 + dc] = v;
      }
    }

    f32x4 oacc[2][8] = {};
    float m_run[2] = {-1e30f, -1e30f}, l_run[2] = {0.f, 0.f};

    // prologue: stage tile 0
    issue_loads(0, 0);
    write_vs(0);
    __syncthreads();

    for (int kt = 0; kt < nkt; ++kt) {
      const int kbase = kt * 64;
      const int buf = kt & 1;
      const bool more = (kt + 1 < nkt);
      if (more) issue_loads(kbase + 64, buf ^ 1);

      if (kbase <= q0 + w * 32 + 31) {  // wave-uniform
        // ---- S^T: K frags once per kb, shared across both s ----
        f32x4 sacc[2][4];
#pragma unroll
        for (int kb = 0; kb < 4; ++kb) {
          const int row = kb * 16 + lr;
          bf16x8 kf[6];
#pragma unroll
          for (int dc = 0; dc < 4; ++dc)
            kf[dc] = *reinterpret_cast<const bf16x8*>(
                &Kn[buf][row * 128 + (((dc * 4 + lg) ^ (row & 15)) * 8)]);
#pragma unroll
          for (int dc = 0; dc < 2; ++dc)
            kf[4 + dc] = *reinterpret_cast<const bf16x8*>(
                &Kr[buf][row * 64 + (((dc * 4 + lg) ^ (row & 7)) * 8)]);
          __builtin_amdgcn_s_setprio(1);
#pragma unroll
          for (int s = 0; s < 2; ++s) {
            f32x4 sa = {0.f, 0.f, 0.f, 0.f};
#pragma unroll
            for (int dc = 0; dc < 6; ++dc) sa = mfma16(kf[dc], qf[s][dc], sa);
            sacc[s][kb] = sa;
          }
          __builtin_amdgcn_s_setprio(0);
        }
        // ---- per-s softmax -> Ps[s]; rescale oacc ----
#pragma unroll
        for (int s = 0; s < 2; ++s) {
          const int qg = q0 + w * 32 + s * 16 + lr;
          float sv[4][4];
          float pmax = -1e30f;
#pragma unroll
          for (int kb = 0; kb < 4; ++kb)
#pragma unroll
            for (int r = 0; r < 4; ++r) {
              int kgl = kbase + kb * 16 + lg * 4 + r;
              float val = (kgl <= qg) ? sacc[s][kb][r] : -1e30f;
              sv[kb][r] = val;
              pmax = fmaxf(pmax, val);
            }
          pmax = fmaxf(pmax, __shfl_xor(pmax, 16));
          pmax = fmaxf(pmax, __shfl_xor(pmax, 32));
          float mnew = fmaxf(m_run[s], pmax);
          float alpha = exp2f(m_run[s] - mnew);
          float ls = 0.f;
#pragma unroll
          for (int kb = 0; kb < 4; ++kb) {
            bf16x4v pw;
#pragma unroll
            for (int r = 0; r < 4; ++r) {
              float p = exp2f(sv[kb][r] - mnew);
              ls += p;
              pw[r] = (bf16)p;
            }
            *reinterpret_cast<bf16x4v*>(
                &Ps[s][w * 1024 + lr * 64 +
                      (((kb * 2 + (lg >> 1)) ^ (lr & 7)) * 8) +
                      (lg & 1) * 4]) = pw;
          }
          ls += __shfl_xor(ls, 16);
          ls += __shfl_xor(ls, 32);
          l_run[s] = l_run[s] * alpha + ls;
          m_run[s] = mnew;
#pragma unroll
          for (int vb = 0; vb < 8; ++vb) {
            oacc[s][vb][0] *= alpha; oacc[s][vb][1] *= alpha;
            oacc[s][vb][2] *= alpha; oacc[s][vb][3] *= alpha;
          }
        }
        // ---- PV, V-frags shared across s ----
#pragma unroll
        for (int c = 0; c < 2; ++c) {
          bf16x8 pb0 = *reinterpret_cast<const bf16x8*>(
              &Ps[0][w * 1024 + lr * 64 + (((c * 4 + lg) ^ (lr & 7)) * 8)]);
          bf16x8 pb1 = *reinterpret_cast<const bf16x8*>(
              &Ps[1][w * 1024 + lr * 64 + (((c * 4 + lg) ^ (lr & 7)) * 8)]);
          __builtin_amdgcn_s_setprio(1);
#pragma unroll
          for (int vb = 0; vb < 8; ++vb) {
            bf16x8 av = *reinterpret_cast<const bf16x8*>(
                &Vs[buf][((c * 8 + vb) * 4 + lg) * 128 + (lr ^ lg) * 8]);
            oacc[0][vb] = mfma16(av, pb0, oacc[0][vb]);
            oacc[1][vb] = mfma16(av, pb1, oacc[1][vb]);
          }
          __builtin_amdgcn_s_setprio(0);
        }
      }
      if (more) write_vs(buf ^ 1);  // vreg dep -> implicit counted vmcnt
      __syncthreads();  // publishes Kn/Kr/Vs(kt+1); drains glds
    }

    // ---- epilogue via LDS (Kn[0] free) -> coalesced b128 stores ----
    bf16* Os = &Kn[0][0] + w * 4096;  // 32 rows x 128 cols per wave
#pragma unroll
    for (int s = 0; s < 2; ++s) {
      float inv = 1.0f / l_run[s];
      const int row = s * 16 + lr;
#pragma unroll
      for (int vb = 0; vb < 8; ++vb) {
        bf16x4v ov;
#pragma unroll
        for (int r = 0; r < 4; ++r) ov[r] = (bf16)(oacc[s][vb][r] * inv);
        int slot16 = vb * 2 + (lg >> 1);
        *reinterpret_cast<bf16x4v*>(
            &Os[row * 128 + ((slot16 ^ (lr & 7)) * 8) + (lg & 1) * 4]) = ov;
      }
    }
    asm volatile("s_waitcnt lgkmcnt(0)");
    __builtin_amdgcn_sched_barrier(0);
#pragma unroll
    for (int i = 0; i < 8; ++i) {
      const int r = i * 4 + lg;  // 0..31
      bf16x8 ov = *reinterpret_cast<const bf16x8*>(
          &Os[r * 128 + ((lr ^ (r & 7)) * 8)]);
      *reinterpret_cast<bf16x8*>(
          o + (rowbase + q0 + w * 32 + r) * 2048 + h * 128 + lr * 8) = ov;
    }
    __syncthreads();  // protect Os region before next task restages LDS
  }
}

// ---------------- launch ----------------
extern "C" void kernel_launch(void* const* d_in, const int* in_sizes, int n_in,
                              void* d_out, int out_size, void* d_ws,
                              size_t ws_size, hipStream_t stream) {
  (void)in_sizes; (void)n_in; (void)out_size; (void)ws_size;
  const float* x       = (const float*)d_in[0];
  const float* q_a_w   = (const float*)d_in[1];
  const float* q_a_ln  = (const float*)d_in[2];
  const float* q_b_w   = (const float*)d_in[3];
  const float* kv_a_w  = (const float*)d_in[4];
  const float* kv_a_ln = (const float*)d_in[5];
  const float* kv_b_w  = (const float*)d_in[6];
  const float* o_w     = (const float*)d_in[7];

  char* ws = (char*)d_ws;
  size_t off = 0;
  auto alloc = [&](size_t bytes) {
    void* p = ws + off;
    off += (bytes + 255) & ~(size_t)255;
    return p;
  };
  bf16* x_bf   = (bf16*)alloc((size_t)MR * 2048 * 2);
  bf16* ab_wt  = (bf16*)alloc((size_t)2112 * 2048 * 2);  // [q_a ; kv_a]^T
  bf16* qb_wt  = (bf16*)alloc((size_t)3072 * 1536 * 2);
  bf16* kvb_wt = (bf16*)alloc((size_t)4096 * 512 * 2);
  bf16* o_wt   = (bf16*)alloc((size_t)2048 * 2048 * 2);
  float* rt    = (float*)alloc((size_t)2048 * 64 * 4);
  bf16* qac    = (bf16*)alloc((size_t)MR * 2112 * 2);  // fused q_a|ckv
  bf16* q_a_n  = (bf16*)alloc((size_t)MR * 1536 * 2);
  bf16* kv_c_n = (bf16*)alloc((size_t)MR * 512 * 2);
  bf16* kr     = (bf16*)alloc((size_t)MR * 64 * 2);
  bf16* qbuf   = (bf16*)alloc((size_t)MR * 3072 * 2);
  bf16* qr     = (bf16*)alloc((size_t)MR * 16 * 64 * 2);
  bf16* kvbuf  = (bf16*)alloc((size_t)MR * 4096 * 2);
  bf16* attn_o = (bf16*)alloc((size_t)MR * 2048 * 2);

  k_cvt_bf16<<<8192, 256, 0, stream>>>(x, x_bf);
  k_transpose<<<dim3(1536 / 32, 2048 / 32), 256, 0, stream>>>(q_a_w, ab_wt, 2048, 1536);
  k_transpose<<<dim3(576 / 32, 2048 / 32), 256, 0, stream>>>(
      kv_a_w, ab_wt + (size_t)1536 * 2048, 2048, 576);
  k_transpose<<<dim3(3072 / 32, 1536 / 32), 256, 0, stream>>>(q_b_w, qb_wt, 1536, 3072);
  k_transpose<<<dim3(4096 / 32, 512 / 32), 256, 0, stream>>>(kv_b_w, kvb_wt, 512, 4096);
  k_transpose<<<dim3(2048 / 32, 2048 / 32), 256, 0, stream>>>(o_w, o_wt, 2048, 2048);
  k_rope_table<<<1024, 64, 0, stream>>>(rt);

  // fused q_a + kv_a down-projection: [4096][2112]
  k_gemm_bt<false><<<dim3(17, 32), 256, 0, stream>>>(x_bf, ab_wt, qac, MR, 2112, 2048);
  k_rmsnorm<3><<<MR, 64, 0, stream>>>(qac, q_a_ln, q_a_n, 2112);
  k_kv_norm_rope<<<MR, 64, 0, stream>>>(qac + 1536, kv_a_ln, rt, kv_c_n, kr, 2112);
  k_gemm_bt<false><<<dim3(24, 32), 256, 0, stream>>>(q_a_n, qb_wt, qbuf, MR, 3072, 1536);
  k_rope_q<<<8192, 256, 0, stream>>>(qbuf, rt, qr);
  k_gemm_bt<false><<<dim3(32, 32), 256, 0, stream>>>(kv_c_n, kvb_wt, kvbuf, MR, 4096, 512);
  k_attn<<<dim3(256), 256, 0, stream>>>(qbuf, qr, kvbuf, kr, attn_o);
  k_gemm_bt<true><<<dim3(16, 32), 256, 0, stream>>>(attn_o, o_wt, d_out, MR, 2048, 2048);
}

// Round 5
// 345.178 us; speedup vs baseline: 1.7810x; 1.1700x over previous
//
#include <hip/hip_runtime.h>
#include <hip/hip_bf16.h>
#include <cstdint>

// MLA: B=2, T=2048, H=16, d_nope=128, d_rope=64, d_qk=192, d_v=128,
// kv_lora=512, q_lora=1536, hidden=2048. Output f32 [4096][2048].

typedef __bf16 bf16;
typedef __bf16 bf16x8 __attribute__((ext_vector_type(8)));
typedef __bf16 bf16x4v __attribute__((ext_vector_type(4)));
typedef float f32x4 __attribute__((ext_vector_type(4)));

#define TSEQ 2048
#define MR 4096  // B*T

typedef const uint32_t __attribute__((address_space(1))) * gas1_t;
typedef uint32_t __attribute__((address_space(3))) * las3_t;

static __device__ __forceinline__ void gload_lds16(const void* g, void* l) {
  __builtin_amdgcn_global_load_lds(
      reinterpret_cast<gas1_t>(reinterpret_cast<uintptr_t>(g)),
      reinterpret_cast<las3_t>(reinterpret_cast<uintptr_t>(l)), 16, 0, 0);
}

static __device__ __forceinline__ f32x4 mfma16(bf16x8 a, bf16x8 b, f32x4 c) {
  return __builtin_amdgcn_mfma_f32_16x16x32_bf16(a, b, c, 0, 0, 0);
}

// ---------------- prep kernels ----------------

__global__ __launch_bounds__(256) void k_cvt_bf16(const float* __restrict__ in,
                                                  bf16* __restrict__ out) {
  int i = blockIdx.x * 256 + threadIdx.x;
  float4 f = reinterpret_cast<const float4*>(in)[i];
  bf16x4v o = {(bf16)f.x, (bf16)f.y, (bf16)f.z, (bf16)f.w};
  reinterpret_cast<bf16x4v*>(out)[i] = o;
}

// W [K][N] f32 -> Wt [N][K] bf16 (K, N multiples of 32)
__global__ __launch_bounds__(256) void k_transpose(const float* __restrict__ W,
                                                   bf16* __restrict__ Wt,
                                                   int K, int N) {
  __shared__ float t[32][33];
  int bi = blockIdx.x, bj = blockIdx.y;
  int c = threadIdx.x & 31, r0 = threadIdx.x >> 5;
#pragma unroll
  for (int rr = 0; rr < 32; rr += 8)
    t[rr + r0][c] = W[(size_t)(bj * 32 + rr + r0) * N + bi * 32 + c];
  __syncthreads();
#pragma unroll
  for (int rr = 0; rr < 32; rr += 8)
    Wt[(size_t)(bi * 32 + rr + r0) * K + bj * 32 + c] = (bf16)t[c][rr + r0];
}

// rt[t][j] = {cos, sin}(t * theta^(-j/32)), t<2048, j<32
__global__ __launch_bounds__(64) void k_rope_table(float* __restrict__ rt) {
  int t = blockIdx.x * 2 + (threadIdx.x >> 5);
  int j = threadIdx.x & 31;
  float freq = exp2f(-(float)j * (1.0f / 32.0f) * log2f(500000.0f));
  float ang = (float)t * freq;
  rt[t * 64 + 2 * j] = cosf(ang);
  rt[t * 64 + 2 * j + 1] = sinf(ang);
}

template <int NCH>  // D = NCH*512, one wave per row; input row stride variable
__global__ __launch_bounds__(64) void k_rmsnorm(const bf16* __restrict__ in,
                                                const float* __restrict__ w,
                                                bf16* __restrict__ out,
                                                int in_stride) {
  int row = blockIdx.x, lane = threadIdx.x;
  const int D = NCH * 512;
  const bf16* ip = in + (size_t)row * in_stride;
  bf16x8 v[NCH];
  float ss = 0.f;
#pragma unroll
  for (int c = 0; c < NCH; ++c) {
    v[c] = *reinterpret_cast<const bf16x8*>(ip + c * 512 + lane * 8);
#pragma unroll
    for (int e = 0; e < 8; ++e) { float f = (float)v[c][e]; ss += f * f; }
  }
#pragma unroll
  for (int m = 1; m <= 32; m <<= 1) ss += __shfl_xor(ss, m);
  float rs = rsqrtf(ss / (float)D + 1e-6f);
  bf16* op = out + (size_t)row * D;
#pragma unroll
  for (int c = 0; c < NCH; ++c) {
    bf16x8 o;
#pragma unroll
    for (int e = 0; e < 8; ++e)
      o[e] = (bf16)((float)v[c][e] * rs * w[c * 512 + lane * 8 + e]);
    *reinterpret_cast<bf16x8*>(op + c * 512 + lane * 8) = o;
  }
}

// in [MR][stride], cols 0..511 rmsnorm -> kvn [MR][512]; cols 512..575 rope -> kr
__global__ __launch_bounds__(64) void k_kv_norm_rope(
    const bf16* __restrict__ in, const float* __restrict__ w,
    const float* __restrict__ rt, bf16* __restrict__ kvn,
    bf16* __restrict__ kr, int in_stride) {
  int row = blockIdx.x, lane = threadIdx.x;
  const bf16* ip = in + (size_t)row * in_stride;
  bf16x8 v = *reinterpret_cast<const bf16x8*>(ip + lane * 8);
  float ss = 0.f;
#pragma unroll
  for (int e = 0; e < 8; ++e) { float f = (float)v[e]; ss += f * f; }
#pragma unroll
  for (int m = 1; m <= 32; m <<= 1) ss += __shfl_xor(ss, m);
  float rs = rsqrtf(ss / 512.0f + 1e-6f);
  bf16x8 o;
#pragma unroll
  for (int e = 0; e < 8; ++e) o[e] = (bf16)((float)v[e] * rs * w[lane * 8 + e]);
  *reinterpret_cast<bf16x8*>(kvn + (size_t)row * 512 + lane * 8) = o;
  if (lane < 32) {
    int t = row & (TSEQ - 1);
    float x0 = (float)ip[512 + 2 * lane], x1 = (float)ip[512 + 2 * lane + 1];
    float c = rt[t * 64 + 2 * lane], s = rt[t * 64 + 2 * lane + 1];
    kr[(size_t)row * 64 + lane] = (bf16)(x0 * c - x1 * s);
    kr[(size_t)row * 64 + 32 + lane] = (bf16)(x1 * c + x0 * s);
  }
}

// q [MR][3072] (16 heads x 192); rope cols h*192+128..+191 -> qr [MR][16][64]
__global__ __launch_bounds__(256) void k_rope_q(const bf16* __restrict__ q,
                                                const float* __restrict__ rt,
                                                bf16* __restrict__ qr) {
  int idx = blockIdx.x * 256 + threadIdx.x;  // MR*16*32 total
  int j = idx & 31, h = (idx >> 5) & 15, row = idx >> 9;
  int t = row & (TSEQ - 1);
  const bf16* src = q + (size_t)row * 3072 + h * 192 + 128;
  float x0 = (float)src[2 * j], x1 = (float)src[2 * j + 1];
  float c = rt[t * 64 + 2 * j], s = rt[t * 64 + 2 * j + 1];
  bf16* dst = qr + ((size_t)row * 16 + h) * 64;
  dst[j] = (bf16)(x0 * c - x1 * s);
  dst[32 + j] = (bf16)(x1 * c + x0 * s);
}

// ---------------- GEMM: C[M][N] = A[M][K] @ Bt[N][K]^T ----------------
template <bool OUT_F32>
__global__ __launch_bounds__(256) void k_gemm_bt(const bf16* __restrict__ A,
                                                 const bf16* __restrict__ Bt,
                                                 void* __restrict__ C, int M,
                                                 int N, int K) {
  __shared__ bf16 As[128 * 32];
  __shared__ bf16 Bs[128 * 32];
  const int tid = threadIdx.x, lane = tid & 63, w = tid >> 6;
  const int wm = w >> 1, wn = w & 1;
  const int lg = lane >> 4, lr = lane & 15;
  const int m0 = blockIdx.y * 128, n0 = blockIdx.x * 128;
  f32x4 acc[4][4] = {};
  for (int k0 = 0; k0 < K; k0 += 32) {
    __syncthreads();
#pragma unroll
    for (int i = 0; i < 2; ++i) {
      int chunk = i * 256 + w * 64 + lane;
      int row = chunk >> 2, cc = chunk & 3;
      gload_lds16(A + (size_t)(m0 + row) * K + k0 + cc * 8,
                  (char*)As + (size_t)(i * 256 + w * 64) * 16);
      int nr = n0 + row;
      nr = nr < N ? nr : N - 1;  // clamp (garbage cols never stored)
      gload_lds16(Bt + (size_t)nr * K + k0 + cc * 8,
                  (char*)Bs + (size_t)(i * 256 + w * 64) * 16);
    }
    __syncthreads();
    bf16x8 af[4], bfr[4];
#pragma unroll
    for (int mi = 0; mi < 4; ++mi)
      af[mi] = *reinterpret_cast<const bf16x8*>(
          &As[(wm * 64 + mi * 16 + lr) * 32 + lg * 8]);
#pragma unroll
    for (int ni = 0; ni < 4; ++ni)
      bfr[ni] = *reinterpret_cast<const bf16x8*>(
          &Bs[(wn * 64 + ni * 16 + lr) * 32 + lg * 8]);
#pragma unroll
    for (int mi = 0; mi < 4; ++mi)
#pragma unroll
      for (int ni = 0; ni < 4; ++ni)
        acc[mi][ni] = mfma16(af[mi], bfr[ni], acc[mi][ni]);
  }
#pragma unroll
  for (int mi = 0; mi < 4; ++mi)
#pragma unroll
    for (int ni = 0; ni < 4; ++ni) {
      int col = n0 + wn * 64 + ni * 16 + lr;
      if (col < N) {
#pragma unroll
        for (int r = 0; r < 4; ++r) {
          int rowg = m0 + wm * 64 + mi * 16 + lg * 4 + r;
          if (OUT_F32)
            reinterpret_cast<float*>(C)[(size_t)rowg * N + col] = acc[mi][ni][r];
          else
            reinterpret_cast<bf16*>(C)[(size_t)rowg * N + col] =
                (bf16)acc[mi][ni][r];
        }
      }
    }
}

// ---------------- causal flash attention v5 ----------------
// 8 waves x 16 q-rows = QBLK 128, KBLK=64. 512-thread block, LDS 96K ->
// 1 block/CU but 2 waves/SIMD (vs 1 before): latency now hides.
// 256 blocks, each runs TWO paired tasks (id, 511-id): qtA+qtB=15 -> every
// block exactly 34 k-tile units, zero tail.
// K via source-preswizzled global_load_lds (dbuf); V reg-staged ->
// fragment-packed Vs (dbuf); single barrier per k-tile.
__global__ __launch_bounds__(512, 2) void k_attn(const bf16* __restrict__ q,
                                                 const bf16* __restrict__ qr,
                                                 const bf16* __restrict__ kv,
                                                 const bf16* __restrict__ kr,
                                                 bf16* __restrict__ o) {
  __shared__ bf16 Kn[2][64 * 128];  // linear chunks; data col = j^(row&15)
  __shared__ bf16 Kr[2][64 * 64];   // data col = j^(row&7)
  __shared__ bf16 Vs[2][64 * 128];  // fragment-packed V^T
  __shared__ bf16 Ps[8 * 1024];     // per-wave P [16 q][64 k] swizzled
  const int tid = threadIdx.x, lane = tid & 63, w = tid >> 6;
  const int lg = lane >> 4, lr = lane & 15;
  const float qsc = 0.07216878364870323f * 1.44269504088896f;  // 192^-.5*log2e
  uint4 vreg[2];
  const int vrr = tid & 31, vvc = tid >> 5;  // V role: rows vrr*2,+1; cols vvc*8..+7

  for (int t = 0; t < 2; ++t) {
    const int id = t ? 511 - (int)blockIdx.x : (int)blockIdx.x;
    const int qt = 15 - (id >> 5);
    const int bh = id & 31;
    const int b = bh >> 4, h = bh & 15;
    const int q0 = qt * 128;
    const size_t rowbase = (size_t)b * TSEQ;
    const int nkt = 2 * qt + 2;
    const int qg = q0 + w * 16 + lr;  // this lane's q row / S^T column

    auto issue_loads = [&](int kbase, int buf) {
      // V -> regs first
#pragma unroll
      for (int kk = 0; kk < 2; ++kk)
        vreg[kk] = *reinterpret_cast<const uint4*>(
            kv + (rowbase + kbase + vrr * 2 + kk) * 4096 + h * 256 + 128 +
            vvc * 8);
#pragma unroll
      for (int i = 0; i < 2; ++i) {
        int c = i * 512 + tid;
        int row = c >> 4, j = c & 15;
        gload_lds16(
            kv + (rowbase + kbase + row) * 4096 + h * 256 +
                ((j ^ (row & 15)) * 8),
            (char*)&Kn[buf][0] + (size_t)(i * 512 + w * 64) * 16);
      }
      {
        int row = tid >> 3, j = tid & 7;
        gload_lds16(kr + (rowbase + kbase + row) * 64 + ((j ^ (row & 7)) * 8),
                    (char*)&Kr[buf][0] + (size_t)(w * 64) * 16);
      }
    };

    auto write_vs = [&](int buf) {
      const int kb0 = vrr * 2;
      const int cC = kb0 >> 5, g = (kb0 >> 3) & 3, j0 = kb0 & 7;
      const uint32_t* r0 = reinterpret_cast<const uint32_t*>(&vreg[0]);
      const uint32_t* r1 = reinterpret_cast<const uint32_t*>(&vreg[1]);
#pragma unroll
      for (int e = 0; e < 8; ++e) {
        uint32_t h0 = (r0[e >> 1] >> ((e & 1) * 16)) & 0xffffu;
        uint32_t h1 = (r1[e >> 1] >> ((e & 1) * 16)) & 0xffffu;
        int vd = vvc * 8 + e;
        int slot = (vd & 15) ^ g;
        *reinterpret_cast<uint32_t*>(
            &Vs[buf][((cC * 8 + (vd >> 4)) * 4 + g) * 128 + slot * 8 + j0]) =
            h0 | (h1 << 16);
      }
    };

    // Q fragments, scale folded in (exp2 softmax domain)
    bf16x8 qf[6];
    {
      const bf16* qp = q + (rowbase + qg) * 3072 + h * 192;
#pragma unroll
      for (int dc = 0; dc < 4; ++dc) {
        bf16x8 v = *reinterpret_cast<const bf16x8*>(qp + dc * 32 + lg * 8);
#pragma unroll
        for (int e = 0; e < 8; ++e) v[e] = (bf16)((float)v[e] * qsc);
        qf[dc] = v;
      }
      const bf16* qrp = qr + ((rowbase + qg) * 16 + h) * 64;
#pragma unroll
      for (int dc = 0; dc < 2; ++dc) {
        bf16x8 v = *reinterpret_cast<const bf16x8*>(qrp + dc * 32 + lg * 8);
#pragma unroll
        for (int e = 0; e < 8; ++e) v[e] = (bf16)((float)v[e] * qsc);
        qf[4 + dc] = v;
      }
    }

    f32x4 oacc[8] = {};
    float m_run = -1e30f, l_run = 0.f;

    // prologue: stage tile 0
    issue_loads(0, 0);
    write_vs(0);
    __syncthreads();

    for (int kt = 0; kt < nkt; ++kt) {
      const int kbase = kt * 64;
      const int buf = kt & 1;
      const bool more = (kt + 1 < nkt);
      if (more) issue_loads(kbase + 64, buf ^ 1);

      if (kbase <= q0 + w * 16 + 15) {  // wave-uniform
        // ---- S^T ----
        f32x4 sacc[4];
#pragma unroll
        for (int kb = 0; kb < 4; ++kb) {
          const int row = kb * 16 + lr;
          bf16x8 kf[6];
#pragma unroll
          for (int dc = 0; dc < 4; ++dc)
            kf[dc] = *reinterpret_cast<const bf16x8*>(
                &Kn[buf][row * 128 + (((dc * 4 + lg) ^ (row & 15)) * 8)]);
#pragma unroll
          for (int dc = 0; dc < 2; ++dc)
            kf[4 + dc] = *reinterpret_cast<const bf16x8*>(
                &Kr[buf][row * 64 + (((dc * 4 + lg) ^ (row & 7)) * 8)]);
          __builtin_amdgcn_s_setprio(1);
          f32x4 sa = {0.f, 0.f, 0.f, 0.f};
#pragma unroll
          for (int dc = 0; dc < 6; ++dc) sa = mfma16(kf[dc], qf[dc], sa);
          sacc[kb] = sa;
          __builtin_amdgcn_s_setprio(0);
        }
        // ---- softmax (exp2 domain) ----
        float sv[4][4];
        float pmax = -1e30f;
#pragma unroll
        for (int kb = 0; kb < 4; ++kb)
#pragma unroll
          for (int r = 0; r < 4; ++r) {
            int kgl = kbase + kb * 16 + lg * 4 + r;
            float val = (kgl <= qg) ? sacc[kb][r] : -1e30f;
            sv[kb][r] = val;
            pmax = fmaxf(pmax, val);
          }
        pmax = fmaxf(pmax, __shfl_xor(pmax, 16));
        pmax = fmaxf(pmax, __shfl_xor(pmax, 32));
        float mnew = fmaxf(m_run, pmax);
        float alpha = exp2f(m_run - mnew);
        float ls = 0.f;
#pragma unroll
        for (int kb = 0; kb < 4; ++kb) {
          bf16x4v pw;
#pragma unroll
          for (int r = 0; r < 4; ++r) {
            float p = exp2f(sv[kb][r] - mnew);
            ls += p;
            pw[r] = (bf16)p;
          }
          *reinterpret_cast<bf16x4v*>(
              &Ps[w * 1024 + lr * 64 +
                  (((kb * 2 + (lg >> 1)) ^ (lr & 7)) * 8) + (lg & 1) * 4]) = pw;
        }
        ls += __shfl_xor(ls, 16);
        ls += __shfl_xor(ls, 32);
        l_run = l_run * alpha + ls;
        m_run = mnew;
#pragma unroll
        for (int vb = 0; vb < 8; ++vb) {
          oacc[vb][0] *= alpha; oacc[vb][1] *= alpha;
          oacc[vb][2] *= alpha; oacc[vb][3] *= alpha;
        }
        // ---- PV: O^T += V^T @ P^T ----
#pragma unroll
        for (int c = 0; c < 2; ++c) {
          bf16x8 pb = *reinterpret_cast<const bf16x8*>(
              &Ps[w * 1024 + lr * 64 + (((c * 4 + lg) ^ (lr & 7)) * 8)]);
          __builtin_amdgcn_s_setprio(1);
#pragma unroll
          for (int vb = 0; vb < 8; ++vb) {
            bf16x8 av = *reinterpret_cast<const bf16x8*>(
                &Vs[buf][((c * 8 + vb) * 4 + lg) * 128 + (lr ^ lg) * 8]);
            oacc[vb] = mfma16(av, pb, oacc[vb]);
          }
          __builtin_amdgcn_s_setprio(0);
        }
      }
      if (more) write_vs(buf ^ 1);  // vreg dep -> counted vmcnt by compiler
      __syncthreads();  // publishes Kn/Kr/Vs(kt+1); drains glds
    }

    // ---- epilogue via LDS (Kn region free) -> coalesced b128 stores ----
    bf16* Os = &Kn[0][0] + w * 2048;  // 16 rows x 128 cols per wave (32K total)
    {
      float inv = 1.0f / l_run;
#pragma unroll
      for (int vb = 0; vb < 8; ++vb) {
        bf16x4v ov;
#pragma unroll
        for (int r = 0; r < 4; ++r) ov[r] = (bf16)(oacc[vb][r] * inv);
        int slot16 = vb * 2 + (lg >> 1);
        *reinterpret_cast<bf16x4v*>(
            &Os[lr * 128 + ((slot16 ^ (lr & 7)) * 8) + (lg & 1) * 4]) = ov;
      }
    }
    asm volatile("s_waitcnt lgkmcnt(0)");
    __builtin_amdgcn_sched_barrier(0);
#pragma unroll
    for (int i = 0; i < 4; ++i) {
      const int r = i * 4 + lg;  // 0..15
      bf16x8 ov = *reinterpret_cast<const bf16x8*>(
          &Os[r * 128 + ((lr ^ (r & 7)) * 8)]);
      *reinterpret_cast<bf16x8*>(
          o + (rowbase + q0 + w * 16 + r) * 2048 + h * 128 + lr * 8) = ov;
    }
    __syncthreads();  // protect Os region before next task restages LDS
  }
}

// ---------------- launch ----------------
extern "C" void kernel_launch(void* const* d_in, const int* in_sizes, int n_in,
                              void* d_out, int out_size, void* d_ws,
                              size_t ws_size, hipStream_t stream) {
  (void)in_sizes; (void)n_in; (void)out_size; (void)ws_size;
  const float* x       = (const float*)d_in[0];
  const float* q_a_w   = (const float*)d_in[1];
  const float* q_a_ln  = (const float*)d_in[2];
  const float* q_b_w   = (const float*)d_in[3];
  const float* kv_a_w  = (const float*)d_in[4];
  const float* kv_a_ln = (const float*)d_in[5];
  const float* kv_b_w  = (const float*)d_in[6];
  const float* o_w     = (const float*)d_in[7];

  char* ws = (char*)d_ws;
  size_t off = 0;
  auto alloc = [&](size_t bytes) {
    void* p = ws + off;
    off += (bytes + 255) & ~(size_t)255;
    return p;
  };
  bf16* x_bf   = (bf16*)alloc((size_t)MR * 2048 * 2);
  bf16* ab_wt  = (bf16*)alloc((size_t)2112 * 2048 * 2);  // [q_a ; kv_a]^T
  bf16* qb_wt  = (bf16*)alloc((size_t)3072 * 1536 * 2);
  bf16* kvb_wt = (bf16*)alloc((size_t)4096 * 512 * 2);
  bf16* o_wt   = (bf16*)alloc((size_t)2048 * 2048 * 2);
  float* rt    = (float*)alloc((size_t)2048 * 64 * 4);
  bf16* qac    = (bf16*)alloc((size_t)MR * 2112 * 2);  // fused q_a|ckv
  bf16* q_a_n  = (bf16*)alloc((size_t)MR * 1536 * 2);
  bf16* kv_c_n = (bf16*)alloc((size_t)MR * 512 * 2);
  bf16* kr     = (bf16*)alloc((size_t)MR * 64 * 2);
  bf16* qbuf   = (bf16*)alloc((size_t)MR * 3072 * 2);
  bf16* qr     = (bf16*)alloc((size_t)MR * 16 * 64 * 2);
  bf16* kvbuf  = (bf16*)alloc((size_t)MR * 4096 * 2);
  bf16* attn_o = (bf16*)alloc((size_t)MR * 2048 * 2);

  k_cvt_bf16<<<8192, 256, 0, stream>>>(x, x_bf);
  k_transpose<<<dim3(1536 / 32, 2048 / 32), 256, 0, stream>>>(q_a_w, ab_wt, 2048, 1536);
  k_transpose<<<dim3(576 / 32, 2048 / 32), 256, 0, stream>>>(
      kv_a_w, ab_wt + (size_t)1536 * 2048, 2048, 576);
  k_transpose<<<dim3(3072 / 32, 1536 / 32), 256, 0, stream>>>(q_b_w, qb_wt, 1536, 3072);
  k_transpose<<<dim3(4096 / 32, 512 / 32), 256, 0, stream>>>(kv_b_w, kvb_wt, 512, 4096);
  k_transpose<<<dim3(2048 / 32, 2048 / 32), 256, 0, stream>>>(o_w, o_wt, 2048, 2048);
  k_rope_table<<<1024, 64, 0, stream>>>(rt);

  // fused q_a + kv_a down-projection: [4096][2112]
  k_gemm_bt<false><<<dim3(17, 32), 256, 0, stream>>>(x_bf, ab_wt, qac, MR, 2112, 2048);
  k_rmsnorm<3><<<MR, 64, 0, stream>>>(qac, q_a_ln, q_a_n, 2112);
  k_kv_norm_rope<<<MR, 64, 0, stream>>>(qac + 1536, kv_a_ln, rt, kv_c_n, kr, 2112);
  k_gemm_bt<false><<<dim3(24, 32), 256, 0, stream>>>(q_a_n, qb_wt, qbuf, MR, 3072, 1536);
  k_rope_q<<<8192, 256, 0, stream>>>(qbuf, rt, qr);
  k_gemm_bt<false><<<dim3(32, 32), 256, 0, stream>>>(kv_c_n, kvb_wt, kvbuf, MR, 4096, 512);
  k_attn<<<dim3(256), 512, 0, stream>>>(qbuf, qr, kvbuf, kr, attn_o);
  k_gemm_bt<true><<<dim3(16, 32), 256, 0, stream>>>(attn_o, o_wt, d_out, MR, 2048, 2048);
}

// Round 6
// 315.703 us; speedup vs baseline: 1.9473x; 1.0934x over previous
//
#include <hip/hip_runtime.h>
#include <hip/hip_bf16.h>
#include <cstdint>

// MLA: B=2, T=2048, H=16, d_nope=128, d_rope=64, d_qk=192, d_v=128,
// kv_lora=512, q_lora=1536, hidden=2048. Output f32 [4096][2048].

typedef __bf16 bf16;
typedef __bf16 bf16x8 __attribute__((ext_vector_type(8)));
typedef __bf16 bf16x4v __attribute__((ext_vector_type(4)));
typedef float f32x4 __attribute__((ext_vector_type(4)));

#define TSEQ 2048
#define MR 4096  // B*T

typedef const uint32_t __attribute__((address_space(1))) * gas1_t;
typedef uint32_t __attribute__((address_space(3))) * las3_t;

static __device__ __forceinline__ void gload_lds16(const void* g, void* l) {
  __builtin_amdgcn_global_load_lds(
      reinterpret_cast<gas1_t>(reinterpret_cast<uintptr_t>(g)),
      reinterpret_cast<las3_t>(reinterpret_cast<uintptr_t>(l)), 16, 0, 0);
}

static __device__ __forceinline__ f32x4 mfma16(bf16x8 a, bf16x8 b, f32x4 c) {
  return __builtin_amdgcn_mfma_f32_16x16x32_bf16(a, b, c, 0, 0, 0);
}

// ---------------- prep kernels ----------------

__global__ __launch_bounds__(256) void k_cvt_bf16(const float* __restrict__ in,
                                                  bf16* __restrict__ out) {
  int i = blockIdx.x * 256 + threadIdx.x;
  float4 f = reinterpret_cast<const float4*>(in)[i];
  bf16x4v o = {(bf16)f.x, (bf16)f.y, (bf16)f.z, (bf16)f.w};
  reinterpret_cast<bf16x4v*>(out)[i] = o;
}

// W [K][N] f32 -> Wt [N][K] bf16 (K, N multiples of 32)
__global__ __launch_bounds__(256) void k_transpose(const float* __restrict__ W,
                                                   bf16* __restrict__ Wt,
                                                   int K, int N) {
  __shared__ float t[32][33];
  int bi = blockIdx.x, bj = blockIdx.y;
  int c = threadIdx.x & 31, r0 = threadIdx.x >> 5;
#pragma unroll
  for (int rr = 0; rr < 32; rr += 8)
    t[rr + r0][c] = W[(size_t)(bj * 32 + rr + r0) * N + bi * 32 + c];
  __syncthreads();
#pragma unroll
  for (int rr = 0; rr < 32; rr += 8)
    Wt[(size_t)(bi * 32 + rr + r0) * K + bj * 32 + c] = (bf16)t[c][rr + r0];
}

// rt[t][j] = {cos, sin}(t * theta^(-j/32)), t<2048, j<32
__global__ __launch_bounds__(64) void k_rope_table(float* __restrict__ rt) {
  int t = blockIdx.x * 2 + (threadIdx.x >> 5);
  int j = threadIdx.x & 31;
  float freq = exp2f(-(float)j * (1.0f / 32.0f) * log2f(500000.0f));
  float ang = (float)t * freq;
  rt[t * 64 + 2 * j] = cosf(ang);
  rt[t * 64 + 2 * j + 1] = sinf(ang);
}

template <int NCH>  // D = NCH*512, one wave per row; input row stride variable
__global__ __launch_bounds__(64) void k_rmsnorm(const bf16* __restrict__ in,
                                                const float* __restrict__ w,
                                                bf16* __restrict__ out,
                                                int in_stride) {
  int row = blockIdx.x, lane = threadIdx.x;
  const int D = NCH * 512;
  const bf16* ip = in + (size_t)row * in_stride;
  bf16x8 v[NCH];
  float ss = 0.f;
#pragma unroll
  for (int c = 0; c < NCH; ++c) {
    v[c] = *reinterpret_cast<const bf16x8*>(ip + c * 512 + lane * 8);
#pragma unroll
    for (int e = 0; e < 8; ++e) { float f = (float)v[c][e]; ss += f * f; }
  }
#pragma unroll
  for (int m = 1; m <= 32; m <<= 1) ss += __shfl_xor(ss, m);
  float rs = rsqrtf(ss / (float)D + 1e-6f);
  bf16* op = out + (size_t)row * D;
#pragma unroll
  for (int c = 0; c < NCH; ++c) {
    bf16x8 o;
#pragma unroll
    for (int e = 0; e < 8; ++e)
      o[e] = (bf16)((float)v[c][e] * rs * w[c * 512 + lane * 8 + e]);
    *reinterpret_cast<bf16x8*>(op + c * 512 + lane * 8) = o;
  }
}

// in [MR][stride], cols 0..511 rmsnorm -> kvn [MR][512]; cols 512..575 rope -> kr
__global__ __launch_bounds__(64) void k_kv_norm_rope(
    const bf16* __restrict__ in, const float* __restrict__ w,
    const float* __restrict__ rt, bf16* __restrict__ kvn,
    bf16* __restrict__ kr, int in_stride) {
  int row = blockIdx.x, lane = threadIdx.x;
  const bf16* ip = in + (size_t)row * in_stride;
  bf16x8 v = *reinterpret_cast<const bf16x8*>(ip + lane * 8);
  float ss = 0.f;
#pragma unroll
  for (int e = 0; e < 8; ++e) { float f = (float)v[e]; ss += f * f; }
#pragma unroll
  for (int m = 1; m <= 32; m <<= 1) ss += __shfl_xor(ss, m);
  float rs = rsqrtf(ss / 512.0f + 1e-6f);
  bf16x8 o;
#pragma unroll
  for (int e = 0; e < 8; ++e) o[e] = (bf16)((float)v[e] * rs * w[lane * 8 + e]);
  *reinterpret_cast<bf16x8*>(kvn + (size_t)row * 512 + lane * 8) = o;
  if (lane < 32) {
    int t = row & (TSEQ - 1);
    float x0 = (float)ip[512 + 2 * lane], x1 = (float)ip[512 + 2 * lane + 1];
    float c = rt[t * 64 + 2 * lane], s = rt[t * 64 + 2 * lane + 1];
    kr[(size_t)row * 64 + lane] = (bf16)(x0 * c - x1 * s);
    kr[(size_t)row * 64 + 32 + lane] = (bf16)(x1 * c + x0 * s);
  }
}

// q [MR][3072] (16 heads x 192); rope cols h*192+128..+191 -> qr [MR][16][64]
__global__ __launch_bounds__(256) void k_rope_q(const bf16* __restrict__ q,
                                                const float* __restrict__ rt,
                                                bf16* __restrict__ qr) {
  int idx = blockIdx.x * 256 + threadIdx.x;  // MR*16*32 total
  int j = idx & 31, h = (idx >> 5) & 15, row = idx >> 9;
  int t = row & (TSEQ - 1);
  const bf16* src = q + (size_t)row * 3072 + h * 192 + 128;
  float x0 = (float)src[2 * j], x1 = (float)src[2 * j + 1];
  float c = rt[t * 64 + 2 * j], s = rt[t * 64 + 2 * j + 1];
  bf16* dst = qr + ((size_t)row * 16 + h) * 64;
  dst[j] = (bf16)(x0 * c - x1 * s);
  dst[32 + j] = (bf16)(x1 * c + x0 * s);
}

// ---------------- GEMM (m97 structure, for N=2112): C = A @ Bt^T ----------
template <bool OUT_F32>
__global__ __launch_bounds__(256) void k_gemm_bt(const bf16* __restrict__ A,
                                                 const bf16* __restrict__ Bt,
                                                 void* __restrict__ C, int M,
                                                 int N, int K) {
  __shared__ bf16 As[128 * 32];
  __shared__ bf16 Bs[128 * 32];
  const int tid = threadIdx.x, lane = tid & 63, w = tid >> 6;
  const int wm = w >> 1, wn = w & 1;
  const int lg = lane >> 4, lr = lane & 15;
  const int m0 = blockIdx.y * 128, n0 = blockIdx.x * 128;
  f32x4 acc[4][4] = {};
  for (int k0 = 0; k0 < K; k0 += 32) {
    __syncthreads();
#pragma unroll
    for (int i = 0; i < 2; ++i) {
      int chunk = i * 256 + w * 64 + lane;
      int row = chunk >> 2, cc = chunk & 3;
      gload_lds16(A + (size_t)(m0 + row) * K + k0 + cc * 8,
                  (char*)As + (size_t)(i * 256 + w * 64) * 16);
      int nr = n0 + row;
      nr = nr < N ? nr : N - 1;  // clamp (garbage cols never stored)
      gload_lds16(Bt + (size_t)nr * K + k0 + cc * 8,
                  (char*)Bs + (size_t)(i * 256 + w * 64) * 16);
    }
    __syncthreads();
    bf16x8 af[4], bfr[4];
#pragma unroll
    for (int mi = 0; mi < 4; ++mi)
      af[mi] = *reinterpret_cast<const bf16x8*>(
          &As[(wm * 64 + mi * 16 + lr) * 32 + lg * 8]);
#pragma unroll
    for (int ni = 0; ni < 4; ++ni)
      bfr[ni] = *reinterpret_cast<const bf16x8*>(
          &Bs[(wn * 64 + ni * 16 + lr) * 32 + lg * 8]);
#pragma unroll
    for (int mi = 0; mi < 4; ++mi)
#pragma unroll
      for (int ni = 0; ni < 4; ++ni)
        acc[mi][ni] = mfma16(af[mi], bfr[ni], acc[mi][ni]);
  }
#pragma unroll
  for (int mi = 0; mi < 4; ++mi)
#pragma unroll
    for (int ni = 0; ni < 4; ++ni) {
      int col = n0 + wn * 64 + ni * 16 + lr;
      if (col < N) {
#pragma unroll
        for (int r = 0; r < 4; ++r) {
          int rowg = m0 + wm * 64 + mi * 16 + lg * 4 + r;
          if (OUT_F32)
            reinterpret_cast<float*>(C)[(size_t)rowg * N + col] = acc[mi][ni][r];
          else
            reinterpret_cast<bf16*>(C)[(size_t)rowg * N + col] =
                (bf16)acc[mi][ni][r];
        }
      }
    }
}

// ---------------- 8-phase 256x256 GEMM (T2+T3+T4+T5) ----------------
// BM=BN=256, BK=64, 8 waves (2M x 4N), 512 threads, LDS 128 KiB.
// 2 K-tiles per iteration, 8 phases; per phase: {ds_read frags; stage one
// half-tile via swizzled-source global_load_lds; barrier; 16 MFMA; barrier}.
// vmcnt(6) only at phases 4/8. XOR swizzle slot^=(row&7) on 16B slots;
// source pre-swizzled so LDS dest stays linear (rule 21).
// Half-tile stream per K-tile s: Bh0@(s-2).ph2, Bh1@.ph3, Ah0@.ph4,
// Ah1@(s-1).ph1 — matches region retirement (B.kh0 dies ph1, B.kh1/A.Mh0
// die ph2, A.Mh1 dies ph4).
#define GPH(BUF, MH, KH, DO_READB, STAGE_STMT, WAIT_STMT)                     \
  {                                                                           \
    if (DO_READB) {                                                           \
      _Pragma("unroll") for (int ni = 0; ni < 4; ++ni) {                      \
        int row = wn * 64 + ni * 16 + lr;                                     \
        breg[KH][ni] = *reinterpret_cast<const bf16x8*>(                      \
            &Bs[BUF][row * 64 + ((((KH)*4 + lg) ^ (row & 7)) * 8)]);          \
      }                                                                       \
    }                                                                         \
    bf16x8 af[4];                                                             \
    _Pragma("unroll") for (int mi = 0; mi < 4; ++mi) {                        \
      int row = wm * 128 + (MH)*64 + mi * 16 + lr;                            \
      af[mi] = *reinterpret_cast<const bf16x8*>(                              \
          &As[BUF][row * 64 + ((((KH)*4 + lg) ^ (row & 7)) * 8)]);            \
    }                                                                         \
    STAGE_STMT;                                                               \
    __builtin_amdgcn_s_barrier();                                             \
    __builtin_amdgcn_s_setprio(1);                                            \
    _Pragma("unroll") for (int mi = 0; mi < 4; ++mi)                          \
        _Pragma("unroll") for (int ni = 0; ni < 4; ++ni)                      \
            acc[(MH)*4 + mi][ni] =                                            \
        mfma16(af[mi], breg[KH][ni], acc[(MH)*4 + mi][ni]);                   \
    __builtin_amdgcn_s_setprio(0);                                            \
    WAIT_STMT;                                                                \
    __builtin_amdgcn_s_barrier();                                             \
  }

template <bool OUT_F32>
__global__ __launch_bounds__(512, 2) void k_gemm8(const bf16* __restrict__ A,
                                                  const bf16* __restrict__ Bt,
                                                  void* __restrict__ C, int M,
                                                  int N, int K) {
  __shared__ bf16 As[2][256 * 64];
  __shared__ bf16 Bs[2][256 * 64];
  const int tid = threadIdx.x, lane = tid & 63, w = tid >> 6;
  const int lg = lane >> 4, lr = lane & 15;
  const int wm = w >> 2, wn = w & 3;
  const int m0 = blockIdx.y * 256, n0 = blockIdx.x * 256;
  const int T = K >> 7;  // iterations; each covers 2 K-tiles of 64

  f32x4 acc[8][4] = {};
  bf16x8 breg[2][4];

  auto stageA = [&](int tau, int h) {
    char* dst = (char*)&As[tau & 1][0] + h * 16384;
#pragma unroll
    for (int j = 0; j < 2; ++j) {
      int c = j * 512 + tid;
      int row = c >> 3, slot = c & 7;
      gload_lds16(A + (size_t)(m0 + h * 128 + row) * K + tau * 64 +
                      ((slot ^ (row & 7)) * 8),
                  dst + (size_t)(j * 512 + w * 64) * 16);
    }
  };
  auto stageB = [&](int tau, int h) {
    char* dst = (char*)&Bs[tau & 1][0] + h * 16384;
#pragma unroll
    for (int j = 0; j < 2; ++j) {
      int c = j * 512 + tid;
      int row = c >> 3, slot = c & 7;
      gload_lds16(Bt + (size_t)(n0 + h * 128 + row) * K + tau * 64 +
                      ((slot ^ (row & 7)) * 8),
                  dst + (size_t)(j * 512 + w * 64) * 16);
    }
  };

  // prologue: tile0 fully + tile1 {Bh0,Bh1,Ah0}; Ah1 of tile1 at it0.ph1
  stageB(0, 0); stageB(0, 1); stageA(0, 0); stageA(0, 1);
  stageB(1, 0); stageB(1, 1); stageA(1, 0);
  asm volatile("s_waitcnt vmcnt(6)" ::: "memory");
  __builtin_amdgcn_s_barrier();

  for (int t = 0; t < T - 1; ++t) {
    const int s2 = 2 * t + 2, s3 = 2 * t + 3, a1 = 2 * t + 1;
    GPH(0, 0, 0, true,  stageA(a1, 1), ((void)0));
    GPH(0, 0, 1, true,  stageB(s2, 0), ((void)0));
    GPH(0, 1, 0, false, stageB(s2, 1), ((void)0));
    GPH(0, 1, 1, false, stageA(s2, 0),
        asm volatile("s_waitcnt vmcnt(6)" ::: "memory"));
    GPH(1, 0, 0, true,  stageA(s2, 1), ((void)0));
    GPH(1, 0, 1, true,  stageB(s3, 0), ((void)0));
    GPH(1, 1, 0, false, stageB(s3, 1), ((void)0));
    GPH(1, 1, 1, false, stageA(s3, 0),
        asm volatile("s_waitcnt vmcnt(6)" ::: "memory"));
  }
  // final iteration: tiles 2T-2 (buf0), 2T-1 (buf1); only ph1 stages
  {
    const int a1 = 2 * T - 1;
    GPH(0, 0, 0, true,  stageA(a1, 1), ((void)0));
    GPH(0, 0, 1, true,  ((void)0),     ((void)0));
    GPH(0, 1, 0, false, ((void)0),     ((void)0));
    GPH(0, 1, 1, false, ((void)0),
        asm volatile("s_waitcnt vmcnt(0)" ::: "memory"));
    GPH(1, 0, 0, true,  ((void)0), ((void)0));
    GPH(1, 0, 1, true,  ((void)0), ((void)0));
    GPH(1, 1, 0, false, ((void)0), ((void)0));
    GPH(1, 1, 1, false, ((void)0), ((void)0));
  }

  // epilogue: direct stores (same mapping as k_gemm_bt, verified)
#pragma unroll
  for (int mi = 0; mi < 8; ++mi)
#pragma unroll
    for (int ni = 0; ni < 4; ++ni) {
      int col = n0 + wn * 64 + ni * 16 + lr;
#pragma unroll
      for (int r = 0; r < 4; ++r) {
        int rowg = m0 + wm * 128 + mi * 16 + lg * 4 + r;
        if (OUT_F32)
          reinterpret_cast<float*>(C)[(size_t)rowg * N + col] = acc[mi][ni][r];
        else
          reinterpret_cast<bf16*>(C)[(size_t)rowg * N + col] =
              (bf16)acc[mi][ni][r];
      }
    }
}

// ---------------- causal flash attention v5 (unchanged) ----------------
__global__ __launch_bounds__(512, 2) void k_attn(const bf16* __restrict__ q,
                                                 const bf16* __restrict__ qr,
                                                 const bf16* __restrict__ kv,
                                                 const bf16* __restrict__ kr,
                                                 bf16* __restrict__ o) {
  __shared__ bf16 Kn[2][64 * 128];  // linear chunks; data col = j^(row&15)
  __shared__ bf16 Kr[2][64 * 64];   // data col = j^(row&7)
  __shared__ bf16 Vs[2][64 * 128];  // fragment-packed V^T
  __shared__ bf16 Ps[8 * 1024];     // per-wave P [16 q][64 k] swizzled
  const int tid = threadIdx.x, lane = tid & 63, w = tid >> 6;
  const int lg = lane >> 4, lr = lane & 15;
  const float qsc = 0.07216878364870323f * 1.44269504088896f;  // 192^-.5*log2e
  uint4 vreg[2];
  const int vrr = tid & 31, vvc = tid >> 5;

  for (int t = 0; t < 2; ++t) {
    const int id = t ? 511 - (int)blockIdx.x : (int)blockIdx.x;
    const int qt = 15 - (id >> 5);
    const int bh = id & 31;
    const int b = bh >> 4, h = bh & 15;
    const int q0 = qt * 128;
    const size_t rowbase = (size_t)b * TSEQ;
    const int nkt = 2 * qt + 2;
    const int qg = q0 + w * 16 + lr;

    auto issue_loads = [&](int kbase, int buf) {
#pragma unroll
      for (int kk = 0; kk < 2; ++kk)
        vreg[kk] = *reinterpret_cast<const uint4*>(
            kv + (rowbase + kbase + vrr * 2 + kk) * 4096 + h * 256 + 128 +
            vvc * 8);
#pragma unroll
      for (int i = 0; i < 2; ++i) {
        int c = i * 512 + tid;
        int row = c >> 4, j = c & 15;
        gload_lds16(
            kv + (rowbase + kbase + row) * 4096 + h * 256 +
                ((j ^ (row & 15)) * 8),
            (char*)&Kn[buf][0] + (size_t)(i * 512 + w * 64) * 16);
      }
      {
        int row = tid >> 3, j = tid & 7;
        gload_lds16(kr + (rowbase + kbase + row) * 64 + ((j ^ (row & 7)) * 8),
                    (char*)&Kr[buf][0] + (size_t)(w * 64) * 16);
      }
    };

    auto write_vs = [&](int buf) {
      const int kb0 = vrr * 2;
      const int cC = kb0 >> 5, g = (kb0 >> 3) & 3, j0 = kb0 & 7;
      const uint32_t* r0 = reinterpret_cast<const uint32_t*>(&vreg[0]);
      const uint32_t* r1 = reinterpret_cast<const uint32_t*>(&vreg[1]);
#pragma unroll
      for (int e = 0; e < 8; ++e) {
        uint32_t h0 = (r0[e >> 1] >> ((e & 1) * 16)) & 0xffffu;
        uint32_t h1 = (r1[e >> 1] >> ((e & 1) * 16)) & 0xffffu;
        int vd = vvc * 8 + e;
        int slot = (vd & 15) ^ g;
        *reinterpret_cast<uint32_t*>(
            &Vs[buf][((cC * 8 + (vd >> 4)) * 4 + g) * 128 + slot * 8 + j0]) =
            h0 | (h1 << 16);
      }
    };

    bf16x8 qf[6];
    {
      const bf16* qp = q + (rowbase + qg) * 3072 + h * 192;
#pragma unroll
      for (int dc = 0; dc < 4; ++dc) {
        bf16x8 v = *reinterpret_cast<const bf16x8*>(qp + dc * 32 + lg * 8);
#pragma unroll
        for (int e = 0; e < 8; ++e) v[e] = (bf16)((float)v[e] * qsc);
        qf[dc] = v;
      }
      const bf16* qrp = qr + ((rowbase + qg) * 16 + h) * 64;
#pragma unroll
      for (int dc = 0; dc < 2; ++dc) {
        bf16x8 v = *reinterpret_cast<const bf16x8*>(qrp + dc * 32 + lg * 8);
#pragma unroll
        for (int e = 0; e < 8; ++e) v[e] = (bf16)((float)v[e] * qsc);
        qf[4 + dc] = v;
      }
    }

    f32x4 oacc[8] = {};
    float m_run = -1e30f, l_run = 0.f;

    issue_loads(0, 0);
    write_vs(0);
    __syncthreads();

    for (int kt = 0; kt < nkt; ++kt) {
      const int kbase = kt * 64;
      const int buf = kt & 1;
      const bool more = (kt + 1 < nkt);
      if (more) issue_loads(kbase + 64, buf ^ 1);

      if (kbase <= q0 + w * 16 + 15) {
        f32x4 sacc[4];
#pragma unroll
        for (int kb = 0; kb < 4; ++kb) {
          const int row = kb * 16 + lr;
          bf16x8 kf[6];
#pragma unroll
          for (int dc = 0; dc < 4; ++dc)
            kf[dc] = *reinterpret_cast<const bf16x8*>(
                &Kn[buf][row * 128 + (((dc * 4 + lg) ^ (row & 15)) * 8)]);
#pragma unroll
          for (int dc = 0; dc < 2; ++dc)
            kf[4 + dc] = *reinterpret_cast<const bf16x8*>(
                &Kr[buf][row * 64 + (((dc * 4 + lg) ^ (row & 7)) * 8)]);
          __builtin_amdgcn_s_setprio(1);
          f32x4 sa = {0.f, 0.f, 0.f, 0.f};
#pragma unroll
          for (int dc = 0; dc < 6; ++dc) sa = mfma16(kf[dc], qf[dc], sa);
          sacc[kb] = sa;
          __builtin_amdgcn_s_setprio(0);
        }
        float sv[4][4];
        float pmax = -1e30f;
#pragma unroll
        for (int kb = 0; kb < 4; ++kb)
#pragma unroll
          for (int r = 0; r < 4; ++r) {
            int kgl = kbase + kb * 16 + lg * 4 + r;
            float val = (kgl <= qg) ? sacc[kb][r] : -1e30f;
            sv[kb][r] = val;
            pmax = fmaxf(pmax, val);
          }
        pmax = fmaxf(pmax, __shfl_xor(pmax, 16));
        pmax = fmaxf(pmax, __shfl_xor(pmax, 32));
        float mnew = fmaxf(m_run, pmax);
        float alpha = exp2f(m_run - mnew);
        float ls = 0.f;
#pragma unroll
        for (int kb = 0; kb < 4; ++kb) {
          bf16x4v pw;
#pragma unroll
          for (int r = 0; r < 4; ++r) {
            float p = exp2f(sv[kb][r] - mnew);
            ls += p;
            pw[r] = (bf16)p;
          }
          *reinterpret_cast<bf16x4v*>(
              &Ps[w * 1024 + lr * 64 +
                  (((kb * 2 + (lg >> 1)) ^ (lr & 7)) * 8) + (lg & 1) * 4]) = pw;
        }
        ls += __shfl_xor(ls, 16);
        ls += __shfl_xor(ls, 32);
        l_run = l_run * alpha + ls;
        m_run = mnew;
#pragma unroll
        for (int vb = 0; vb < 8; ++vb) {
          oacc[vb][0] *= alpha; oacc[vb][1] *= alpha;
          oacc[vb][2] *= alpha; oacc[vb][3] *= alpha;
        }
#pragma unroll
        for (int c = 0; c < 2; ++c) {
          bf16x8 pb = *reinterpret_cast<const bf16x8*>(
              &Ps[w * 1024 + lr * 64 + (((c * 4 + lg) ^ (lr & 7)) * 8)]);
          __builtin_amdgcn_s_setprio(1);
#pragma unroll
          for (int vb = 0; vb < 8; ++vb) {
            bf16x8 av = *reinterpret_cast<const bf16x8*>(
                &Vs[buf][((c * 8 + vb) * 4 + lg) * 128 + (lr ^ lg) * 8]);
            oacc[vb] = mfma16(av, pb, oacc[vb]);
          }
          __builtin_amdgcn_s_setprio(0);
        }
      }
      if (more) write_vs(buf ^ 1);
      __syncthreads();
    }

    bf16* Os = &Kn[0][0] + w * 2048;
    {
      float inv = 1.0f / l_run;
#pragma unroll
      for (int vb = 0; vb < 8; ++vb) {
        bf16x4v ov;
#pragma unroll
        for (int r = 0; r < 4; ++r) ov[r] = (bf16)(oacc[vb][r] * inv);
        int slot16 = vb * 2 + (lg >> 1);
        *reinterpret_cast<bf16x4v*>(
            &Os[lr * 128 + ((slot16 ^ (lr & 7)) * 8) + (lg & 1) * 4]) = ov;
      }
    }
    asm volatile("s_waitcnt lgkmcnt(0)");
    __builtin_amdgcn_sched_barrier(0);
#pragma unroll
    for (int i = 0; i < 4; ++i) {
      const int r = i * 4 + lg;
      bf16x8 ov = *reinterpret_cast<const bf16x8*>(
          &Os[r * 128 + ((lr ^ (r & 7)) * 8)]);
      *reinterpret_cast<bf16x8*>(
          o + (rowbase + q0 + w * 16 + r) * 2048 + h * 128 + lr * 8) = ov;
    }
    __syncthreads();
  }
}

// ---------------- launch ----------------
extern "C" void kernel_launch(void* const* d_in, const int* in_sizes, int n_in,
                              void* d_out, int out_size, void* d_ws,
                              size_t ws_size, hipStream_t stream) {
  (void)in_sizes; (void)n_in; (void)out_size; (void)ws_size;
  const float* x       = (const float*)d_in[0];
  const float* q_a_w   = (const float*)d_in[1];
  const float* q_a_ln  = (const float*)d_in[2];
  const float* q_b_w   = (const float*)d_in[3];
  const float* kv_a_w  = (const float*)d_in[4];
  const float* kv_a_ln = (const float*)d_in[5];
  const float* kv_b_w  = (const float*)d_in[6];
  const float* o_w     = (const float*)d_in[7];

  char* ws = (char*)d_ws;
  size_t off = 0;
  auto alloc = [&](size_t bytes) {
    void* p = ws + off;
    off += (bytes + 255) & ~(size_t)255;
    return p;
  };
  bf16* x_bf   = (bf16*)alloc((size_t)MR * 2048 * 2);
  bf16* ab_wt  = (bf16*)alloc((size_t)2112 * 2048 * 2);  // [q_a ; kv_a]^T
  bf16* qb_wt  = (bf16*)alloc((size_t)3072 * 1536 * 2);
  bf16* kvb_wt = (bf16*)alloc((size_t)4096 * 512 * 2);
  bf16* o_wt   = (bf16*)alloc((size_t)2048 * 2048 * 2);
  float* rt    = (float*)alloc((size_t)2048 * 64 * 4);
  bf16* qac    = (bf16*)alloc((size_t)MR * 2112 * 2);  // fused q_a|ckv
  bf16* q_a_n  = (bf16*)alloc((size_t)MR * 1536 * 2);
  bf16* kv_c_n = (bf16*)alloc((size_t)MR * 512 * 2);
  bf16* kr     = (bf16*)alloc((size_t)MR * 64 * 2);
  bf16* qbuf   = (bf16*)alloc((size_t)MR * 3072 * 2);
  bf16* qr     = (bf16*)alloc((size_t)MR * 16 * 64 * 2);
  bf16* kvbuf  = (bf16*)alloc((size_t)MR * 4096 * 2);
  bf16* attn_o = (bf16*)alloc((size_t)MR * 2048 * 2);

  k_cvt_bf16<<<8192, 256, 0, stream>>>(x, x_bf);
  k_transpose<<<dim3(1536 / 32, 2048 / 32), 256, 0, stream>>>(q_a_w, ab_wt, 2048, 1536);
  k_transpose<<<dim3(576 / 32, 2048 / 32), 256, 0, stream>>>(
      kv_a_w, ab_wt + (size_t)1536 * 2048, 2048, 576);
  k_transpose<<<dim3(3072 / 32, 1536 / 32), 256, 0, stream>>>(q_b_w, qb_wt, 1536, 3072);
  k_transpose<<<dim3(4096 / 32, 512 / 32), 256, 0, stream>>>(kv_b_w, kvb_wt, 512, 4096);
  k_transpose<<<dim3(2048 / 32, 2048 / 32), 256, 0, stream>>>(o_w, o_wt, 2048, 2048);
  k_rope_table<<<1024, 64, 0, stream>>>(rt);

  // fused q_a + kv_a down-projection: [4096][2112] (N indivisible by 256)
  k_gemm_bt<false><<<dim3(17, 32), 256, 0, stream>>>(x_bf, ab_wt, qac, MR, 2112, 2048);
  k_rmsnorm<3><<<MR, 64, 0, stream>>>(qac, q_a_ln, q_a_n, 2112);
  k_kv_norm_rope<<<MR, 64, 0, stream>>>(qac + 1536, kv_a_ln, rt, kv_c_n, kr, 2112);
  k_gemm8<false><<<dim3(12, 16), 512, 0, stream>>>(q_a_n, qb_wt, qbuf, MR, 3072, 1536);
  k_rope_q<<<8192, 256, 0, stream>>>(qbuf, rt, qr);
  k_gemm8<false><<<dim3(16, 16), 512, 0, stream>>>(kv_c_n, kvb_wt, kvbuf, MR, 4096, 512);
  k_attn<<<dim3(256), 512, 0, stream>>>(qbuf, qr, kvbuf, kr, attn_o);
  k_gemm8<true><<<dim3(8, 16), 512, 0, stream>>>(attn_o, o_wt, d_out, MR, 2048, 2048);
}

// Round 7
// 302.462 us; speedup vs baseline: 2.0325x; 1.0438x over previous
//
#include <hip/hip_runtime.h>
#include <hip/hip_bf16.h>
#include <cstdint>

// MLA: B=2, T=2048, H=16, d_nope=128, d_rope=64, d_qk=192, d_v=128,
// kv_lora=512, q_lora=1536, hidden=2048. Output f32 [4096][2048].

typedef __bf16 bf16;
typedef __bf16 bf16x8 __attribute__((ext_vector_type(8)));
typedef __bf16 bf16x4v __attribute__((ext_vector_type(4)));
typedef float f32x4 __attribute__((ext_vector_type(4)));

#define TSEQ 2048
#define MR 4096  // B*T

typedef const uint32_t __attribute__((address_space(1))) * gas1_t;
typedef uint32_t __attribute__((address_space(3))) * las3_t;

static __device__ __forceinline__ void gload_lds16(const void* g, void* l) {
  __builtin_amdgcn_global_load_lds(
      reinterpret_cast<gas1_t>(reinterpret_cast<uintptr_t>(g)),
      reinterpret_cast<las3_t>(reinterpret_cast<uintptr_t>(l)), 16, 0, 0);
}

static __device__ __forceinline__ f32x4 mfma16(bf16x8 a, bf16x8 b, f32x4 c) {
  return __builtin_amdgcn_mfma_f32_16x16x32_bf16(a, b, c, 0, 0, 0);
}

// ---------------- prep kernels ----------------

__global__ __launch_bounds__(256) void k_cvt_bf16(const float* __restrict__ in,
                                                  bf16* __restrict__ out) {
  int i = blockIdx.x * 256 + threadIdx.x;
  float4 f = reinterpret_cast<const float4*>(in)[i];
  bf16x4v o = {(bf16)f.x, (bf16)f.y, (bf16)f.z, (bf16)f.w};
  reinterpret_cast<bf16x4v*>(out)[i] = o;
}

__global__ __launch_bounds__(256) void k_zerofill(bf16* __restrict__ p) {
  uint4 z = make_uint4(0, 0, 0, 0);
  reinterpret_cast<uint4*>(p)[blockIdx.x * 256 + threadIdx.x] = z;
}

// W [K][N] f32 -> Wt [N][K] bf16 (K, N multiples of 32)
__global__ __launch_bounds__(256) void k_transpose(const float* __restrict__ W,
                                                   bf16* __restrict__ Wt,
                                                   int K, int N) {
  __shared__ float t[32][33];
  int bi = blockIdx.x, bj = blockIdx.y;
  int c = threadIdx.x & 31, r0 = threadIdx.x >> 5;
#pragma unroll
  for (int rr = 0; rr < 32; rr += 8)
    t[rr + r0][c] = W[(size_t)(bj * 32 + rr + r0) * N + bi * 32 + c];
  __syncthreads();
#pragma unroll
  for (int rr = 0; rr < 32; rr += 8)
    Wt[(size_t)(bi * 32 + rr + r0) * K + bj * 32 + c] = (bf16)t[c][rr + r0];
}

// rt[t][j] = {cos, sin}(t * theta^(-j/32)), t<2048, j<32
__global__ __launch_bounds__(64) void k_rope_table(float* __restrict__ rt) {
  int t = blockIdx.x * 2 + (threadIdx.x >> 5);
  int j = threadIdx.x & 31;
  float freq = exp2f(-(float)j * (1.0f / 32.0f) * log2f(500000.0f));
  float ang = (float)t * freq;
  rt[t * 64 + 2 * j] = cosf(ang);
  rt[t * 64 + 2 * j + 1] = sinf(ang);
}

template <int NCH>  // D = NCH*512, one wave per row; input row stride variable
__global__ __launch_bounds__(64) void k_rmsnorm(const bf16* __restrict__ in,
                                                const float* __restrict__ w,
                                                bf16* __restrict__ out,
                                                int in_stride) {
  int row = blockIdx.x, lane = threadIdx.x;
  const int D = NCH * 512;
  const bf16* ip = in + (size_t)row * in_stride;
  bf16x8 v[NCH];
  float ss = 0.f;
#pragma unroll
  for (int c = 0; c < NCH; ++c) {
    v[c] = *reinterpret_cast<const bf16x8*>(ip + c * 512 + lane * 8);
#pragma unroll
    for (int e = 0; e < 8; ++e) { float f = (float)v[c][e]; ss += f * f; }
  }
#pragma unroll
  for (int m = 1; m <= 32; m <<= 1) ss += __shfl_xor(ss, m);
  float rs = rsqrtf(ss / (float)D + 1e-6f);
  bf16* op = out + (size_t)row * D;
#pragma unroll
  for (int c = 0; c < NCH; ++c) {
    bf16x8 o;
#pragma unroll
    for (int e = 0; e < 8; ++e)
      o[e] = (bf16)((float)v[c][e] * rs * w[c * 512 + lane * 8 + e]);
    *reinterpret_cast<bf16x8*>(op + c * 512 + lane * 8) = o;
  }
}

// in [MR][stride], cols 0..511 rmsnorm -> kvn [MR][512]; cols 512..575 rope -> kr
__global__ __launch_bounds__(64) void k_kv_norm_rope(
    const bf16* __restrict__ in, const float* __restrict__ w,
    const float* __restrict__ rt, bf16* __restrict__ kvn,
    bf16* __restrict__ kr, int in_stride) {
  int row = blockIdx.x, lane = threadIdx.x;
  const bf16* ip = in + (size_t)row * in_stride;
  bf16x8 v = *reinterpret_cast<const bf16x8*>(ip + lane * 8);
  float ss = 0.f;
#pragma unroll
  for (int e = 0; e < 8; ++e) { float f = (float)v[e]; ss += f * f; }
#pragma unroll
  for (int m = 1; m <= 32; m <<= 1) ss += __shfl_xor(ss, m);
  float rs = rsqrtf(ss / 512.0f + 1e-6f);
  bf16x8 o;
#pragma unroll
  for (int e = 0; e < 8; ++e) o[e] = (bf16)((float)v[e] * rs * w[lane * 8 + e]);
  *reinterpret_cast<bf16x8*>(kvn + (size_t)row * 512 + lane * 8) = o;
  if (lane < 32) {
    int t = row & (TSEQ - 1);
    float x0 = (float)ip[512 + 2 * lane], x1 = (float)ip[512 + 2 * lane + 1];
    float c = rt[t * 64 + 2 * lane], s = rt[t * 64 + 2 * lane + 1];
    kr[(size_t)row * 64 + lane] = (bf16)(x0 * c - x1 * s);
    kr[(size_t)row * 64 + 32 + lane] = (bf16)(x1 * c + x0 * s);
  }
}

// q [MR][3072] (16 heads x 192); rope cols h*192+128..+191 -> qr [MR][16][64]
__global__ __launch_bounds__(256) void k_rope_q(const bf16* __restrict__ q,
                                                const float* __restrict__ rt,
                                                bf16* __restrict__ qr) {
  int idx = blockIdx.x * 256 + threadIdx.x;  // MR*16*32 total
  int j = idx & 31, h = (idx >> 5) & 15, row = idx >> 9;
  int t = row & (TSEQ - 1);
  const bf16* src = q + (size_t)row * 3072 + h * 192 + 128;
  float x0 = (float)src[2 * j], x1 = (float)src[2 * j + 1];
  float c = rt[t * 64 + 2 * j], s = rt[t * 64 + 2 * j + 1];
  bf16* dst = qr + ((size_t)row * 16 + h) * 64;
  dst[j] = (bf16)(x0 * c - x1 * s);
  dst[32 + j] = (bf16)(x1 * c + x0 * s);
}

// ---------------- 8-phase 256x256 GEMM (T2+T3+T4+T5) ----------------
// BM=BN=256, BK=64, 8 waves (2M x 4N), 512 threads, LDS 128 KiB.
// vmcnt(6) only at phases 4/8. XOR swizzle slot^=(row&7) on 16B slots;
// source pre-swizzled so LDS dest stays linear (rule 21).
#define GPH(BUF, MH, KH, DO_READB, STAGE_STMT, WAIT_STMT)                     \
  {                                                                           \
    if (DO_READB) {                                                           \
      _Pragma("unroll") for (int ni = 0; ni < 4; ++ni) {                      \
        int row = wn * 64 + ni * 16 + lr;                                     \
        breg[KH][ni] = *reinterpret_cast<const bf16x8*>(                      \
            &Bs[BUF][row * 64 + ((((KH)*4 + lg) ^ (row & 7)) * 8)]);          \
      }                                                                       \
    }                                                                         \
    bf16x8 af[4];                                                             \
    _Pragma("unroll") for (int mi = 0; mi < 4; ++mi) {                        \
      int row = wm * 128 + (MH)*64 + mi * 16 + lr;                            \
      af[mi] = *reinterpret_cast<const bf16x8*>(                              \
          &As[BUF][row * 64 + ((((KH)*4 + lg) ^ (row & 7)) * 8)]);            \
    }                                                                         \
    STAGE_STMT;                                                               \
    __builtin_amdgcn_s_barrier();                                             \
    __builtin_amdgcn_s_setprio(1);                                            \
    _Pragma("unroll") for (int mi = 0; mi < 4; ++mi)                          \
        _Pragma("unroll") for (int ni = 0; ni < 4; ++ni)                      \
            acc[(MH)*4 + mi][ni] =                                            \
        mfma16(af[mi], breg[KH][ni], acc[(MH)*4 + mi][ni]);                   \
    __builtin_amdgcn_s_setprio(0);                                            \
    WAIT_STMT;                                                                \
    __builtin_amdgcn_s_barrier();                                             \
  }

template <bool OUT_F32>
__global__ __launch_bounds__(512, 2) void k_gemm8(const bf16* __restrict__ A,
                                                  const bf16* __restrict__ Bt,
                                                  void* __restrict__ C, int M,
                                                  int N, int K) {
  __shared__ bf16 As[2][256 * 64];
  __shared__ bf16 Bs[2][256 * 64];
  const int tid = threadIdx.x, lane = tid & 63, w = tid >> 6;
  const int lg = lane >> 4, lr = lane & 15;
  const int wm = w >> 2, wn = w & 3;
  const int m0 = blockIdx.y * 256, n0 = blockIdx.x * 256;
  const int T = K >> 7;  // iterations; each covers 2 K-tiles of 64

  f32x4 acc[8][4] = {};
  bf16x8 breg[2][4];

  auto stageA = [&](int tau, int h) {
    char* dst = (char*)&As[tau & 1][0] + h * 16384;
#pragma unroll
    for (int j = 0; j < 2; ++j) {
      int c = j * 512 + tid;
      int row = c >> 3, slot = c & 7;
      gload_lds16(A + (size_t)(m0 + h * 128 + row) * K + tau * 64 +
                      ((slot ^ (row & 7)) * 8),
                  dst + (size_t)(j * 512 + w * 64) * 16);
    }
  };
  auto stageB = [&](int tau, int h) {
    char* dst = (char*)&Bs[tau & 1][0] + h * 16384;
#pragma unroll
    for (int j = 0; j < 2; ++j) {
      int c = j * 512 + tid;
      int row = c >> 3, slot = c & 7;
      gload_lds16(Bt + (size_t)(n0 + h * 128 + row) * K + tau * 64 +
                      ((slot ^ (row & 7)) * 8),
                  dst + (size_t)(j * 512 + w * 64) * 16);
    }
  };

  // prologue: tile0 fully + tile1 {Bh0,Bh1,Ah0}; Ah1 of tile1 at it0.ph1
  stageB(0, 0); stageB(0, 1); stageA(0, 0); stageA(0, 1);
  stageB(1, 0); stageB(1, 1); stageA(1, 0);
  asm volatile("s_waitcnt vmcnt(6)" ::: "memory");
  __builtin_amdgcn_s_barrier();

  for (int t = 0; t < T - 1; ++t) {
    const int s2 = 2 * t + 2, s3 = 2 * t + 3, a1 = 2 * t + 1;
    GPH(0, 0, 0, true,  stageA(a1, 1), ((void)0));
    GPH(0, 0, 1, true,  stageB(s2, 0), ((void)0));
    GPH(0, 1, 0, false, stageB(s2, 1), ((void)0));
    GPH(0, 1, 1, false, stageA(s2, 0),
        asm volatile("s_waitcnt vmcnt(6)" ::: "memory"));
    GPH(1, 0, 0, true,  stageA(s2, 1), ((void)0));
    GPH(1, 0, 1, true,  stageB(s3, 0), ((void)0));
    GPH(1, 1, 0, false, stageB(s3, 1), ((void)0));
    GPH(1, 1, 1, false, stageA(s3, 0),
        asm volatile("s_waitcnt vmcnt(6)" ::: "memory"));
  }
  // final iteration
  {
    const int a1 = 2 * T - 1;
    GPH(0, 0, 0, true,  stageA(a1, 1), ((void)0));
    GPH(0, 0, 1, true,  ((void)0),     ((void)0));
    GPH(0, 1, 0, false, ((void)0),     ((void)0));
    GPH(0, 1, 1, false, ((void)0),
        asm volatile("s_waitcnt vmcnt(0)" ::: "memory"));
    GPH(1, 0, 0, true,  ((void)0), ((void)0));
    GPH(1, 0, 1, true,  ((void)0), ((void)0));
    GPH(1, 1, 0, false, ((void)0), ((void)0));
    GPH(1, 1, 1, false, ((void)0), ((void)0));
  }

#pragma unroll
  for (int mi = 0; mi < 8; ++mi)
#pragma unroll
    for (int ni = 0; ni < 4; ++ni) {
      int col = n0 + wn * 64 + ni * 16 + lr;
#pragma unroll
      for (int r = 0; r < 4; ++r) {
        int rowg = m0 + wm * 128 + mi * 16 + lg * 4 + r;
        if (OUT_F32)
          reinterpret_cast<float*>(C)[(size_t)rowg * N + col] = acc[mi][ni][r];
        else
          reinterpret_cast<bf16*>(C)[(size_t)rowg * N + col] =
              (bf16)acc[mi][ni][r];
      }
    }
}

// ---------------- causal flash attention v6 ----------------
// v5 + T13 defer-max (THR=8, exp2 domain) + full-tile mask hoist.
__global__ __launch_bounds__(512, 2) void k_attn(const bf16* __restrict__ q,
                                                 const bf16* __restrict__ qr,
                                                 const bf16* __restrict__ kv,
                                                 const bf16* __restrict__ kr,
                                                 bf16* __restrict__ o) {
  __shared__ bf16 Kn[2][64 * 128];  // linear chunks; data col = j^(row&15)
  __shared__ bf16 Kr[2][64 * 64];   // data col = j^(row&7)
  __shared__ bf16 Vs[2][64 * 128];  // fragment-packed V^T
  __shared__ bf16 Ps[8 * 1024];     // per-wave P [16 q][64 k] swizzled
  const int tid = threadIdx.x, lane = tid & 63, w = tid >> 6;
  const int lg = lane >> 4, lr = lane & 15;
  const float qsc = 0.07216878364870323f * 1.44269504088896f;  // 192^-.5*log2e
  uint4 vreg[2];
  const int vrr = tid & 31, vvc = tid >> 5;

  for (int t = 0; t < 2; ++t) {
    const int id = t ? 511 - (int)blockIdx.x : (int)blockIdx.x;
    const int qt = 15 - (id >> 5);
    const int bh = id & 31;
    const int b = bh >> 4, h = bh & 15;
    const int q0 = qt * 128;
    const size_t rowbase = (size_t)b * TSEQ;
    const int nkt = 2 * qt + 2;
    const int qg = q0 + w * 16 + lr;

    auto issue_loads = [&](int kbase, int buf) {
#pragma unroll
      for (int kk = 0; kk < 2; ++kk)
        vreg[kk] = *reinterpret_cast<const uint4*>(
            kv + (rowbase + kbase + vrr * 2 + kk) * 4096 + h * 256 + 128 +
            vvc * 8);
#pragma unroll
      for (int i = 0; i < 2; ++i) {
        int c = i * 512 + tid;
        int row = c >> 4, j = c & 15;
        gload_lds16(
            kv + (rowbase + kbase + row) * 4096 + h * 256 +
                ((j ^ (row & 15)) * 8),
            (char*)&Kn[buf][0] + (size_t)(i * 512 + w * 64) * 16);
      }
      {
        int row = tid >> 3, j = tid & 7;
        gload_lds16(kr + (rowbase + kbase + row) * 64 + ((j ^ (row & 7)) * 8),
                    (char*)&Kr[buf][0] + (size_t)(w * 64) * 16);
      }
    };

    auto write_vs = [&](int buf) {
      const int kb0 = vrr * 2;
      const int cC = kb0 >> 5, g = (kb0 >> 3) & 3, j0 = kb0 & 7;
      const uint32_t* r0 = reinterpret_cast<const uint32_t*>(&vreg[0]);
      const uint32_t* r1 = reinterpret_cast<const uint32_t*>(&vreg[1]);
#pragma unroll
      for (int e = 0; e < 8; ++e) {
        uint32_t h0 = (r0[e >> 1] >> ((e & 1) * 16)) & 0xffffu;
        uint32_t h1 = (r1[e >> 1] >> ((e & 1) * 16)) & 0xffffu;
        int vd = vvc * 8 + e;
        int slot = (vd & 15) ^ g;
        *reinterpret_cast<uint32_t*>(
            &Vs[buf][((cC * 8 + (vd >> 4)) * 4 + g) * 128 + slot * 8 + j0]) =
            h0 | (h1 << 16);
      }
    };

    bf16x8 qf[6];
    {
      const bf16* qp = q + (rowbase + qg) * 3072 + h * 192;
#pragma unroll
      for (int dc = 0; dc < 4; ++dc) {
        bf16x8 v = *reinterpret_cast<const bf16x8*>(qp + dc * 32 + lg * 8);
#pragma unroll
        for (int e = 0; e < 8; ++e) v[e] = (bf16)((float)v[e] * qsc);
        qf[dc] = v;
      }
      const bf16* qrp = qr + ((rowbase + qg) * 16 + h) * 64;
#pragma unroll
      for (int dc = 0; dc < 2; ++dc) {
        bf16x8 v = *reinterpret_cast<const bf16x8*>(qrp + dc * 32 + lg * 8);
#pragma unroll
        for (int e = 0; e < 8; ++e) v[e] = (bf16)((float)v[e] * qsc);
        qf[4 + dc] = v;
      }
    }

    f32x4 oacc[8] = {};
    float m_run = -1e30f, l_run = 0.f;

    issue_loads(0, 0);
    write_vs(0);
    __syncthreads();

    for (int kt = 0; kt < nkt; ++kt) {
      const int kbase = kt * 64;
      const int buf = kt & 1;
      const bool more = (kt + 1 < nkt);
      if (more) issue_loads(kbase + 64, buf ^ 1);

      if (kbase <= q0 + w * 16 + 15) {
        f32x4 sacc[4];
#pragma unroll
        for (int kb = 0; kb < 4; ++kb) {
          const int row = kb * 16 + lr;
          bf16x8 kf[6];
#pragma unroll
          for (int dc = 0; dc < 4; ++dc)
            kf[dc] = *reinterpret_cast<const bf16x8*>(
                &Kn[buf][row * 128 + (((dc * 4 + lg) ^ (row & 15)) * 8)]);
#pragma unroll
          for (int dc = 0; dc < 2; ++dc)
            kf[4 + dc] = *reinterpret_cast<const bf16x8*>(
                &Kr[buf][row * 64 + (((dc * 4 + lg) ^ (row & 7)) * 8)]);
          __builtin_amdgcn_s_setprio(1);
          f32x4 sa = {0.f, 0.f, 0.f, 0.f};
#pragma unroll
          for (int dc = 0; dc < 6; ++dc) sa = mfma16(kf[dc], qf[dc], sa);
          sacc[kb] = sa;
          __builtin_amdgcn_s_setprio(0);
        }
        // ---- causal mask: only the diagonal tile needs it (wave-uniform) ----
        float sv[4][4];
        if (kbase + 63 <= q0 + w * 16) {  // fully unmasked tile
#pragma unroll
          for (int kb = 0; kb < 4; ++kb)
#pragma unroll
            for (int r = 0; r < 4; ++r) sv[kb][r] = sacc[kb][r];
        } else {
#pragma unroll
          for (int kb = 0; kb < 4; ++kb)
#pragma unroll
            for (int r = 0; r < 4; ++r) {
              int kgl = kbase + kb * 16 + lg * 4 + r;
              sv[kb][r] = (kgl <= qg) ? sacc[kb][r] : -1e30f;
            }
        }
        float pmax = -1e30f;
#pragma unroll
        for (int kb = 0; kb < 4; ++kb)
#pragma unroll
          for (int r = 0; r < 4; ++r) pmax = fmaxf(pmax, sv[kb][r]);
        pmax = fmaxf(pmax, __shfl_xor(pmax, 16));
        pmax = fmaxf(pmax, __shfl_xor(pmax, 32));
        // ---- T13 defer-max: rescale only when row max grew by > 8 ----
        if (!__all(pmax - m_run <= 8.0f)) {
          float mnew = fmaxf(m_run, pmax);
          float alpha = exp2f(m_run - mnew);
          l_run *= alpha;
#pragma unroll
          for (int vb = 0; vb < 8; ++vb) {
            oacc[vb][0] *= alpha; oacc[vb][1] *= alpha;
            oacc[vb][2] *= alpha; oacc[vb][3] *= alpha;
          }
          m_run = mnew;
        }
        float ls = 0.f;
#pragma unroll
        for (int kb = 0; kb < 4; ++kb) {
          bf16x4v pw;
#pragma unroll
          for (int r = 0; r < 4; ++r) {
            float p = exp2f(sv[kb][r] - m_run);
            ls += p;
            pw[r] = (bf16)p;
          }
          *reinterpret_cast<bf16x4v*>(
              &Ps[w * 1024 + lr * 64 +
                  (((kb * 2 + (lg >> 1)) ^ (lr & 7)) * 8) + (lg & 1) * 4]) = pw;
        }
        ls += __shfl_xor(ls, 16);
        ls += __shfl_xor(ls, 32);
        l_run += ls;
#pragma unroll
        for (int c = 0; c < 2; ++c) {
          bf16x8 pb = *reinterpret_cast<const bf16x8*>(
              &Ps[w * 1024 + lr * 64 + (((c * 4 + lg) ^ (lr & 7)) * 8)]);
          __builtin_amdgcn_s_setprio(1);
#pragma unroll
          for (int vb = 0; vb < 8; ++vb) {
            bf16x8 av = *reinterpret_cast<const bf16x8*>(
                &Vs[buf][((c * 8 + vb) * 4 + lg) * 128 + (lr ^ lg) * 8]);
            oacc[vb] = mfma16(av, pb, oacc[vb]);
          }
          __builtin_amdgcn_s_setprio(0);
        }
      }
      if (more) write_vs(buf ^ 1);
      __syncthreads();
    }

    bf16* Os = &Kn[0][0] + w * 2048;
    {
      float inv = 1.0f / l_run;
#pragma unroll
      for (int vb = 0; vb < 8; ++vb) {
        bf16x4v ov;
#pragma unroll
        for (int r = 0; r < 4; ++r) ov[r] = (bf16)(oacc[vb][r] * inv);
        int slot16 = vb * 2 + (lg >> 1);
        *reinterpret_cast<bf16x4v*>(
            &Os[lr * 128 + ((slot16 ^ (lr & 7)) * 8) + (lg & 1) * 4]) = ov;
      }
    }
    asm volatile("s_waitcnt lgkmcnt(0)");
    __builtin_amdgcn_sched_barrier(0);
#pragma unroll
    for (int i = 0; i < 4; ++i) {
      const int r = i * 4 + lg;
      bf16x8 ov = *reinterpret_cast<const bf16x8*>(
          &Os[r * 128 + ((lr ^ (r & 7)) * 8)]);
      *reinterpret_cast<bf16x8*>(
          o + (rowbase + q0 + w * 16 + r) * 2048 + h * 128 + lr * 8) = ov;
    }
    __syncthreads();
  }
}

// ---------------- launch ----------------
extern "C" void kernel_launch(void* const* d_in, const int* in_sizes, int n_in,
                              void* d_out, int out_size, void* d_ws,
                              size_t ws_size, hipStream_t stream) {
  (void)in_sizes; (void)n_in; (void)out_size; (void)ws_size;
  const float* x       = (const float*)d_in[0];
  const float* q_a_w   = (const float*)d_in[1];
  const float* q_a_ln  = (const float*)d_in[2];
  const float* q_b_w   = (const float*)d_in[3];
  const float* kv_a_w  = (const float*)d_in[4];
  const float* kv_a_ln = (const float*)d_in[5];
  const float* kv_b_w  = (const float*)d_in[6];
  const float* o_w     = (const float*)d_in[7];

  char* ws = (char*)d_ws;
  size_t off = 0;
  auto alloc = [&](size_t bytes) {
    void* p = ws + off;
    off += (bytes + 255) & ~(size_t)255;
    return p;
  };
  bf16* x_bf   = (bf16*)alloc((size_t)MR * 2048 * 2);
  bf16* ab_wt  = (bf16*)alloc((size_t)2304 * 2048 * 2);  // [q_a; kv_a; 0pad]^T
  bf16* qb_wt  = (bf16*)alloc((size_t)3072 * 1536 * 2);
  bf16* kvb_wt = (bf16*)alloc((size_t)4096 * 512 * 2);
  bf16* o_wt   = (bf16*)alloc((size_t)2048 * 2048 * 2);
  float* rt    = (float*)alloc((size_t)2048 * 64 * 4);
  bf16* qac    = (bf16*)alloc((size_t)MR * 2304 * 2);  // fused q_a|ckv|pad
  bf16* q_a_n  = (bf16*)alloc((size_t)MR * 1536 * 2);
  bf16* kv_c_n = (bf16*)alloc((size_t)MR * 512 * 2);
  bf16* kr     = (bf16*)alloc((size_t)MR * 64 * 2);
  bf16* qbuf   = (bf16*)alloc((size_t)MR * 3072 * 2);
  bf16* qr     = (bf16*)alloc((size_t)MR * 16 * 64 * 2);
  bf16* kvbuf  = (bf16*)alloc((size_t)MR * 4096 * 2);
  bf16* attn_o = (bf16*)alloc((size_t)MR * 2048 * 2);

  k_cvt_bf16<<<8192, 256, 0, stream>>>(x, x_bf);
  k_transpose<<<dim3(1536 / 32, 2048 / 32), 256, 0, stream>>>(q_a_w, ab_wt, 2048, 1536);
  k_transpose<<<dim3(576 / 32, 2048 / 32), 256, 0, stream>>>(
      kv_a_w, ab_wt + (size_t)1536 * 2048, 2048, 576);
  k_zerofill<<<192, 256, 0, stream>>>(ab_wt + (size_t)2112 * 2048);  // pad rows
  k_transpose<<<dim3(3072 / 32, 1536 / 32), 256, 0, stream>>>(q_b_w, qb_wt, 1536, 3072);
  k_transpose<<<dim3(4096 / 32, 512 / 32), 256, 0, stream>>>(kv_b_w, kvb_wt, 512, 4096);
  k_transpose<<<dim3(2048 / 32, 2048 / 32), 256, 0, stream>>>(o_w, o_wt, 2048, 2048);
  k_rope_table<<<1024, 64, 0, stream>>>(rt);

  // fused q_a + kv_a down-projection, N padded 2112 -> 2304 (pad cols = 0)
  k_gemm8<false><<<dim3(9, 16), 512, 0, stream>>>(x_bf, ab_wt, qac, MR, 2304, 2048);
  k_rmsnorm<3><<<MR, 64, 0, stream>>>(qac, q_a_ln, q_a_n, 2304);
  k_kv_norm_rope<<<MR, 64, 0, stream>>>(qac + 1536, kv_a_ln, rt, kv_c_n, kr, 2304);
  k_gemm8<false><<<dim3(12, 16), 512, 0, stream>>>(q_a_n, qb_wt, qbuf, MR, 3072, 1536);
  k_rope_q<<<8192, 256, 0, stream>>>(qbuf, rt, qr);
  k_gemm8<false><<<dim3(16, 16), 512, 0, stream>>>(kv_c_n, kvb_wt, kvbuf, MR, 4096, 512);
  k_attn<<<dim3(256), 512, 0, stream>>>(qbuf, qr, kvbuf, kr, attn_o);
  k_gemm8<true><<<dim3(8, 16), 512, 0, stream>>>(attn_o, o_wt, d_out, MR, 2048, 2048);
}

// Round 9
// 299.862 us; speedup vs baseline: 2.0502x; 1.0087x over previous
//
#include <hip/hip_runtime.h>
#include <hip/hip_bf16.h>
#include <cstdint>

// MLA: B=2, T=2048, H=16, d_nope=128, d_rope=64, d_qk=192, d_v=128,
// kv_lora=512, q_lora=1536, hidden=2048. Output f32 [4096][2048].

typedef __bf16 bf16;
typedef __bf16 bf16x8 __attribute__((ext_vector_type(8)));
typedef __bf16 bf16x4v __attribute__((ext_vector_type(4)));
typedef float f32x4 __attribute__((ext_vector_type(4)));

#define TSEQ 2048
#define MR 4096  // B*T

typedef const uint32_t __attribute__((address_space(1))) * gas1_t;
typedef uint32_t __attribute__((address_space(3))) * las3_t;

static __device__ __forceinline__ void gload_lds16(const void* g, void* l) {
  __builtin_amdgcn_global_load_lds(
      reinterpret_cast<gas1_t>(reinterpret_cast<uintptr_t>(g)),
      reinterpret_cast<las3_t>(reinterpret_cast<uintptr_t>(l)), 16, 0, 0);
}

static __device__ __forceinline__ f32x4 mfma16(bf16x8 a, bf16x8 b, f32x4 c) {
  return __builtin_amdgcn_mfma_f32_16x16x32_bf16(a, b, c, 0, 0, 0);
}

// ---------------- prep kernels ----------------

__global__ __launch_bounds__(256) void k_cvt_bf16(const float* __restrict__ in,
                                                  bf16* __restrict__ out) {
  int i = blockIdx.x * 256 + threadIdx.x;
  float4 f = reinterpret_cast<const float4*>(in)[i];
  bf16x4v o = {(bf16)f.x, (bf16)f.y, (bf16)f.z, (bf16)f.w};
  reinterpret_cast<bf16x4v*>(out)[i] = o;
}

__global__ __launch_bounds__(256) void k_zerofill(bf16* __restrict__ p) {
  uint4 z = make_uint4(0, 0, 0, 0);
  reinterpret_cast<uint4*>(p)[blockIdx.x * 256 + threadIdx.x] = z;
}

// W [K][N] f32 -> Wt [N][K] bf16 (K, N multiples of 32)
__global__ __launch_bounds__(256) void k_transpose(const float* __restrict__ W,
                                                   bf16* __restrict__ Wt,
                                                   int K, int N) {
  __shared__ float t[32][33];
  int bi = blockIdx.x, bj = blockIdx.y;
  int c = threadIdx.x & 31, r0 = threadIdx.x >> 5;
#pragma unroll
  for (int rr = 0; rr < 32; rr += 8)
    t[rr + r0][c] = W[(size_t)(bj * 32 + rr + r0) * N + bi * 32 + c];
  __syncthreads();
#pragma unroll
  for (int rr = 0; rr < 32; rr += 8)
    Wt[(size_t)(bi * 32 + rr + r0) * K + bj * 32 + c] = (bf16)t[c][rr + r0];
}

// rt[t][j] = {cos, sin}(t * theta^(-j/32)), t<2048, j<32
__global__ __launch_bounds__(64) void k_rope_table(float* __restrict__ rt) {
  int t = blockIdx.x * 2 + (threadIdx.x >> 5);
  int j = threadIdx.x & 31;
  float freq = exp2f(-(float)j * (1.0f / 32.0f) * log2f(500000.0f));
  float ang = (float)t * freq;
  rt[t * 64 + 2 * j] = cosf(ang);
  rt[t * 64 + 2 * j + 1] = sinf(ang);
}

template <int NCH>  // D = NCH*512, one wave per row; input row stride variable
__global__ __launch_bounds__(64) void k_rmsnorm(const bf16* __restrict__ in,
                                                const float* __restrict__ w,
                                                bf16* __restrict__ out,
                                                int in_stride) {
  int row = blockIdx.x, lane = threadIdx.x;
  const int D = NCH * 512;
  const bf16* ip = in + (size_t)row * in_stride;
  bf16x8 v[NCH];
  float ss = 0.f;
#pragma unroll
  for (int c = 0; c < NCH; ++c) {
    v[c] = *reinterpret_cast<const bf16x8*>(ip + c * 512 + lane * 8);
#pragma unroll
    for (int e = 0; e < 8; ++e) { float f = (float)v[c][e]; ss += f * f; }
  }
#pragma unroll
  for (int m = 1; m <= 32; m <<= 1) ss += __shfl_xor(ss, m);
  float rs = rsqrtf(ss / (float)D + 1e-6f);
  bf16* op = out + (size_t)row * D;
#pragma unroll
  for (int c = 0; c < NCH; ++c) {
    bf16x8 o;
#pragma unroll
    for (int e = 0; e < 8; ++e)
      o[e] = (bf16)((float)v[c][e] * rs * w[c * 512 + lane * 8 + e]);
    *reinterpret_cast<bf16x8*>(op + c * 512 + lane * 8) = o;
  }
}

// in [MR][stride], cols 0..511 rmsnorm -> kvn [MR][512]; cols 512..575 rope -> kr
__global__ __launch_bounds__(64) void k_kv_norm_rope(
    const bf16* __restrict__ in, const float* __restrict__ w,
    const float* __restrict__ rt, bf16* __restrict__ kvn,
    bf16* __restrict__ kr, int in_stride) {
  int row = blockIdx.x, lane = threadIdx.x;
  const bf16* ip = in + (size_t)row * in_stride;
  bf16x8 v = *reinterpret_cast<const bf16x8*>(ip + lane * 8);
  float ss = 0.f;
#pragma unroll
  for (int e = 0; e < 8; ++e) { float f = (float)v[e]; ss += f * f; }
#pragma unroll
  for (int m = 1; m <= 32; m <<= 1) ss += __shfl_xor(ss, m);
  float rs = rsqrtf(ss / 512.0f + 1e-6f);
  bf16x8 o;
#pragma unroll
  for (int e = 0; e < 8; ++e) o[e] = (bf16)((float)v[e] * rs * w[lane * 8 + e]);
  *reinterpret_cast<bf16x8*>(kvn + (size_t)row * 512 + lane * 8) = o;
  if (lane < 32) {
    int t = row & (TSEQ - 1);
    float x0 = (float)ip[512 + 2 * lane], x1 = (float)ip[512 + 2 * lane + 1];
    float c = rt[t * 64 + 2 * lane], s = rt[t * 64 + 2 * lane + 1];
    kr[(size_t)row * 64 + lane] = (bf16)(x0 * c - x1 * s);
    kr[(size_t)row * 64 + 32 + lane] = (bf16)(x1 * c + x0 * s);
  }
}

// q [MR][3072] (16 heads x 192); rope cols h*192+128..+191 -> qr [MR][16][64]
__global__ __launch_bounds__(256) void k_rope_q(const bf16* __restrict__ q,
                                                const float* __restrict__ rt,
                                                bf16* __restrict__ qr) {
  int idx = blockIdx.x * 256 + threadIdx.x;  // MR*16*32 total
  int j = idx & 31, h = (idx >> 5) & 15, row = idx >> 9;
  int t = row & (TSEQ - 1);
  const bf16* src = q + (size_t)row * 3072 + h * 192 + 128;
  float x0 = (float)src[2 * j], x1 = (float)src[2 * j + 1];
  float c = rt[t * 64 + 2 * j], s = rt[t * 64 + 2 * j + 1];
  bf16* dst = qr + ((size_t)row * 16 + h) * 64;
  dst[j] = (bf16)(x0 * c - x1 * s);
  dst[32 + j] = (bf16)(x1 * c + x0 * s);
}

// ---------------- 8-phase 256x256 GEMM (T2+T3+T4+T5) ----------------
// BM=BN=256, BK=64, 8 waves (2M x 4N), 512 threads, LDS 128 KiB.
// vmcnt(6) only at phases 4/8. XOR swizzle slot^=(row&7) on 16B slots;
// source pre-swizzled so LDS dest stays linear (rule 21).
#define GPH(BUF, MH, KH, DO_READB, STAGE_STMT, WAIT_STMT)                     \
  {                                                                           \
    if (DO_READB) {                                                           \
      _Pragma("unroll") for (int ni = 0; ni < 4; ++ni) {                      \
        int row = wn * 64 + ni * 16 + lr;                                     \
        breg[KH][ni] = *reinterpret_cast<const bf16x8*>(                      \
            &Bs[BUF][row * 64 + ((((KH)*4 + lg) ^ (row & 7)) * 8)]);          \
      }                                                                       \
    }                                                                         \
    bf16x8 af[4];                                                             \
    _Pragma("unroll") for (int mi = 0; mi < 4; ++mi) {                        \
      int row = wm * 128 + (MH)*64 + mi * 16 + lr;                            \
      af[mi] = *reinterpret_cast<const bf16x8*>(                              \
          &As[BUF][row * 64 + ((((KH)*4 + lg) ^ (row & 7)) * 8)]);            \
    }                                                                         \
    STAGE_STMT;                                                               \
    __builtin_amdgcn_s_barrier();                                             \
    __builtin_amdgcn_s_setprio(1);                                            \
    _Pragma("unroll") for (int mi = 0; mi < 4; ++mi)                          \
        _Pragma("unroll") for (int ni = 0; ni < 4; ++ni)                      \
            acc[(MH)*4 + mi][ni] =                                            \
        mfma16(af[mi], breg[KH][ni], acc[(MH)*4 + mi][ni]);                   \
    __builtin_amdgcn_s_setprio(0);                                            \
    WAIT_STMT;                                                                \
    __builtin_amdgcn_s_barrier();                                             \
  }

template <bool OUT_F32>
__global__ __launch_bounds__(512, 2) void k_gemm8(const bf16* __restrict__ A,
                                                  const bf16* __restrict__ Bt,
                                                  void* __restrict__ C, int M,
                                                  int N, int K) {
  __shared__ bf16 As[2][256 * 64];
  __shared__ bf16 Bs[2][256 * 64];
  const int tid = threadIdx.x, lane = tid & 63, w = tid >> 6;
  const int lg = lane >> 4, lr = lane & 15;
  const int wm = w >> 2, wn = w & 3;
  const int m0 = blockIdx.y * 256, n0 = blockIdx.x * 256;
  const int T = K >> 7;  // iterations; each covers 2 K-tiles of 64

  f32x4 acc[8][4] = {};
  bf16x8 breg[2][4];

  auto stageA = [&](int tau, int h) {
    char* dst = (char*)&As[tau & 1][0] + h * 16384;
#pragma unroll
    for (int j = 0; j < 2; ++j) {
      int c = j * 512 + tid;
      int row = c >> 3, slot = c & 7;
      gload_lds16(A + (size_t)(m0 + h * 128 + row) * K + tau * 64 +
                      ((slot ^ (row & 7)) * 8),
                  dst + (size_t)(j * 512 + w * 64) * 16);
    }
  };
  auto stageB = [&](int tau, int h) {
    char* dst = (char*)&Bs[tau & 1][0] + h * 16384;
#pragma unroll
    for (int j = 0; j < 2; ++j) {
      int c = j * 512 + tid;
      int row = c >> 3, slot = c & 7;
      gload_lds16(Bt + (size_t)(n0 + h * 128 + row) * K + tau * 64 +
                      ((slot ^ (row & 7)) * 8),
                  dst + (size_t)(j * 512 + w * 64) * 16);
    }
  };

  // prologue: tile0 fully + tile1 {Bh0,Bh1,Ah0}; Ah1 of tile1 at it0.ph1
  stageB(0, 0); stageB(0, 1); stageA(0, 0); stageA(0, 1);
  stageB(1, 0); stageB(1, 1); stageA(1, 0);
  asm volatile("s_waitcnt vmcnt(6)" ::: "memory");
  __builtin_amdgcn_s_barrier();

  for (int t = 0; t < T - 1; ++t) {
    const int s2 = 2 * t + 2, s3 = 2 * t + 3, a1 = 2 * t + 1;
    GPH(0, 0, 0, true,  stageA(a1, 1), ((void)0));
    GPH(0, 0, 1, true,  stageB(s2, 0), ((void)0));
    GPH(0, 1, 0, false, stageB(s2, 1), ((void)0));
    GPH(0, 1, 1, false, stageA(s2, 0),
        asm volatile("s_waitcnt vmcnt(6)" ::: "memory"));
    GPH(1, 0, 0, true,  stageA(s2, 1), ((void)0));
    GPH(1, 0, 1, true,  stageB(s3, 0), ((void)0));
    GPH(1, 1, 0, false, stageB(s3, 1), ((void)0));
    GPH(1, 1, 1, false, stageA(s3, 0),
        asm volatile("s_waitcnt vmcnt(6)" ::: "memory"));
  }
  // final iteration
  {
    const int a1 = 2 * T - 1;
    GPH(0, 0, 0, true,  stageA(a1, 1), ((void)0));
    GPH(0, 0, 1, true,  ((void)0),     ((void)0));
    GPH(0, 1, 0, false, ((void)0),     ((void)0));
    GPH(0, 1, 1, false, ((void)0),
        asm volatile("s_waitcnt vmcnt(0)" ::: "memory"));
    GPH(1, 0, 0, true,  ((void)0), ((void)0));
    GPH(1, 0, 1, true,  ((void)0), ((void)0));
    GPH(1, 1, 0, false, ((void)0), ((void)0));
    GPH(1, 1, 1, false, ((void)0), ((void)0));
  }

#pragma unroll
  for (int mi = 0; mi < 8; ++mi)
#pragma unroll
    for (int ni = 0; ni < 4; ++ni) {
      int col = n0 + wn * 64 + ni * 16 + lr;
#pragma unroll
      for (int r = 0; r < 4; ++r) {
        int rowg = m0 + wm * 128 + mi * 16 + lg * 4 + r;
        if (OUT_F32)
          reinterpret_cast<float*>(C)[(size_t)rowg * N + col] = acc[mi][ni][r];
        else
          reinterpret_cast<bf16*>(C)[(size_t)rowg * N + col] =
              (bf16)acc[mi][ni][r];
      }
    }
}

// ---------------- causal flash attention v6 ----------------
// v5 + T13 defer-max (THR=8, exp2 domain) + full-tile mask hoist.
__global__ __launch_bounds__(512, 2) void k_attn(const bf16* __restrict__ q,
                                                 const bf16* __restrict__ qr,
                                                 const bf16* __restrict__ kv,
                                                 const bf16* __restrict__ kr,
                                                 bf16* __restrict__ o) {
  __shared__ bf16 Kn[2][64 * 128];  // linear chunks; data col = j^(row&15)
  __shared__ bf16 Kr[2][64 * 64];   // data col = j^(row&7)
  __shared__ bf16 Vs[2][64 * 128];  // fragment-packed V^T
  __shared__ bf16 Ps[8 * 1024];     // per-wave P [16 q][64 k] swizzled
  const int tid = threadIdx.x, lane = tid & 63, w = tid >> 6;
  const int lg = lane >> 4, lr = lane & 15;
  const float qsc = 0.07216878364870323f * 1.44269504088896f;  // 192^-.5*log2e
  uint4 vreg[2];
  const int vrr = tid & 31, vvc = tid >> 5;

  for (int t = 0; t < 2; ++t) {
    const int id = t ? 511 - (int)blockIdx.x : (int)blockIdx.x;
    const int qt = 15 - (id >> 5);
    const int bh = id & 31;
    const int b = bh >> 4, h = bh & 15;
    const int q0 = qt * 128;
    const size_t rowbase = (size_t)b * TSEQ;
    const int nkt = 2 * qt + 2;
    const int qg = q0 + w * 16 + lr;

    auto issue_loads = [&](int kbase, int buf) {
#pragma unroll
      for (int kk = 0; kk < 2; ++kk)
        vreg[kk] = *reinterpret_cast<const uint4*>(
            kv + (rowbase + kbase + vrr * 2 + kk) * 4096 + h * 256 + 128 +
            vvc * 8);
#pragma unroll
      for (int i = 0; i < 2; ++i) {
        int c = i * 512 + tid;
        int row = c >> 4, j = c & 15;
        gload_lds16(
            kv + (rowbase + kbase + row) * 4096 + h * 256 +
                ((j ^ (row & 15)) * 8),
            (char*)&Kn[buf][0] + (size_t)(i * 512 + w * 64) * 16);
      }
      {
        int row = tid >> 3, j = tid & 7;
        gload_lds16(kr + (rowbase + kbase + row) * 64 + ((j ^ (row & 7)) * 8),
                    (char*)&Kr[buf][0] + (size_t)(w * 64) * 16);
      }
    };

    auto write_vs = [&](int buf) {
      const int kb0 = vrr * 2;
      const int cC = kb0 >> 5, g = (kb0 >> 3) & 3, j0 = kb0 & 7;
      const uint32_t* r0 = reinterpret_cast<const uint32_t*>(&vreg[0]);
      const uint32_t* r1 = reinterpret_cast<const uint32_t*>(&vreg[1]);
#pragma unroll
      for (int e = 0; e < 8; ++e) {
        uint32_t h0 = (r0[e >> 1] >> ((e & 1) * 16)) & 0xffffu;
        uint32_t h1 = (r1[e >> 1] >> ((e & 1) * 16)) & 0xffffu;
        int vd = vvc * 8 + e;
        int slot = (vd & 15) ^ g;
        *reinterpret_cast<uint32_t*>(
            &Vs[buf][((cC * 8 + (vd >> 4)) * 4 + g) * 128 + slot * 8 + j0]) =
            h0 | (h1 << 16);
      }
    };

    bf16x8 qf[6];
    {
      const bf16* qp = q + (rowbase + qg) * 3072 + h * 192;
#pragma unroll
      for (int dc = 0; dc < 4; ++dc) {
        bf16x8 v = *reinterpret_cast<const bf16x8*>(qp + dc * 32 + lg * 8);
#pragma unroll
        for (int e = 0; e < 8; ++e) v[e] = (bf16)((float)v[e] * qsc);
        qf[dc] = v;
      }
      const bf16* qrp = qr + ((rowbase + qg) * 16 + h) * 64;
#pragma unroll
      for (int dc = 0; dc < 2; ++dc) {
        bf16x8 v = *reinterpret_cast<const bf16x8*>(qrp + dc * 32 + lg * 8);
#pragma unroll
        for (int e = 0; e < 8; ++e) v[e] = (bf16)((float)v[e] * qsc);
        qf[4 + dc] = v;
      }
    }

    f32x4 oacc[8] = {};
    float m_run = -1e30f, l_run = 0.f;

    issue_loads(0, 0);
    write_vs(0);
    __syncthreads();

    for (int kt = 0; kt < nkt; ++kt) {
      const int kbase = kt * 64;
      const int buf = kt & 1;
      const bool more = (kt + 1 < nkt);
      if (more) issue_loads(kbase + 64, buf ^ 1);

      if (kbase <= q0 + w * 16 + 15) {
        f32x4 sacc[4];
#pragma unroll
        for (int kb = 0; kb < 4; ++kb) {
          const int row = kb * 16 + lr;
          bf16x8 kf[6];
#pragma unroll
          for (int dc = 0; dc < 4; ++dc)
            kf[dc] = *reinterpret_cast<const bf16x8*>(
                &Kn[buf][row * 128 + (((dc * 4 + lg) ^ (row & 15)) * 8)]);
#pragma unroll
          for (int dc = 0; dc < 2; ++dc)
            kf[4 + dc] = *reinterpret_cast<const bf16x8*>(
                &Kr[buf][row * 64 + (((dc * 4 + lg) ^ (row & 7)) * 8)]);
          __builtin_amdgcn_s_setprio(1);
          f32x4 sa = {0.f, 0.f, 0.f, 0.f};
#pragma unroll
          for (int dc = 0; dc < 6; ++dc) sa = mfma16(kf[dc], qf[dc], sa);
          sacc[kb] = sa;
          __builtin_amdgcn_s_setprio(0);
        }
        // ---- causal mask: only the diagonal tile needs it (wave-uniform) ----
        float sv[4][4];
        if (kbase + 63 <= q0 + w * 16) {  // fully unmasked tile
#pragma unroll
          for (int kb = 0; kb < 4; ++kb)
#pragma unroll
            for (int r = 0; r < 4; ++r) sv[kb][r] = sacc[kb][r];
        } else {
#pragma unroll
          for (int kb = 0; kb < 4; ++kb)
#pragma unroll
            for (int r = 0; r < 4; ++r) {
              int kgl = kbase + kb * 16 + lg * 4 + r;
              sv[kb][r] = (kgl <= qg) ? sacc[kb][r] : -1e30f;
            }
        }
        float pmax = -1e30f;
#pragma unroll
        for (int kb = 0; kb < 4; ++kb)
#pragma unroll
          for (int r = 0; r < 4; ++r) pmax = fmaxf(pmax, sv[kb][r]);
        pmax = fmaxf(pmax, __shfl_xor(pmax, 16));
        pmax = fmaxf(pmax, __shfl_xor(pmax, 32));
        // ---- T13 defer-max: rescale only when row max grew by > 8 ----
        if (!__all(pmax - m_run <= 8.0f)) {
          float mnew = fmaxf(m_run, pmax);
          float alpha = exp2f(m_run - mnew);
          l_run *= alpha;
#pragma unroll
          for (int vb = 0; vb < 8; ++vb) {
            oacc[vb][0] *= alpha; oacc[vb][1] *= alpha;
            oacc[vb][2] *= alpha; oacc[vb][3] *= alpha;
          }
          m_run = mnew;
        }
        float ls = 0.f;
#pragma unroll
        for (int kb = 0; kb < 4; ++kb) {
          bf16x4v pw;
#pragma unroll
          for (int r = 0; r < 4; ++r) {
            float p = exp2f(sv[kb][r] - m_run);
            ls += p;
            pw[r] = (bf16)p;
          }
          *reinterpret_cast<bf16x4v*>(
              &Ps[w * 1024 + lr * 64 +
                  (((kb * 2 + (lg >> 1)) ^ (lr & 7)) * 8) + (lg & 1) * 4]) = pw;
        }
        ls += __shfl_xor(ls, 16);
        ls += __shfl_xor(ls, 32);
        l_run += ls;
#pragma unroll
        for (int c = 0; c < 2; ++c) {
          bf16x8 pb = *reinterpret_cast<const bf16x8*>(
              &Ps[w * 1024 + lr * 64 + (((c * 4 + lg) ^ (lr & 7)) * 8)]);
          __builtin_amdgcn_s_setprio(1);
#pragma unroll
          for (int vb = 0; vb < 8; ++vb) {
            bf16x8 av = *reinterpret_cast<const bf16x8*>(
                &Vs[buf][((c * 8 + vb) * 4 + lg) * 128 + (lr ^ lg) * 8]);
            oacc[vb] = mfma16(av, pb, oacc[vb]);
          }
          __builtin_amdgcn_s_setprio(0);
        }
      }
      if (more) write_vs(buf ^ 1);
      __syncthreads();
    }

    bf16* Os = &Kn[0][0] + w * 2048;
    {
      float inv = 1.0f / l_run;
#pragma unroll
      for (int vb = 0; vb < 8; ++vb) {
        bf16x4v ov;
#pragma unroll
        for (int r = 0; r < 4; ++r) ov[r] = (bf16)(oacc[vb][r] * inv);
        int slot16 = vb * 2 + (lg >> 1);
        *reinterpret_cast<bf16x4v*>(
            &Os[lr * 128 + ((slot16 ^ (lr & 7)) * 8) + (lg & 1) * 4]) = ov;
      }
    }
    asm volatile("s_waitcnt lgkmcnt(0)");
    __builtin_amdgcn_sched_barrier(0);
#pragma unroll
    for (int i = 0; i < 4; ++i) {
      const int r = i * 4 + lg;
      bf16x8 ov = *reinterpret_cast<const bf16x8*>(
          &Os[r * 128 + ((lr ^ (r & 7)) * 8)]);
      *reinterpret_cast<bf16x8*>(
          o + (rowbase + q0 + w * 16 + r) * 2048 + h * 128 + lr * 8) = ov;
    }
    __syncthreads();
  }
}

// ---------------- launch ----------------
extern "C" void kernel_launch(void* const* d_in, const int* in_sizes, int n_in,
                              void* d_out, int out_size, void* d_ws,
                              size_t ws_size, hipStream_t stream) {
  (void)in_sizes; (void)n_in; (void)out_size; (void)ws_size;
  const float* x       = (const float*)d_in[0];
  const float* q_a_w   = (const float*)d_in[1];
  const float* q_a_ln  = (const float*)d_in[2];
  const float* q_b_w   = (const float*)d_in[3];
  const float* kv_a_w  = (const float*)d_in[4];
  const float* kv_a_ln = (const float*)d_in[5];
  const float* kv_b_w  = (const float*)d_in[6];
  const float* o_w     = (const float*)d_in[7];

  char* ws = (char*)d_ws;
  size_t off = 0;
  auto alloc = [&](size_t bytes) {
    void* p = ws + off;
    off += (bytes + 255) & ~(size_t)255;
    return p;
  };
  bf16* x_bf   = (bf16*)alloc((size_t)MR * 2048 * 2);
  bf16* ab_wt  = (bf16*)alloc((size_t)2304 * 2048 * 2);  // [q_a; kv_a; 0pad]^T
  bf16* qb_wt  = (bf16*)alloc((size_t)3072 * 1536 * 2);
  bf16* kvb_wt = (bf16*)alloc((size_t)4096 * 512 * 2);
  bf16* o_wt   = (bf16*)alloc((size_t)2048 * 2048 * 2);
  float* rt    = (float*)alloc((size_t)2048 * 64 * 4);
  bf16* qac    = (bf16*)alloc((size_t)MR * 2304 * 2);  // fused q_a|ckv|pad
  bf16* q_a_n  = (bf16*)alloc((size_t)MR * 1536 * 2);
  bf16* kv_c_n = (bf16*)alloc((size_t)MR * 512 * 2);
  bf16* kr     = (bf16*)alloc((size_t)MR * 64 * 2);
  bf16* qbuf   = (bf16*)alloc((size_t)MR * 3072 * 2);
  bf16* qr     = (bf16*)alloc((size_t)MR * 16 * 64 * 2);
  bf16* kvbuf  = (bf16*)alloc((size_t)MR * 4096 * 2);
  bf16* attn_o = (bf16*)alloc((size_t)MR * 2048 * 2);

  k_cvt_bf16<<<8192, 256, 0, stream>>>(x, x_bf);
  k_transpose<<<dim3(1536 / 32, 2048 / 32), 256, 0, stream>>>(q_a_w, ab_wt, 2048, 1536);
  k_transpose<<<dim3(576 / 32, 2048 / 32), 256, 0, stream>>>(
      kv_a_w, ab_wt + (size_t)1536 * 2048, 2048, 576);
  k_zerofill<<<192, 256, 0, stream>>>(ab_wt + (size_t)2112 * 2048);  // pad rows
  k_transpose<<<dim3(3072 / 32, 1536 / 32), 256, 0, stream>>>(q_b_w, qb_wt, 1536, 3072);
  k_transpose<<<dim3(4096 / 32, 512 / 32), 256, 0, stream>>>(kv_b_w, kvb_wt, 512, 4096);
  k_transpose<<<dim3(2048 / 32, 2048 / 32), 256, 0, stream>>>(o_w, o_wt, 2048, 2048);
  k_rope_table<<<1024, 64, 0, stream>>>(rt);

  // fused q_a + kv_a down-projection, N padded 2112 -> 2304 (pad cols = 0)
  k_gemm8<false><<<dim3(9, 16), 512, 0, stream>>>(x_bf, ab_wt, qac, MR, 2304, 2048);
  k_rmsnorm<3><<<MR, 64, 0, stream>>>(qac, q_a_ln, q_a_n, 2304);
  k_kv_norm_rope<<<MR, 64, 0, stream>>>(qac + 1536, kv_a_ln, rt, kv_c_n, kr, 2304);
  k_gemm8<false><<<dim3(12, 16), 512, 0, stream>>>(q_a_n, qb_wt, qbuf, MR, 3072, 1536);
  k_rope_q<<<8192, 256, 0, stream>>>(qbuf, rt, qr);
  k_gemm8<false><<<dim3(16, 16), 512, 0, stream>>>(kv_c_n, kvb_wt, kvbuf, MR, 4096, 512);
  k_attn<<<dim3(256), 512, 0, stream>>>(qbuf, qr, kvbuf, kr, attn_o);
  k_gemm8<true><<<dim3(8, 16), 512, 0, stream>>>(attn_o, o_wt, d_out, MR, 2048, 2048);
}